// Round 2
// baseline (1099.792 us; speedup 1.0000x reference)
//
#include <hip/hip_runtime.h>
#include <cmath>

#define NB   16
#define CINC 256
#define DPC  512
#define COUTC 256
#define HDIM 64
#define WDIM 64
#define HWS  4096
#define EPSF 1.1920928955078125e-07f
#define BN_EPS 1e-5f
#define EXP_CLAMP 88.722835f

// ---------------------------------------------------------------------------
// Tiled fp32 GEMM: out[b][o][hw] = bias[o] + sum_c A[o][c] * Bm[b][c][hw]
// optionally + skip[b][o][hw].
// grid: (HWS/128, OTOT/128, NB), block 256.
// ---------------------------------------------------------------------------
template<int OTOT, int KTOT, bool ADD_SKIP>
__global__ __launch_bounds__(256) void gemm_k(const float* __restrict__ A,
                                              const float* __restrict__ Bm,
                                              const float* __restrict__ bias,
                                              const float* __restrict__ skip,
                                              float* __restrict__ out) {
    const int hw0 = blockIdx.x * 128;
    const int o0  = blockIdx.y * 128;
    const int b   = blockIdx.z;
    __shared__ float As[8][128];
    __shared__ float Bs[8][128];
    const int tid = threadIdx.x;
    const int to = tid >> 4;   // 0..15 (o dim)
    const int tn = tid & 15;   // 0..15 (hw dim)

    float acc[8][8];
#pragma unroll
    for (int i = 0; i < 8; ++i)
#pragma unroll
        for (int j = 0; j < 8; ++j) acc[i][j] = 0.f;

    const float* Bb = Bm + (size_t)b * KTOT * HWS;

    const int a_o  = tid & 127;        // 0..127
    const int a_k  = (tid >> 7) * 4;   // 0 or 4
    const int b_k  = tid >> 5;         // 0..7
    const int b_hw = (tid & 31) * 4;   // 0..124

    for (int k0 = 0; k0 < KTOT; k0 += 8) {
        float4 av = *reinterpret_cast<const float4*>(A + (size_t)(o0 + a_o) * KTOT + k0 + a_k);
        float4 bv = *reinterpret_cast<const float4*>(Bb + (size_t)(k0 + b_k) * HWS + hw0 + b_hw);
        __syncthreads();
        As[a_k + 0][a_o] = av.x;
        As[a_k + 1][a_o] = av.y;
        As[a_k + 2][a_o] = av.z;
        As[a_k + 3][a_o] = av.w;
        *reinterpret_cast<float4*>(&Bs[b_k][b_hw]) = bv;
        __syncthreads();
#pragma unroll
        for (int k = 0; k < 8; ++k) {
            float4 a0 = *reinterpret_cast<const float4*>(&As[k][to * 8]);
            float4 a1 = *reinterpret_cast<const float4*>(&As[k][to * 8 + 4]);
            float4 b0 = *reinterpret_cast<const float4*>(&Bs[k][tn * 8]);
            float4 b1 = *reinterpret_cast<const float4*>(&Bs[k][tn * 8 + 4]);
            float av8[8] = {a0.x, a0.y, a0.z, a0.w, a1.x, a1.y, a1.z, a1.w};
            float bv8[8] = {b0.x, b0.y, b0.z, b0.w, b1.x, b1.y, b1.z, b1.w};
#pragma unroll
            for (int i = 0; i < 8; ++i)
#pragma unroll
                for (int j = 0; j < 8; ++j)
                    acc[i][j] = fmaf(av8[i], bv8[j], acc[i][j]);
        }
    }

#pragma unroll
    for (int i = 0; i < 8; ++i) {
        int o = o0 + to * 8 + i;
        float bi = bias[o];
        size_t base = ((size_t)b * OTOT + o) * HWS + hw0 + tn * 8;
        float* op = out + base;
        const float* sp = ADD_SKIP ? (skip + base) : nullptr;
#pragma unroll
        for (int j = 0; j < 8; ++j) {
            float v = acc[i][j] + bi;
            if (ADD_SKIP) v += sp[j];
            op[j] = v;
        }
    }
}

// ---------------------------------------------------------------------------
// Dynamic pool: per (b,c) plane. out = log(conv5x5(exp(min(x,clamp)), kern_c) + eps)
// kern_c from sigma[c], normalized. grid: NB*DPC blocks, 256 threads.
// ---------------------------------------------------------------------------
__global__ __launch_bounds__(256) void pool_k(const float* __restrict__ in,
                                              const float* __restrict__ sigma,
                                              float* __restrict__ out) {
    const int bc = blockIdx.x;
    const int c = bc % DPC;
    __shared__ float ex[HWS];
    const int tid = threadIdx.x;
    const float* ip = in + (size_t)bc * HWS;
    float* op = out + (size_t)bc * HWS;

    // per-channel 5x5 gaussian weights in registers
    float s = sigma[c];
    float inv = 0.5f / (s * s + EPSF);
    float kw[25];
    float tot = 0.f;
#pragma unroll
    for (int i = 0; i < 5; ++i)
#pragma unroll
        for (int j = 0; j < 5; ++j) {
            float d2 = (float)((i - 2) * (i - 2) + (j - 2) * (j - 2));
            float v = expf(-d2 * inv);
            kw[i * 5 + j] = v;
            tot += v;
        }
    float rnorm = 1.f / tot;

#pragma unroll
    for (int t = 0; t < 4; ++t) {
        int idx = tid * 4 + t * 1024;
        float4 v = *reinterpret_cast<const float4*>(ip + idx);
        ex[idx + 0] = expf(fminf(v.x, EXP_CLAMP));
        ex[idx + 1] = expf(fminf(v.y, EXP_CLAMP));
        ex[idx + 2] = expf(fminf(v.z, EXP_CLAMP));
        ex[idx + 3] = expf(fminf(v.w, EXP_CLAMP));
    }
    __syncthreads();

    for (int t = 0; t < 16; ++t) {
        int p = tid + t * 256;
        int h = p >> 6, w = p & 63;
        float acc = 0.f;
        if (h >= 2 && h < 62 && w >= 2 && w < 62) {
#pragma unroll
            for (int i = 0; i < 5; ++i)
#pragma unroll
                for (int j = 0; j < 5; ++j)
                    acc = fmaf(kw[i * 5 + j], ex[(h + i - 2) * 64 + (w + j - 2)], acc);
        } else {
#pragma unroll
            for (int i = 0; i < 5; ++i) {
                int hh = h + i - 2;
                if (hh < 0 || hh >= 64) continue;
#pragma unroll
                for (int j = 0; j < 5; ++j) {
                    int ww = w + j - 2;
                    if (ww < 0 || ww >= 64) continue;
                    acc = fmaf(kw[i * 5 + j], ex[hh * 64 + ww], acc);
                }
            }
        }
        op[p] = logf(acc * rnorm + EPSF);
    }
}

// ---------------------------------------------------------------------------
// Displace: bilinear per-channel uniform shift with zero padding.
// ---------------------------------------------------------------------------
__global__ __launch_bounds__(256) void displace_k(const float* __restrict__ in,
                                                  const float* __restrict__ offsets,
                                                  float* __restrict__ out) {
    int i = blockIdx.x * 256 + threadIdx.x;   // < NB*DPC*HWS = 33554432
    int hw = i & (HWS - 1);
    int bc = i >> 12;
    int c = bc % DPC;
    int h = hw >> 6, w = hw & 63;
    int oi = c >> 3;   // c / 8
    float dy = offsets[oi * 2 + 0];
    float dx = offsets[oi * 2 + 1];
    float y0f = floorf(dy), x0f = floorf(dx);
    float fy = dy - y0f, fx = dx - x0f;
    int y0 = (int)y0f, x0 = (int)x0f;
    const float* ip = in + (size_t)bc * HWS;
    float acc = 0.f;
#pragma unroll
    for (int oy = 0; oy < 2; ++oy) {
#pragma unroll
        for (int ox = 0; ox < 2; ++ox) {
            int ry = h + y0 + oy;
            int rx = w + x0 + ox;
            float wgt = (oy ? fy : 1.f - fy) * (ox ? fx : 1.f - fx);
            if (ry >= 0 && ry < 64 && rx >= 0 && rx < 64)
                acc += wgt * ip[ry * 64 + rx];
        }
    }
    out[i] = acc;
}

// ---------------------------------------------------------------------------
// BN stats per channel over (B, HW): scale/shift so bn(x) = x*scale + shift
// ---------------------------------------------------------------------------
template<int CT>
__global__ __launch_bounds__(256) void bnstats_k(const float* __restrict__ a,
                                                 const float* __restrict__ gamma,
                                                 const float* __restrict__ beta,
                                                 float* __restrict__ scale,
                                                 float* __restrict__ shift) {
    const int c = blockIdx.x;
    float s = 0.f, s2 = 0.f;
    for (int b = 0; b < NB; ++b) {
        const float* p = a + ((size_t)b * CT + c) * HWS;
        for (int i = threadIdx.x * 4; i < HWS; i += 1024) {
            float4 v = *reinterpret_cast<const float4*>(p + i);
            s += v.x + v.y + v.z + v.w;
            s2 += v.x * v.x + v.y * v.y + v.z * v.z + v.w * v.w;
        }
    }
#pragma unroll
    for (int off = 32; off > 0; off >>= 1) {
        s += __shfl_down(s, off, 64);
        s2 += __shfl_down(s2, off, 64);
    }
    __shared__ float t1[4], t2[4];
    int lane = threadIdx.x & 63, wid = threadIdx.x >> 6;
    if (lane == 0) { t1[wid] = s; t2[wid] = s2; }
    __syncthreads();
    if (threadIdx.x == 0) {
        float S = t1[0] + t1[1] + t1[2] + t1[3];
        float S2 = t2[0] + t2[1] + t2[2] + t2[3];
        float n = (float)(NB * HWS);
        float mean = S / n;
        float var = S2 / n - mean * mean;
        float invs = rsqrtf(var + BN_EPS);
        float sc = invs * gamma[c];
        scale[c] = sc;
        shift[c] = beta[c] - mean * sc;
    }
}

__device__ inline float softplusf(float v) {
    return fmaxf(v, 0.f) + log1pf(expf(-fabsf(v)));
}

// ---------------------------------------------------------------------------
// Spatial sums of softplus(bn(a)) per (b,c).  grid NB*DPC.
// ---------------------------------------------------------------------------
__global__ __launch_bounds__(256) void ssum_k(const float* __restrict__ a,
                                              const float* __restrict__ scale,
                                              const float* __restrict__ shift,
                                              float* __restrict__ ssum) {
    const int bc = blockIdx.x;
    const int c = bc % DPC;
    float sc = scale[c], sh = shift[c];
    const float* p = a + (size_t)bc * HWS;
    float s = 0.f;
    for (int i = threadIdx.x * 4; i < HWS; i += 1024) {
        float4 v = *reinterpret_cast<const float4*>(p + i);
        s += softplusf(v.x * sc + sh);
        s += softplusf(v.y * sc + sh);
        s += softplusf(v.z * sc + sh);
        s += softplusf(v.w * sc + sh);
    }
#pragma unroll
    for (int off = 32; off > 0; off >>= 1) s += __shfl_down(s, off, 64);
    __shared__ float t1[4];
    int lane = threadIdx.x & 63, wid = threadIdx.x >> 6;
    if (lane == 0) t1[wid] = s;
    __syncthreads();
    if (threadIdx.x == 0) ssum[bc] = t1[0] + t1[1] + t1[2] + t1[3];
}

// ---------------------------------------------------------------------------
// m = softplus(bn(a)) / ssum[b,c] * disp   (in place over a)
// ---------------------------------------------------------------------------
__global__ __launch_bounds__(256) void attmul_k(float* __restrict__ a,
                                                const float* __restrict__ disp,
                                                const float* __restrict__ scale,
                                                const float* __restrict__ shift,
                                                const float* __restrict__ ssum) {
    int i = blockIdx.x * 256 + threadIdx.x;
    int bc = i >> 12;
    int c = bc % DPC;
    float v = a[i] * scale[c] + shift[c];
    a[i] = softplusf(v) / ssum[bc] * disp[i];
}

// ---------------------------------------------------------------------------
// Final: out = relu(out*scale + shift) in place
// ---------------------------------------------------------------------------
__global__ __launch_bounds__(256) void final_k(float* __restrict__ out,
                                               const float* __restrict__ scale,
                                               const float* __restrict__ shift) {
    int i = blockIdx.x * 256 + threadIdx.x;
    int c = (i >> 12) & (COUTC - 1);
    float v = out[i] * scale[c] + shift[c];
    out[i] = fmaxf(v, 0.f);
}

extern "C" void kernel_launch(void* const* d_in, const int* in_sizes, int n_in,
                              void* d_out, int out_size, void* d_ws, size_t ws_size,
                              hipStream_t stream) {
    const float* x           = (const float*)d_in[0];
    const float* pre_w       = (const float*)d_in[1];
    const float* pre_b       = (const float*)d_in[2];
    const float* sigma       = (const float*)d_in[3];
    const float* offsets     = (const float*)d_in[4];
    const float* atten_w     = (const float*)d_in[5];
    const float* atten_b     = (const float*)d_in[6];
    const float* atten_gamma = (const float*)d_in[7];
    const float* atten_beta  = (const float*)d_in[8];
    const float* post_w      = (const float*)d_in[9];
    const float* post_b      = (const float*)d_in[10];
    const float* bn_gamma    = (const float*)d_in[11];
    const float* bn_beta     = (const float*)d_in[12];
    float* out = (float*)d_out;

    float* ws = (float*)d_ws;
    const size_t BIG = (size_t)NB * DPC * HWS;   // 33554432 floats
    float* buf1 = ws;                 // [B, DP, HW]  (exactly fills 256 MiB with buf2)
    float* buf2 = ws + BIG;           // [B, DP, HW]

    // Small stats live in the TAIL of d_out during steps 1-7; step 8's GEMM
    // fully overwrites d_out afterwards, so this is transient scratch.
    // (Avoids needing d_ws > 2*BIG*4 bytes == exactly 256 MiB.)
    float* stA    = out + (size_t)out_size - 10240;
    float* scaleA = stA;              // 512
    float* shiftA = stA + 512;        // 512
    float* ssum   = stA + 1024;       // 8192  (total 9216 <= 10240)

    // scale2/shift2 used in steps 9-10: buf1 region is dead after step 7.
    float* scale2 = buf1;             // 256
    float* shift2 = buf1 + 256;       // 256

    // 1. pre conv1x1 -> buf1
    gemm_k<DPC, CINC, false><<<dim3(32, 4, NB), 256, 0, stream>>>(pre_w, x, pre_b, nullptr, buf1);
    // 2. dynamic pool -> buf2
    pool_k<<<NB * DPC, 256, 0, stream>>>(buf1, sigma, buf2);
    // 3. displace -> buf1
    displace_k<<<(NB * DPC * HWS) / 256, 256, 0, stream>>>(buf2, offsets, buf1);
    // 4. atten conv1x1 -> buf2
    gemm_k<DPC, CINC, false><<<dim3(32, 4, NB), 256, 0, stream>>>(atten_w, x, atten_b, nullptr, buf2);
    // 5. BN stats (atten)
    bnstats_k<DPC><<<DPC, 256, 0, stream>>>(buf2, atten_gamma, atten_beta, scaleA, shiftA);
    // 6. spatial softplus sums
    ssum_k<<<NB * DPC, 256, 0, stream>>>(buf2, scaleA, shiftA, ssum);
    // 7. m = atten * disp -> buf2 (in place; consumes buf1 + stats in d_out tail)
    attmul_k<<<(NB * DPC * HWS) / 256, 256, 0, stream>>>(buf2, buf1, scaleA, shiftA, ssum);
    // 8. post conv1x1 + skip -> out (fully overwrites d_out incl. stats tail)
    gemm_k<COUTC, DPC, true><<<dim3(32, 2, NB), 256, 0, stream>>>(post_w, buf2, post_b, x, out);
    // 9. BN stats (final) -> scale2/shift2 in buf1 (dead)
    bnstats_k<COUTC><<<COUTC, 256, 0, stream>>>(out, bn_gamma, bn_beta, scale2, shift2);
    // 10. relu(bn) in place
    final_k<<<out_size / 256, 256, 0, stream>>>(out, scale2, shift2);
}

// Round 3
// 662.572 us; speedup vs baseline: 1.6599x; 1.6599x over previous
//
#include <hip/hip_runtime.h>
#include <cmath>

#define NB   16
#define CINC 256
#define DPC  512
#define COUTC 256
#define HWS  4096
#define EPSF 1.1920928955078125e-07f
#define BN_EPS 1e-5f
#define EXP_CLAMP 88.722835f

typedef unsigned int uint32;
typedef unsigned short ushort;
typedef __bf16 bf16x8 __attribute__((ext_vector_type(8)));
typedef float f32x4 __attribute__((ext_vector_type(4)));
typedef unsigned short ushort8 __attribute__((ext_vector_type(8)));

__device__ inline ushort f2bf(float f) {          // RNE float->bf16
    uint32 u = __builtin_bit_cast(uint32, f);
    u += 0x7fffu + ((u >> 16) & 1u);
    return (ushort)(u >> 16);
}
__device__ inline float bf2f(ushort u) {
    return __builtin_bit_cast(float, (uint32)u << 16);
}
__device__ inline float softplusf(float v) {
    return fmaxf(v, 0.f) + log1pf(expf(-fabsf(v)));
}

// ---------------------------------------------------------------------------
// MFMA bf16 GEMM: out[b][o][hw] = bias[o] + sum_k A[o][k] * BT[b][hw][k]
// A: [OTOT][KTOT] bf16 row-major.  BT: [NB][HWS][KTOT] bf16 (K-major!).
// 128x128 tile, BK=32, 4 waves (each 64x64 = 4x4 frags of 16x16x32 MFMA).
// grid (HWS/128, OTOT/128, NB), block 256.
// ---------------------------------------------------------------------------
template<int OTOT, int KTOT, bool BF16_OUT, bool ADD_SKIP>
__global__ __launch_bounds__(256) void mfma_gemm_k(
    const ushort* __restrict__ A, const ushort* __restrict__ BT,
    const float* __restrict__ bias, const float* __restrict__ skip,
    void* __restrict__ outv) {
    const int hw0 = blockIdx.x * 128;
    const int o0  = blockIdx.y * 128;
    const int b   = blockIdx.z;
    __shared__ ushort As[128 * 32];
    __shared__ ushort Bs[128 * 32];
    const int tid  = threadIdx.x;
    const int lane = tid & 63;
    const int w    = tid >> 6;
    const int wm0  = (w >> 1) * 64;
    const int wn0  = (w & 1) * 64;

    f32x4 acc[4][4] = {};

    const ushort* Ab = A + (size_t)o0 * KTOT;
    const ushort* Bb = BT + ((size_t)b * HWS + hw0) * KTOT;
    const int r0 = tid >> 2;        // 0..63 (tile row within half)
    const int kb = (tid & 3) * 8;   // ushort offset in 32-wide K slab

    ushort8 apre[2], bpre[2];
#pragma unroll
    for (int j = 0; j < 2; ++j) {
        apre[j] = *reinterpret_cast<const ushort8*>(Ab + (size_t)(j * 64 + r0) * KTOT + kb);
        bpre[j] = *reinterpret_cast<const ushort8*>(Bb + (size_t)(j * 64 + r0) * KTOT + kb);
    }

    constexpr int NSTEP = KTOT / 32;
    for (int step = 0; step < NSTEP; ++step) {
        __syncthreads();
#pragma unroll
        for (int j = 0; j < 2; ++j) {
            *reinterpret_cast<ushort8*>(As + j * 2048 + tid * 8) = apre[j];
            *reinterpret_cast<ushort8*>(Bs + j * 2048 + tid * 8) = bpre[j];
        }
        __syncthreads();
        if (step + 1 < NSTEP) {
            int k0 = (step + 1) * 32;
#pragma unroll
            for (int j = 0; j < 2; ++j) {
                apre[j] = *reinterpret_cast<const ushort8*>(Ab + (size_t)(j * 64 + r0) * KTOT + k0 + kb);
                bpre[j] = *reinterpret_cast<const ushort8*>(Bb + (size_t)(j * 64 + r0) * KTOT + k0 + kb);
            }
        }
        bf16x8 af[4], bfr[4];
#pragma unroll
        for (int mi = 0; mi < 4; ++mi)
            af[mi] = *reinterpret_cast<const bf16x8*>(As + (wm0 + mi * 16 + (lane & 15)) * 32 + (lane >> 4) * 8);
#pragma unroll
        for (int ni = 0; ni < 4; ++ni)
            bfr[ni] = *reinterpret_cast<const bf16x8*>(Bs + (wn0 + ni * 16 + (lane & 15)) * 32 + (lane >> 4) * 8);
#pragma unroll
        for (int mi = 0; mi < 4; ++mi)
#pragma unroll
            for (int ni = 0; ni < 4; ++ni)
                acc[mi][ni] = __builtin_amdgcn_mfma_f32_16x16x32_bf16(af[mi], bfr[ni], acc[mi][ni], 0, 0, 0);
    }

    // Epilogue.  D frag: col = lane&15 (hw), row = (lane>>4)*4 + r (o).
#pragma unroll
    for (int mi = 0; mi < 4; ++mi) {
#pragma unroll
        for (int r = 0; r < 4; ++r) {
            int o = o0 + wm0 + mi * 16 + ((lane >> 4) << 2) + r;
            float bi = bias[o];
            size_t base = ((size_t)b * OTOT + o) * HWS + hw0 + wn0 + (lane & 15);
            if constexpr (BF16_OUT) {
                ushort* outp = (ushort*)outv;
#pragma unroll
                for (int ni = 0; ni < 4; ++ni)
                    outp[base + ni * 16] = f2bf(acc[mi][ni][r] + bi);
            } else {
                float* outp = (float*)outv;
#pragma unroll
                for (int ni = 0; ni < 4; ++ni) {
                    float v = acc[mi][ni][r] + bi;
                    if constexpr (ADD_SKIP) v += skip[base + ni * 16];
                    outp[base + ni * 16] = v;
                }
            }
        }
    }
}

// ---------------------------------------------------------------------------
// x [B][256][HW] f32  ->  xT [B][HW][256] bf16 (tiled transpose + cast)
// grid (HW/64, 256/64, NB), block 256.
// ---------------------------------------------------------------------------
__global__ __launch_bounds__(256) void castT_k(const float* __restrict__ x,
                                               ushort* __restrict__ xT) {
    const int b = blockIdx.z, c0 = blockIdx.y * 64, hw0 = blockIdx.x * 64;
    __shared__ float tile[64][65];
    const int tid = threadIdx.x;
#pragma unroll
    for (int r = 0; r < 16; ++r) {
        int cl = r * 4 + (tid >> 6), hwl = tid & 63;
        tile[cl][hwl] = x[((size_t)b * CINC + c0 + cl) * HWS + hw0 + hwl];
    }
    __syncthreads();
#pragma unroll
    for (int r = 0; r < 16; ++r) {
        int hwl = r * 4 + (tid >> 6), cl = tid & 63;
        xT[((size_t)b * HWS + hw0 + hwl) * CINC + c0 + cl] = f2bf(tile[cl][hwl]);
    }
}

// generic f32 -> bf16 cast (n multiple of 1024)
__global__ __launch_bounds__(256) void cast_k(const float* __restrict__ in,
                                              ushort* __restrict__ out, int n) {
    int i = (blockIdx.x * 256 + threadIdx.x) * 4;
    if (i < n) {
        float4 v = *reinterpret_cast<const float4*>(in + i);
        out[i + 0] = f2bf(v.x); out[i + 1] = f2bf(v.y);
        out[i + 2] = f2bf(v.z); out[i + 3] = f2bf(v.w);
    }
}

// ---------------------------------------------------------------------------
// Dynamic pool: f32 in -> bf16 out, per (b,c) plane
// ---------------------------------------------------------------------------
__global__ __launch_bounds__(256) void pool_k(const float* __restrict__ in,
                                              const float* __restrict__ sigma,
                                              ushort* __restrict__ out) {
    const int bc = blockIdx.x;
    const int c = bc % DPC;
    __shared__ float ex[HWS];
    const int tid = threadIdx.x;
    const float* ip = in + (size_t)bc * HWS;
    ushort* op = out + (size_t)bc * HWS;

    float s = sigma[c];
    float inv = 0.5f / (s * s + EPSF);
    float kw[25];
    float tot = 0.f;
#pragma unroll
    for (int i = 0; i < 5; ++i)
#pragma unroll
        for (int j = 0; j < 5; ++j) {
            float d2 = (float)((i - 2) * (i - 2) + (j - 2) * (j - 2));
            float v = expf(-d2 * inv);
            kw[i * 5 + j] = v; tot += v;
        }
    float rnorm = 1.f / tot;

#pragma unroll
    for (int t = 0; t < 4; ++t) {
        int idx = tid * 4 + t * 1024;
        float4 v = *reinterpret_cast<const float4*>(ip + idx);
        ex[idx + 0] = expf(fminf(v.x, EXP_CLAMP));
        ex[idx + 1] = expf(fminf(v.y, EXP_CLAMP));
        ex[idx + 2] = expf(fminf(v.z, EXP_CLAMP));
        ex[idx + 3] = expf(fminf(v.w, EXP_CLAMP));
    }
    __syncthreads();

    for (int t = 0; t < 16; ++t) {
        int p = tid + t * 256;
        int h = p >> 6, w = p & 63;
        float acc = 0.f;
        if (h >= 2 && h < 62 && w >= 2 && w < 62) {
#pragma unroll
            for (int i = 0; i < 5; ++i)
#pragma unroll
                for (int j = 0; j < 5; ++j)
                    acc = fmaf(kw[i * 5 + j], ex[(h + i - 2) * 64 + (w + j - 2)], acc);
        } else {
#pragma unroll
            for (int i = 0; i < 5; ++i) {
                int hh = h + i - 2;
                if (hh < 0 || hh >= 64) continue;
#pragma unroll
                for (int j = 0; j < 5; ++j) {
                    int ww = w + j - 2;
                    if (ww < 0 || ww >= 64) continue;
                    acc = fmaf(kw[i * 5 + j], ex[hh * 64 + ww], acc);
                }
            }
        }
        op[p] = f2bf(logf(acc * rnorm + EPSF));
    }
}

// ---------------------------------------------------------------------------
// Displace: bf16 in -> bf16 out
// ---------------------------------------------------------------------------
__global__ __launch_bounds__(256) void displace_k(const ushort* __restrict__ in,
                                                  const float* __restrict__ offsets,
                                                  ushort* __restrict__ out) {
    int i = blockIdx.x * 256 + threadIdx.x;
    int hw = i & (HWS - 1);
    int bc = i >> 12;
    int c = bc % DPC;
    int h = hw >> 6, w = hw & 63;
    int oi = c >> 3;
    float dy = offsets[oi * 2 + 0];
    float dx = offsets[oi * 2 + 1];
    float y0f = floorf(dy), x0f = floorf(dx);
    float fy = dy - y0f, fx = dx - x0f;
    int y0 = (int)y0f, x0 = (int)x0f;
    const ushort* ip = in + (size_t)bc * HWS;
    float acc = 0.f;
#pragma unroll
    for (int oy = 0; oy < 2; ++oy)
#pragma unroll
        for (int ox = 0; ox < 2; ++ox) {
            int ry = h + y0 + oy;
            int rx = w + x0 + ox;
            float wgt = (oy ? fy : 1.f - fy) * (ox ? fx : 1.f - fx);
            if (ry >= 0 && ry < 64 && rx >= 0 && rx < 64)
                acc += wgt * bf2f(ip[ry * 64 + rx]);
        }
    out[i] = f2bf(acc);
}

// ---------------------------------------------------------------------------
// BN stats over bf16 tensor [NB][CT][HWS]
// ---------------------------------------------------------------------------
template<int CT>
__global__ __launch_bounds__(256) void bnstats_bf_k(const ushort* __restrict__ a,
                                                    const float* __restrict__ gamma,
                                                    const float* __restrict__ beta,
                                                    float* __restrict__ scale,
                                                    float* __restrict__ shift) {
    const int c = blockIdx.x;
    float s = 0.f, s2 = 0.f;
    for (int b = 0; b < NB; ++b) {
        const ushort* p = a + ((size_t)b * CT + c) * HWS;
        for (int i = threadIdx.x * 8; i < HWS; i += 2048) {
            ushort8 v = *reinterpret_cast<const ushort8*>(p + i);
#pragma unroll
            for (int j = 0; j < 8; ++j) { float f = bf2f(v[j]); s += f; s2 += f * f; }
        }
    }
#pragma unroll
    for (int off = 32; off > 0; off >>= 1) {
        s += __shfl_down(s, off, 64);
        s2 += __shfl_down(s2, off, 64);
    }
    __shared__ float t1[4], t2[4];
    int lane = threadIdx.x & 63, wid = threadIdx.x >> 6;
    if (lane == 0) { t1[wid] = s; t2[wid] = s2; }
    __syncthreads();
    if (threadIdx.x == 0) {
        float S = t1[0] + t1[1] + t1[2] + t1[3];
        float S2 = t2[0] + t2[1] + t2[2] + t2[3];
        float n = (float)(NB * HWS);
        float mean = S / n;
        float var = S2 / n - mean * mean;
        float invs = rsqrtf(var + BN_EPS);
        float sc = invs * gamma[c];
        scale[c] = sc;
        shift[c] = beta[c] - mean * sc;
    }
}

// BN stats over f32 tensor (final BN on d_out)
template<int CT>
__global__ __launch_bounds__(256) void bnstats_k(const float* __restrict__ a,
                                                 const float* __restrict__ gamma,
                                                 const float* __restrict__ beta,
                                                 float* __restrict__ scale,
                                                 float* __restrict__ shift) {
    const int c = blockIdx.x;
    float s = 0.f, s2 = 0.f;
    for (int b = 0; b < NB; ++b) {
        const float* p = a + ((size_t)b * CT + c) * HWS;
        for (int i = threadIdx.x * 4; i < HWS; i += 1024) {
            float4 v = *reinterpret_cast<const float4*>(p + i);
            s += v.x + v.y + v.z + v.w;
            s2 += v.x * v.x + v.y * v.y + v.z * v.z + v.w * v.w;
        }
    }
#pragma unroll
    for (int off = 32; off > 0; off >>= 1) {
        s += __shfl_down(s, off, 64);
        s2 += __shfl_down(s2, off, 64);
    }
    __shared__ float t1[4], t2[4];
    int lane = threadIdx.x & 63, wid = threadIdx.x >> 6;
    if (lane == 0) { t1[wid] = s; t2[wid] = s2; }
    __syncthreads();
    if (threadIdx.x == 0) {
        float S = t1[0] + t1[1] + t1[2] + t1[3];
        float S2 = t2[0] + t2[1] + t2[2] + t2[3];
        float n = (float)(NB * HWS);
        float mean = S / n;
        float var = S2 / n - mean * mean;
        float invs = rsqrtf(var + BN_EPS);
        float sc = invs * gamma[c];
        scale[c] = sc;
        shift[c] = beta[c] - mean * sc;
    }
}

// ---------------------------------------------------------------------------
// Spatial softplus sums per (b,c) on bf16 att
// ---------------------------------------------------------------------------
__global__ __launch_bounds__(256) void ssum_k(const ushort* __restrict__ a,
                                              const float* __restrict__ scale,
                                              const float* __restrict__ shift,
                                              float* __restrict__ ssum) {
    const int bc = blockIdx.x;
    const int c = bc % DPC;
    float sc = scale[c], sh = shift[c];
    const ushort* p = a + (size_t)bc * HWS;
    float s = 0.f;
    for (int i = threadIdx.x * 8; i < HWS; i += 2048) {
        ushort8 v = *reinterpret_cast<const ushort8*>(p + i);
#pragma unroll
        for (int j = 0; j < 8; ++j) s += softplusf(bf2f(v[j]) * sc + sh);
    }
#pragma unroll
    for (int off = 32; off > 0; off >>= 1) s += __shfl_down(s, off, 64);
    __shared__ float t1[4];
    int lane = threadIdx.x & 63, wid = threadIdx.x >> 6;
    if (lane == 0) t1[wid] = s;
    __syncthreads();
    if (threadIdx.x == 0) ssum[bc] = t1[0] + t1[1] + t1[2] + t1[3];
}

// ---------------------------------------------------------------------------
// m = softplus(bn(att))/ssum * disp, written TRANSPOSED as mT[b][hw][512] bf16
// grid (HW/64, 512/64, NB), block 256.
// ---------------------------------------------------------------------------
__global__ __launch_bounds__(256) void attmulT_k(const ushort* __restrict__ att,
                                                 const ushort* __restrict__ disp,
                                                 const float* __restrict__ scale,
                                                 const float* __restrict__ shift,
                                                 const float* __restrict__ ssum,
                                                 ushort* __restrict__ mT) {
    const int b = blockIdx.z, c0 = blockIdx.y * 64, hw0 = blockIdx.x * 64;
    __shared__ float tile[64][65];
    const int tid = threadIdx.x;
#pragma unroll
    for (int r = 0; r < 16; ++r) {
        int cl = r * 4 + (tid >> 6), hwl = tid & 63;
        int c = c0 + cl;
        size_t idx = ((size_t)b * DPC + c) * HWS + hw0 + hwl;
        float a = bf2f(att[idx]) * scale[c] + shift[c];
        float m = softplusf(a) / ssum[b * DPC + c] * bf2f(disp[idx]);
        tile[cl][hwl] = m;
    }
    __syncthreads();
#pragma unroll
    for (int r = 0; r < 16; ++r) {
        int hwl = r * 4 + (tid >> 6), cl = tid & 63;
        mT[((size_t)b * HWS + hw0 + hwl) * DPC + c0 + cl] = f2bf(tile[cl][hwl]);
    }
}

// Final: out = relu(out*scale + shift) in place
__global__ __launch_bounds__(256) void final_k(float* __restrict__ out,
                                               const float* __restrict__ scale,
                                               const float* __restrict__ shift) {
    int i = blockIdx.x * 256 + threadIdx.x;
    int c = (i >> 12) & (COUTC - 1);
    float v = out[i] * scale[c] + shift[c];
    out[i] = fmaxf(v, 0.f);
}

extern "C" void kernel_launch(void* const* d_in, const int* in_sizes, int n_in,
                              void* d_out, int out_size, void* d_ws, size_t ws_size,
                              hipStream_t stream) {
    const float* x           = (const float*)d_in[0];
    const float* pre_w       = (const float*)d_in[1];
    const float* pre_b       = (const float*)d_in[2];
    const float* sigma       = (const float*)d_in[3];
    const float* offsets     = (const float*)d_in[4];
    const float* atten_w     = (const float*)d_in[5];
    const float* atten_b     = (const float*)d_in[6];
    const float* atten_gamma = (const float*)d_in[7];
    const float* atten_beta  = (const float*)d_in[8];
    const float* post_w      = (const float*)d_in[9];
    const float* post_b      = (const float*)d_in[10];
    const float* bn_gamma    = (const float*)d_in[11];
    const float* bn_beta     = (const float*)d_in[12];
    float* out = (float*)d_out;

    // Workspace layout (byte offsets, MiB).  Peak use 226 MiB <= 256 MiB.
    char* wsb = (char*)d_ws;
    ushort* xT    = (ushort*)(wsb);                         // [0,32)   bf16 x^T
    ushort* wb    = (ushort*)(wsb + ((size_t)32 << 20));    // [32,33)  bf16 weights
    float*  stats = (float*)(wsb + ((size_t)33 << 20));     // [33,34)
    float*  pre   = (float*)(wsb + ((size_t)34 << 20));     // [34,162) f32 pre_out
    ushort* pool  = (ushort*)(wsb + ((size_t)162 << 20));   // [162,226) bf16
    ushort* disp  = (ushort*)(wsb + ((size_t)34 << 20));    // [34,98)  reuse pre
    ushort* att   = (ushort*)(wsb + ((size_t)98 << 20));    // [98,162) reuse pre
    ushort* mT    = (ushort*)(wsb + ((size_t)162 << 20));   // [162,226) reuse pool

    ushort* wb_pre  = wb;
    ushort* wb_att  = wb + 131072;
    ushort* wb_post = wb + 262144;
    float* scaleA = stats;          // 512
    float* shiftA = stats + 512;    // 512
    float* ssum   = stats + 1024;   // 8192
    float* scale2 = stats + 9216;   // 256
    float* shift2 = stats + 9472;   // 256

    // 0. casts / transposes
    castT_k<<<dim3(64, 4, NB), 256, 0, stream>>>(x, xT);
    cast_k<<<128, 256, 0, stream>>>(pre_w,   wb_pre,  DPC * CINC);
    cast_k<<<128, 256, 0, stream>>>(atten_w, wb_att,  DPC * CINC);
    cast_k<<<128, 256, 0, stream>>>(post_w,  wb_post, COUTC * DPC);

    // 1. pre conv1x1 (MFMA) -> pre (f32)
    mfma_gemm_k<DPC, CINC, false, false><<<dim3(32, 4, NB), 256, 0, stream>>>(
        wb_pre, xT, pre_b, nullptr, pre);
    // 2. dynamic pool -> pool (bf16)
    pool_k<<<NB * DPC, 256, 0, stream>>>(pre, sigma, pool);
    // 3. displace -> disp (bf16)
    displace_k<<<(NB * DPC * HWS) / 256, 256, 0, stream>>>(pool, offsets, disp);
    // 4. atten conv1x1 (MFMA) -> att (bf16)
    mfma_gemm_k<DPC, CINC, true, false><<<dim3(32, 4, NB), 256, 0, stream>>>(
        wb_att, xT, atten_b, nullptr, att);
    // 5. BN stats (atten)
    bnstats_bf_k<DPC><<<DPC, 256, 0, stream>>>(att, atten_gamma, atten_beta, scaleA, shiftA);
    // 6. spatial softplus sums
    ssum_k<<<NB * DPC, 256, 0, stream>>>(att, scaleA, shiftA, ssum);
    // 7. m = atten*disp, transposed -> mT (bf16, K-major)
    attmulT_k<<<dim3(64, 8, NB), 256, 0, stream>>>(att, disp, scaleA, shiftA, ssum, mT);
    // 8. post conv1x1 (MFMA) + skip -> out (f32)
    mfma_gemm_k<COUTC, DPC, false, true><<<dim3(32, 2, NB), 256, 0, stream>>>(
        wb_post, mT, post_b, x, out);
    // 9. final BN stats
    bnstats_k<COUTC><<<COUTC, 256, 0, stream>>>(out, bn_gamma, bn_beta, scale2, shift2);
    // 10. relu(bn) in place
    final_k<<<out_size / 256, 256, 0, stream>>>(out, scale2, shift2);
}

// Round 4
// 385.229 us; speedup vs baseline: 2.8549x; 1.7199x over previous
//
#include <hip/hip_runtime.h>
#include <cmath>

#define NB   16
#define CINC 256
#define DPC  512
#define COUTC 256
#define HWS  4096
#define EPSF 1.1920928955078125e-07f
#define BN_EPS 1e-5f
#define EXP_CLAMP 88.722835f

typedef unsigned int uint32;
typedef unsigned short ushort;
typedef __bf16 bf16x8 __attribute__((ext_vector_type(8)));
typedef float f32x4 __attribute__((ext_vector_type(4)));
typedef unsigned short ushort8 __attribute__((ext_vector_type(8)));

__device__ inline ushort f2bf(float f) {          // RNE float->bf16
    uint32 u = __builtin_bit_cast(uint32, f);
    u += 0x7fffu + ((u >> 16) & 1u);
    return (ushort)(u >> 16);
}
__device__ inline float bf2f(ushort u) {
    return __builtin_bit_cast(float, (uint32)u << 16);
}
__device__ inline float softplus_fast(float v) {
    return fmaxf(v, 0.f) + __logf(1.f + __expf(-fabsf(v)));
}

// ---------------------------------------------------------------------------
// MFMA bf16 GEMM: out[b][o][hw] = bias[o] + sum_k A[o][k] * BT[b][hw][k]
// A: [OTOT][KTOT] bf16 row-major.  BT: [NB][HWS][KTOT] bf16 (K-major).
// 128x128 tile, BK=32, 4 waves.  grid (HWS/128, OTOT/128, NB), block 256.
// ---------------------------------------------------------------------------
template<int OTOT, int KTOT, bool BF16_OUT, bool ADD_SKIP>
__global__ __launch_bounds__(256) void mfma_gemm_k(
    const ushort* __restrict__ A, const ushort* __restrict__ BT,
    const float* __restrict__ bias, const float* __restrict__ skip,
    void* __restrict__ outv) {
    const int hw0 = blockIdx.x * 128;
    const int o0  = blockIdx.y * 128;
    const int b   = blockIdx.z;
    __shared__ ushort As[128 * 32];
    __shared__ ushort Bs[128 * 32];
    const int tid  = threadIdx.x;
    const int lane = tid & 63;
    const int w    = tid >> 6;
    const int wm0  = (w >> 1) * 64;
    const int wn0  = (w & 1) * 64;

    f32x4 acc[4][4] = {};

    const ushort* Ab = A + (size_t)o0 * KTOT;
    const ushort* Bb = BT + ((size_t)b * HWS + hw0) * KTOT;
    const int r0 = tid >> 2;        // 0..63
    const int kb = (tid & 3) * 8;   // ushort offset in 32-wide K slab

    ushort8 apre[2], bpre[2];
#pragma unroll
    for (int j = 0; j < 2; ++j) {
        apre[j] = *reinterpret_cast<const ushort8*>(Ab + (size_t)(j * 64 + r0) * KTOT + kb);
        bpre[j] = *reinterpret_cast<const ushort8*>(Bb + (size_t)(j * 64 + r0) * KTOT + kb);
    }

    constexpr int NSTEP = KTOT / 32;
    for (int step = 0; step < NSTEP; ++step) {
        __syncthreads();
#pragma unroll
        for (int j = 0; j < 2; ++j) {
            *reinterpret_cast<ushort8*>(As + j * 2048 + tid * 8) = apre[j];
            *reinterpret_cast<ushort8*>(Bs + j * 2048 + tid * 8) = bpre[j];
        }
        __syncthreads();
        if (step + 1 < NSTEP) {
            int k0 = (step + 1) * 32;
#pragma unroll
            for (int j = 0; j < 2; ++j) {
                apre[j] = *reinterpret_cast<const ushort8*>(Ab + (size_t)(j * 64 + r0) * KTOT + k0 + kb);
                bpre[j] = *reinterpret_cast<const ushort8*>(Bb + (size_t)(j * 64 + r0) * KTOT + k0 + kb);
            }
        }
        bf16x8 af[4], bfr[4];
#pragma unroll
        for (int mi = 0; mi < 4; ++mi)
            af[mi] = *reinterpret_cast<const bf16x8*>(As + (wm0 + mi * 16 + (lane & 15)) * 32 + (lane >> 4) * 8);
#pragma unroll
        for (int ni = 0; ni < 4; ++ni)
            bfr[ni] = *reinterpret_cast<const bf16x8*>(Bs + (wn0 + ni * 16 + (lane & 15)) * 32 + (lane >> 4) * 8);
#pragma unroll
        for (int mi = 0; mi < 4; ++mi)
#pragma unroll
            for (int ni = 0; ni < 4; ++ni)
                acc[mi][ni] = __builtin_amdgcn_mfma_f32_16x16x32_bf16(af[mi], bfr[ni], acc[mi][ni], 0, 0, 0);
    }

    // D frag: col = lane&15 (hw), row = (lane>>4)*4 + r (o).
#pragma unroll
    for (int mi = 0; mi < 4; ++mi) {
#pragma unroll
        for (int r = 0; r < 4; ++r) {
            int o = o0 + wm0 + mi * 16 + ((lane >> 4) << 2) + r;
            float bi = bias[o];
            size_t base = ((size_t)b * OTOT + o) * HWS + hw0 + wn0 + (lane & 15);
            if constexpr (BF16_OUT) {
                ushort* outp = (ushort*)outv;
#pragma unroll
                for (int ni = 0; ni < 4; ++ni)
                    outp[base + ni * 16] = f2bf(acc[mi][ni][r] + bi);
            } else {
                float* outp = (float*)outv;
#pragma unroll
                for (int ni = 0; ni < 4; ++ni) {
                    float v = acc[mi][ni][r] + bi;
                    if constexpr (ADD_SKIP) v += skip[base + ni * 16];
                    outp[base + ni * 16] = v;
                }
            }
        }
    }
}

// ---------------------------------------------------------------------------
// x [B][256][HW] f32  ->  xT [B][HW][256] bf16
// ---------------------------------------------------------------------------
__global__ __launch_bounds__(256) void castT_k(const float* __restrict__ x,
                                               ushort* __restrict__ xT) {
    const int b = blockIdx.z, c0 = blockIdx.y * 64, hw0 = blockIdx.x * 64;
    __shared__ float tile[64][65];
    const int tid = threadIdx.x;
#pragma unroll
    for (int r = 0; r < 16; ++r) {
        int cl = r * 4 + (tid >> 6), hwl = tid & 63;
        tile[cl][hwl] = x[((size_t)b * CINC + c0 + cl) * HWS + hw0 + hwl];
    }
    __syncthreads();
#pragma unroll
    for (int r = 0; r < 16; ++r) {
        int hwl = r * 4 + (tid >> 6), cl = tid & 63;
        xT[((size_t)b * HWS + hw0 + hwl) * CINC + c0 + cl] = f2bf(tile[cl][hwl]);
    }
}

// generic f32 -> bf16 cast
__global__ __launch_bounds__(256) void cast_k(const float* __restrict__ in,
                                              ushort* __restrict__ out, int n) {
    int i = (blockIdx.x * 256 + threadIdx.x) * 4;
    if (i < n) {
        float4 v = *reinterpret_cast<const float4*>(in + i);
        out[i + 0] = f2bf(v.x); out[i + 1] = f2bf(v.y);
        out[i + 2] = f2bf(v.z); out[i + 3] = f2bf(v.w);
    }
}

// ---------------------------------------------------------------------------
// FUSED dynamic_pool + displace, one block per (b,c) plane, bf16 in/out.
// Separable 5x5 Gaussian: row pass then col pass in LDS; bilinear shift
// applied straight from the LDS log-plane.
// ---------------------------------------------------------------------------
__global__ __launch_bounds__(256) void pooldisp_k(const ushort* __restrict__ in,
                                                  const float* __restrict__ sigma,
                                                  const float* __restrict__ offsets,
                                                  ushort* __restrict__ out) {
    const int bc = blockIdx.x;
    const int c = bc % DPC;
    __shared__ float ex[68 * 68];    // padded exp plane; later reused as pl[64][68]
    __shared__ float tmp[68 * 68];   // row-pass intermediate (stride 68, cols 0..63 used)
    const int tid = threadIdx.x;
    const ushort* ip = in + (size_t)bc * HWS;
    ushort* op = out + (size_t)bc * HWS;

    float s = sigma[c];
    float inv = 0.5f / (s * s + EPSF);
    float g0 = __expf(-4.f * inv), g1 = __expf(-1.f * inv), g2 = 1.f;
    float gs = g0 + g1 + g2 + g1 + g0;
    float rnorm = 1.f / (gs * gs);

    // zero-pad ex
    for (int i = tid; i < 68 * 68; i += 256) ex[i] = 0.f;
    __syncthreads();

    // stage exp(min(x,clamp)) into interior
#pragma unroll
    for (int t = 0; t < 2; ++t) {
        int p = (tid + t * 256) * 8;
        int h = p >> 6, w = p & 63;
        ushort8 v = *reinterpret_cast<const ushort8*>(ip + p);
        float* er = &ex[(h + 2) * 68 + (w + 2)];
#pragma unroll
        for (int q = 0; q < 8; ++q)
            er[q] = __expf(fminf(bf2f(v[q]), EXP_CLAMP));
    }
    __syncthreads();

    // row pass: tmp[r][w] = sum_j g[j] * ex[r][w+j], r in 0..67, w in 0..63
#pragma unroll
    for (int t = 0; t < 5; ++t) {
        int task = tid + t * 256;
        if (task < 1088) {
            int r = task >> 4, wq = (task & 15) * 4;
            float4 e0 = *reinterpret_cast<const float4*>(&ex[r * 68 + wq]);
            float4 e1 = *reinterpret_cast<const float4*>(&ex[r * 68 + wq + 4]);
            float e[8] = {e0.x, e0.y, e0.z, e0.w, e1.x, e1.y, e1.z, e1.w};
            float4 o;
            o.x = g0 * (e[0] + e[4]) + g1 * (e[1] + e[3]) + e[2];
            o.y = g0 * (e[1] + e[5]) + g1 * (e[2] + e[4]) + e[3];
            o.z = g0 * (e[2] + e[6]) + g1 * (e[3] + e[5]) + e[4];
            o.w = g0 * (e[3] + e[7]) + g1 * (e[4] + e[6]) + e[5];
            *reinterpret_cast<float4*>(&tmp[r * 68 + wq]) = o;
        }
    }
    __syncthreads();

    // col pass + log -> pl (reuse ex storage, stride 68)
    float* pl = ex;
#pragma unroll
    for (int t = 0; t < 4; ++t) {
        int task = tid + t * 256;
        int h = task >> 4, wq = (task & 15) * 4;
        float4 t0 = *reinterpret_cast<const float4*>(&tmp[(h + 0) * 68 + wq]);
        float4 t1 = *reinterpret_cast<const float4*>(&tmp[(h + 1) * 68 + wq]);
        float4 t2 = *reinterpret_cast<const float4*>(&tmp[(h + 2) * 68 + wq]);
        float4 t3 = *reinterpret_cast<const float4*>(&tmp[(h + 3) * 68 + wq]);
        float4 t4 = *reinterpret_cast<const float4*>(&tmp[(h + 4) * 68 + wq]);
        float4 o;
        o.x = g0 * (t0.x + t4.x) + g1 * (t1.x + t3.x) + t2.x;
        o.y = g0 * (t0.y + t4.y) + g1 * (t1.y + t3.y) + t2.y;
        o.z = g0 * (t0.z + t4.z) + g1 * (t1.z + t3.z) + t2.z;
        o.w = g0 * (t0.w + t4.w) + g1 * (t1.w + t3.w) + t2.w;
        float4 r;
        r.x = __logf(o.x * rnorm + EPSF);
        r.y = __logf(o.y * rnorm + EPSF);
        r.z = __logf(o.z * rnorm + EPSF);
        r.w = __logf(o.w * rnorm + EPSF);
        *reinterpret_cast<float4*>(&pl[h * 68 + wq]) = r;
    }
    __syncthreads();

    // displace: bilinear shift of pl with zero padding, write bf16
    int oi = c >> 3;
    float dy = offsets[oi * 2 + 0];
    float dx = offsets[oi * 2 + 1];
    float y0f = floorf(dy), x0f = floorf(dx);
    float fy = dy - y0f, fx = dx - x0f;
    int y0 = (int)y0f, x0 = (int)x0f;
    float w00 = (1.f - fy) * (1.f - fx), w01 = (1.f - fy) * fx;
    float w10 = fy * (1.f - fx),         w11 = fy * fx;
#pragma unroll
    for (int t = 0; t < 2; ++t) {
        int p = (tid + t * 256) * 8;
        int h = p >> 6, w = p & 63;
        int ry0 = h + y0, ry1 = ry0 + 1;
        bool my0 = (ry0 >= 0) & (ry0 < 64);
        bool my1 = (ry1 >= 0) & (ry1 < 64);
        ushort8 ov;
#pragma unroll
        for (int q = 0; q < 8; ++q) {
            int rx0 = w + q + x0, rx1 = rx0 + 1;
            bool mx0 = (rx0 >= 0) & (rx0 < 64);
            bool mx1 = (rx1 >= 0) & (rx1 < 64);
            float acc = 0.f;
            if (my0 & mx0) acc += w00 * pl[ry0 * 68 + rx0];
            if (my0 & mx1) acc += w01 * pl[ry0 * 68 + rx1];
            if (my1 & mx0) acc += w10 * pl[ry1 * 68 + rx0];
            if (my1 & mx1) acc += w11 * pl[ry1 * 68 + rx1];
            ov[q] = f2bf(acc);
        }
        *reinterpret_cast<ushort8*>(op + p) = ov;
    }
}

// ---------------------------------------------------------------------------
// BN stats over bf16 tensor [NB][CT][HWS]
// ---------------------------------------------------------------------------
template<int CT>
__global__ __launch_bounds__(256) void bnstats_bf_k(const ushort* __restrict__ a,
                                                    const float* __restrict__ gamma,
                                                    const float* __restrict__ beta,
                                                    float* __restrict__ scale,
                                                    float* __restrict__ shift) {
    const int c = blockIdx.x;
    float s = 0.f, s2 = 0.f;
    for (int b = 0; b < NB; ++b) {
        const ushort* p = a + ((size_t)b * CT + c) * HWS;
        for (int i = threadIdx.x * 8; i < HWS; i += 2048) {
            ushort8 v = *reinterpret_cast<const ushort8*>(p + i);
#pragma unroll
            for (int j = 0; j < 8; ++j) { float f = bf2f(v[j]); s += f; s2 += f * f; }
        }
    }
#pragma unroll
    for (int off = 32; off > 0; off >>= 1) {
        s += __shfl_down(s, off, 64);
        s2 += __shfl_down(s2, off, 64);
    }
    __shared__ float t1[4], t2[4];
    int lane = threadIdx.x & 63, wid = threadIdx.x >> 6;
    if (lane == 0) { t1[wid] = s; t2[wid] = s2; }
    __syncthreads();
    if (threadIdx.x == 0) {
        float S = t1[0] + t1[1] + t1[2] + t1[3];
        float S2 = t2[0] + t2[1] + t2[2] + t2[3];
        float n = (float)(NB * HWS);
        float mean = S / n;
        float var = S2 / n - mean * mean;
        float invs = rsqrtf(var + BN_EPS);
        float sc = invs * gamma[c];
        scale[c] = sc;
        shift[c] = beta[c] - mean * sc;
    }
}

// BN stats over f32 tensor (final BN on d_out)
template<int CT>
__global__ __launch_bounds__(256) void bnstats_k(const float* __restrict__ a,
                                                 const float* __restrict__ gamma,
                                                 const float* __restrict__ beta,
                                                 float* __restrict__ scale,
                                                 float* __restrict__ shift) {
    const int c = blockIdx.x;
    float s = 0.f, s2 = 0.f;
    for (int b = 0; b < NB; ++b) {
        const float* p = a + ((size_t)b * CT + c) * HWS;
        for (int i = threadIdx.x * 4; i < HWS; i += 1024) {
            float4 v = *reinterpret_cast<const float4*>(p + i);
            s += v.x + v.y + v.z + v.w;
            s2 += v.x * v.x + v.y * v.y + v.z * v.z + v.w * v.w;
        }
    }
#pragma unroll
    for (int off = 32; off > 0; off >>= 1) {
        s += __shfl_down(s, off, 64);
        s2 += __shfl_down(s2, off, 64);
    }
    __shared__ float t1[4], t2[4];
    int lane = threadIdx.x & 63, wid = threadIdx.x >> 6;
    if (lane == 0) { t1[wid] = s; t2[wid] = s2; }
    __syncthreads();
    if (threadIdx.x == 0) {
        float S = t1[0] + t1[1] + t1[2] + t1[3];
        float S2 = t2[0] + t2[1] + t2[2] + t2[3];
        float n = (float)(NB * HWS);
        float mean = S / n;
        float var = S2 / n - mean * mean;
        float invs = rsqrtf(var + BN_EPS);
        float sc = invs * gamma[c];
        scale[c] = sc;
        shift[c] = beta[c] - mean * sc;
    }
}

// ---------------------------------------------------------------------------
// Spatial softplus sums per (b,c) on bf16 att
// ---------------------------------------------------------------------------
__global__ __launch_bounds__(256) void ssum_k(const ushort* __restrict__ a,
                                              const float* __restrict__ scale,
                                              const float* __restrict__ shift,
                                              float* __restrict__ ssum) {
    const int bc = blockIdx.x;
    const int c = bc % DPC;
    float sc = scale[c], sh = shift[c];
    const ushort* p = a + (size_t)bc * HWS;
    float s = 0.f;
    for (int i = threadIdx.x * 8; i < HWS; i += 2048) {
        ushort8 v = *reinterpret_cast<const ushort8*>(p + i);
#pragma unroll
        for (int j = 0; j < 8; ++j) s += softplus_fast(bf2f(v[j]) * sc + sh);
    }
#pragma unroll
    for (int off = 32; off > 0; off >>= 1) s += __shfl_down(s, off, 64);
    __shared__ float t1[4];
    int lane = threadIdx.x & 63, wid = threadIdx.x >> 6;
    if (lane == 0) t1[wid] = s;
    __syncthreads();
    if (threadIdx.x == 0) ssum[bc] = t1[0] + t1[1] + t1[2] + t1[3];
}

// ---------------------------------------------------------------------------
// m = softplus(bn(att))/ssum * disp, written TRANSPOSED as mT[b][hw][512] bf16
// ---------------------------------------------------------------------------
__global__ __launch_bounds__(256) void attmulT_k(const ushort* __restrict__ att,
                                                 const ushort* __restrict__ disp,
                                                 const float* __restrict__ scale,
                                                 const float* __restrict__ shift,
                                                 const float* __restrict__ ssum,
                                                 ushort* __restrict__ mT) {
    const int b = blockIdx.z, c0 = blockIdx.y * 64, hw0 = blockIdx.x * 64;
    __shared__ float tile[64][65];
    const int tid = threadIdx.x;
#pragma unroll
    for (int r = 0; r < 16; ++r) {
        int cl = r * 4 + (tid >> 6), hwl = tid & 63;
        int c = c0 + cl;
        size_t idx = ((size_t)b * DPC + c) * HWS + hw0 + hwl;
        float a = bf2f(att[idx]) * scale[c] + shift[c];
        float m = softplus_fast(a) / ssum[b * DPC + c] * bf2f(disp[idx]);
        tile[cl][hwl] = m;
    }
    __syncthreads();
#pragma unroll
    for (int r = 0; r < 16; ++r) {
        int hwl = r * 4 + (tid >> 6), cl = tid & 63;
        mT[((size_t)b * HWS + hw0 + hwl) * DPC + c0 + cl] = f2bf(tile[cl][hwl]);
    }
}

// Final: out = relu(out*scale + shift) in place
__global__ __launch_bounds__(256) void final_k(float* __restrict__ out,
                                               const float* __restrict__ scale,
                                               const float* __restrict__ shift) {
    int i = blockIdx.x * 256 + threadIdx.x;
    int c = (i >> 12) & (COUTC - 1);
    float v = out[i] * scale[c] + shift[c];
    out[i] = fmaxf(v, 0.f);
}

extern "C" void kernel_launch(void* const* d_in, const int* in_sizes, int n_in,
                              void* d_out, int out_size, void* d_ws, size_t ws_size,
                              hipStream_t stream) {
    const float* x           = (const float*)d_in[0];
    const float* pre_w       = (const float*)d_in[1];
    const float* pre_b       = (const float*)d_in[2];
    const float* sigma       = (const float*)d_in[3];
    const float* offsets     = (const float*)d_in[4];
    const float* atten_w     = (const float*)d_in[5];
    const float* atten_b     = (const float*)d_in[6];
    const float* atten_gamma = (const float*)d_in[7];
    const float* atten_beta  = (const float*)d_in[8];
    const float* post_w      = (const float*)d_in[9];
    const float* post_b      = (const float*)d_in[10];
    const float* bn_gamma    = (const float*)d_in[11];
    const float* bn_beta     = (const float*)d_in[12];
    float* out = (float*)d_out;

    // Workspace layout (MiB offsets).  Peak 226 MiB.
    char* wsb = (char*)d_ws;
    ushort* xT    = (ushort*)(wsb);                         // [0,32)
    ushort* wb    = (ushort*)(wsb + ((size_t)32 << 20));    // [32,33)
    float*  stats = (float*)(wsb + ((size_t)33 << 20));     // [33,34)
    ushort* pre   = (ushort*)(wsb + ((size_t)34 << 20));    // [34,98)  bf16 pre_out
    ushort* disp  = (ushort*)(wsb + ((size_t)98 << 20));    // [98,162)
    ushort* att   = (ushort*)(wsb + ((size_t)162 << 20));   // [162,226)
    ushort* mT    = (ushort*)(wsb + ((size_t)34 << 20));    // [34,98)  reuse pre

    ushort* wb_pre  = wb;
    ushort* wb_att  = wb + 131072;
    ushort* wb_post = wb + 262144;
    float* scaleA = stats;          // 512
    float* shiftA = stats + 512;    // 512
    float* ssum   = stats + 1024;   // 8192
    float* scale2 = stats + 9216;   // 256
    float* shift2 = stats + 9472;   // 256

    // 0. casts / transposes
    castT_k<<<dim3(64, 4, NB), 256, 0, stream>>>(x, xT);
    cast_k<<<128, 256, 0, stream>>>(pre_w,   wb_pre,  DPC * CINC);
    cast_k<<<128, 256, 0, stream>>>(atten_w, wb_att,  DPC * CINC);
    cast_k<<<128, 256, 0, stream>>>(post_w,  wb_post, COUTC * DPC);

    // 1. pre conv1x1 (MFMA) -> pre (bf16)
    mfma_gemm_k<DPC, CINC, true, false><<<dim3(32, 4, NB), 256, 0, stream>>>(
        wb_pre, xT, pre_b, nullptr, pre);
    // 2+3. fused dynamic pool + displace -> disp (bf16)
    pooldisp_k<<<NB * DPC, 256, 0, stream>>>(pre, sigma, offsets, disp);
    // 4. atten conv1x1 (MFMA) -> att (bf16)
    mfma_gemm_k<DPC, CINC, true, false><<<dim3(32, 4, NB), 256, 0, stream>>>(
        wb_att, xT, atten_b, nullptr, att);
    // 5. BN stats (atten)
    bnstats_bf_k<DPC><<<DPC, 256, 0, stream>>>(att, atten_gamma, atten_beta, scaleA, shiftA);
    // 6. spatial softplus sums
    ssum_k<<<NB * DPC, 256, 0, stream>>>(att, scaleA, shiftA, ssum);
    // 7. m = atten*disp, transposed -> mT (bf16, K-major; overwrites dead pre)
    attmulT_k<<<dim3(64, 8, NB), 256, 0, stream>>>(att, disp, scaleA, shiftA, ssum, mT);
    // 8. post conv1x1 (MFMA) + skip -> out (f32)
    mfma_gemm_k<COUTC, DPC, false, true><<<dim3(32, 2, NB), 256, 0, stream>>>(
        wb_post, mT, post_b, x, out);
    // 9. final BN stats
    bnstats_k<COUTC><<<COUTC, 256, 0, stream>>>(out, bn_gamma, bn_beta, scale2, shift2);
    // 10. relu(bn) in place
    final_k<<<out_size / 256, 256, 0, stream>>>(out, scale2, shift2);
}

// Round 6
// 382.647 us; speedup vs baseline: 2.8742x; 1.0067x over previous
//
#include <hip/hip_runtime.h>
#include <cmath>

#define NB   16
#define CINC 256
#define DPC  512
#define COUTC 256
#define HWS  4096
#define EPSF 1.1920928955078125e-07f
#define BN_EPS 1e-5f
#define EXP_CLAMP 88.722835f

typedef unsigned int uint32;
typedef unsigned short ushort;
typedef __bf16 bf16x8 __attribute__((ext_vector_type(8)));
typedef float f32x4 __attribute__((ext_vector_type(4)));
typedef unsigned short ushort8 __attribute__((ext_vector_type(8)));

__device__ inline ushort f2bf(float f) {          // RNE float->bf16
    uint32 u = __builtin_bit_cast(uint32, f);
    u += 0x7fffu + ((u >> 16) & 1u);
    return (ushort)(u >> 16);
}
__device__ inline float bf2f(ushort u) {
    return __builtin_bit_cast(float, (uint32)u << 16);
}
__device__ inline float softplus_fast(float v) {
    return fmaxf(v, 0.f) + __logf(1.f + __expf(-fabsf(v)));
}
__device__ __forceinline__ void gload16(const void* g, void* l) {
    // async global->LDS, 16B per lane; LDS dest = wave-uniform base + lane*16
    __builtin_amdgcn_global_load_lds(
        (__attribute__((address_space(1))) void*)g,
        (__attribute__((address_space(3))) void*)l, 16, 0, 0);
}

// ---------------------------------------------------------------------------
// MFMA bf16 GEMM, m97-style global_load_lds staging, bank-conflict-free via
// source-side slot permutation (slot ^= (row>>1)&3, involution per 64B row).
// out[b][o][hw] = bias[o] + sum_k A[o][k] * BT[b][hw][k]  (+skip)
// A: [OTOT][KTOT] bf16.  BT: [NB][HWS][KTOT] bf16 (K-major).
// 128x128 tile, BK=32, 4 waves.  grid (HWS/128, OTOT/128, NB), block 256.
// ---------------------------------------------------------------------------
template<int OTOT, int KTOT, bool BF16_OUT, bool ADD_SKIP>
__global__ __launch_bounds__(256) void mfma_gemm_k(
    const ushort* __restrict__ A, const ushort* __restrict__ BT,
    const float* __restrict__ bias1, const float* __restrict__ bias2,
    const float* __restrict__ skip, void* __restrict__ outv) {
    const int hw0 = blockIdx.x * 128;
    const int o0  = blockIdx.y * 128;
    const int b   = blockIdx.z;
    __shared__ ushort As[128 * 32];
    __shared__ ushort Bs[128 * 32];
    const int tid  = threadIdx.x;
    const int lane = tid & 63;
    const int w    = tid >> 6;
    const int wm0  = (w >> 1) * 64;
    const int wn0  = (w & 1) * 64;

    f32x4 acc[4][4] = {};

    const ushort* Ab = A + (size_t)o0 * KTOT;
    const ushort* Bb = BT + ((size_t)b * HWS + hw0) * KTOT;
    // staging geometry: issue (w,i) covers rows w*32+i*16 .. +15 of the tile;
    // lane l -> row += (l>>2), phys slot l&3; SOURCE k-slot permuted so the
    // swizzled ds_read below is conflict-free while LDS dest stays linear.
    const int rsub  = lane >> 2;                               // 0..15
    const int ksubp = ((lane & 3) ^ ((lane >> 3) & 3)) * 8;    // permuted k slot
    // NOTE: (lane>>3)&3 == (row_within_issue>>1)&3 since row_within_issue = lane>>2.

    for (int step = 0; step < KTOT / 32; ++step) {
        const int k0 = step * 32;
#pragma unroll
        for (int i = 0; i < 2; ++i) {
            const int row = w * 32 + i * 16 + rsub;
            gload16(Ab + (size_t)row * KTOT + k0 + ksubp, &As[(w * 32 + i * 16) * 32]);
            gload16(Bb + (size_t)row * KTOT + k0 + ksubp, &Bs[(w * 32 + i * 16) * 32]);
        }
        __syncthreads();   // drains vmcnt, staging complete
        bf16x8 af[4], bfr[4];
#pragma unroll
        for (int mi = 0; mi < 4; ++mi) {
            int row = wm0 + mi * 16 + (lane & 15);
            int sl = (lane >> 4) ^ ((row >> 1) & 3);
            af[mi] = *reinterpret_cast<const bf16x8*>(As + row * 32 + sl * 8);
        }
#pragma unroll
        for (int ni = 0; ni < 4; ++ni) {
            int row = wn0 + ni * 16 + (lane & 15);
            int sl = (lane >> 4) ^ ((row >> 1) & 3);
            bfr[ni] = *reinterpret_cast<const bf16x8*>(Bs + row * 32 + sl * 8);
        }
#pragma unroll
        for (int mi = 0; mi < 4; ++mi)
#pragma unroll
            for (int ni = 0; ni < 4; ++ni)
                acc[mi][ni] = __builtin_amdgcn_mfma_f32_16x16x32_bf16(af[mi], bfr[ni], acc[mi][ni], 0, 0, 0);
        __syncthreads();   // LDS safe to overwrite
    }

    // D frag: col = lane&15 (hw), row = (lane>>4)*4 + r (o).
#pragma unroll
    for (int mi = 0; mi < 4; ++mi) {
#pragma unroll
        for (int r = 0; r < 4; ++r) {
            int o = o0 + wm0 + mi * 16 + ((lane >> 4) << 2) + r;
            float bi = (o < 512) ? bias1[o] : bias2[o - 512];
            size_t base = ((size_t)b * OTOT + o) * HWS + hw0 + wn0 + (lane & 15);
            if constexpr (BF16_OUT) {
                ushort* outp = (ushort*)outv;
#pragma unroll
                for (int ni = 0; ni < 4; ++ni)
                    outp[base + ni * 16] = f2bf(acc[mi][ni][r] + bi);
            } else {
                float* outp = (float*)outv;
#pragma unroll
                for (int ni = 0; ni < 4; ++ni) {
                    float v = acc[mi][ni][r] + bi;
                    if constexpr (ADD_SKIP) v += skip[base + ni * 16];
                    outp[base + ni * 16] = v;
                }
            }
        }
    }
}

// ---------------------------------------------------------------------------
// x [B][256][HW] f32  ->  xT [B][HW][256] bf16
// ---------------------------------------------------------------------------
__global__ __launch_bounds__(256) void castT_k(const float* __restrict__ x,
                                               ushort* __restrict__ xT) {
    const int b = blockIdx.z, c0 = blockIdx.y * 64, hw0 = blockIdx.x * 64;
    __shared__ float tile[64][65];
    const int tid = threadIdx.x;
#pragma unroll
    for (int r = 0; r < 16; ++r) {
        int cl = r * 4 + (tid >> 6), hwl = tid & 63;
        tile[cl][hwl] = x[((size_t)b * CINC + c0 + cl) * HWS + hw0 + hwl];
    }
    __syncthreads();
#pragma unroll
    for (int r = 0; r < 16; ++r) {
        int hwl = r * 4 + (tid >> 6), cl = tid & 63;
        xT[((size_t)b * HWS + hw0 + hwl) * CINC + c0 + cl] = f2bf(tile[cl][hwl]);
    }
}

// generic f32 -> bf16 cast
__global__ __launch_bounds__(256) void cast_k(const float* __restrict__ in,
                                              ushort* __restrict__ out, int n) {
    int i = (blockIdx.x * 256 + threadIdx.x) * 4;
    if (i < n) {
        float4 v = *reinterpret_cast<const float4*>(in + i);
        out[i + 0] = f2bf(v.x); out[i + 1] = f2bf(v.y);
        out[i + 2] = f2bf(v.z); out[i + 3] = f2bf(v.w);
    }
}

// ---------------------------------------------------------------------------
// FUSED dynamic_pool + displace, IN PLACE on plane (b,c) of dpout[b][1024][hw]
// (pre half: c < 512).  Separable 5x5 Gaussian in LDS + bilinear shift.
// ---------------------------------------------------------------------------
__global__ __launch_bounds__(256) void pooldisp_k(ushort* __restrict__ dp,
                                                  const float* __restrict__ sigma,
                                                  const float* __restrict__ offsets) {
    const int bc = blockIdx.x;
    const int b = bc >> 9, c = bc & 511;
    __shared__ float ex[68 * 68];    // padded exp plane; reused as pl
    __shared__ float tmp[68 * 68];
    const int tid = threadIdx.x;
    ushort* ip = dp + ((size_t)b * 1024 + c) * HWS;

    float s = sigma[c];
    float inv = 0.5f / (s * s + EPSF);
    float g0 = __expf(-4.f * inv), g1 = __expf(-1.f * inv);
    float gs = g0 + g1 + 1.f + g1 + g0;
    float rnorm = 1.f / (gs * gs);

    for (int i = tid; i < 68 * 68; i += 256) ex[i] = 0.f;
    __syncthreads();

#pragma unroll
    for (int t = 0; t < 2; ++t) {
        int p = (tid + t * 256) * 8;
        int h = p >> 6, w = p & 63;
        ushort8 v = *reinterpret_cast<const ushort8*>(ip + p);
        float* er = &ex[(h + 2) * 68 + (w + 2)];
#pragma unroll
        for (int q = 0; q < 8; ++q)
            er[q] = __expf(fminf(bf2f(v[q]), EXP_CLAMP));
    }
    __syncthreads();

    // row pass
#pragma unroll
    for (int t = 0; t < 5; ++t) {
        int task = tid + t * 256;
        if (task < 1088) {
            int r = task >> 4, wq = (task & 15) * 4;
            float4 e0 = *reinterpret_cast<const float4*>(&ex[r * 68 + wq]);
            float4 e1 = *reinterpret_cast<const float4*>(&ex[r * 68 + wq + 4]);
            float e[8] = {e0.x, e0.y, e0.z, e0.w, e1.x, e1.y, e1.z, e1.w};
            float4 o;
            o.x = g0 * (e[0] + e[4]) + g1 * (e[1] + e[3]) + e[2];
            o.y = g0 * (e[1] + e[5]) + g1 * (e[2] + e[4]) + e[3];
            o.z = g0 * (e[2] + e[6]) + g1 * (e[3] + e[5]) + e[4];
            o.w = g0 * (e[3] + e[7]) + g1 * (e[4] + e[6]) + e[5];
            *reinterpret_cast<float4*>(&tmp[r * 68 + wq]) = o;
        }
    }
    __syncthreads();

    // col pass + log
    float* pl = ex;
#pragma unroll
    for (int t = 0; t < 4; ++t) {
        int task = tid + t * 256;
        int h = task >> 4, wq = (task & 15) * 4;
        float4 t0 = *reinterpret_cast<const float4*>(&tmp[(h + 0) * 68 + wq]);
        float4 t1 = *reinterpret_cast<const float4*>(&tmp[(h + 1) * 68 + wq]);
        float4 t2 = *reinterpret_cast<const float4*>(&tmp[(h + 2) * 68 + wq]);
        float4 t3 = *reinterpret_cast<const float4*>(&tmp[(h + 3) * 68 + wq]);
        float4 t4 = *reinterpret_cast<const float4*>(&tmp[(h + 4) * 68 + wq]);
        float4 o;
        o.x = g0 * (t0.x + t4.x) + g1 * (t1.x + t3.x) + t2.x;
        o.y = g0 * (t0.y + t4.y) + g1 * (t1.y + t3.y) + t2.y;
        o.z = g0 * (t0.z + t4.z) + g1 * (t1.z + t3.z) + t2.z;
        o.w = g0 * (t0.w + t4.w) + g1 * (t1.w + t3.w) + t2.w;
        float4 r;
        r.x = __logf(o.x * rnorm + EPSF);
        r.y = __logf(o.y * rnorm + EPSF);
        r.z = __logf(o.z * rnorm + EPSF);
        r.w = __logf(o.w * rnorm + EPSF);
        *reinterpret_cast<float4*>(&pl[h * 68 + wq]) = r;
    }
    __syncthreads();

    // displace: bilinear shift, zero padding; write back in place (bf16)
    int oi = c >> 3;
    float dy = offsets[oi * 2 + 0];
    float dx = offsets[oi * 2 + 1];
    float y0f = floorf(dy), x0f = floorf(dx);
    float fy = dy - y0f, fx = dx - x0f;
    int y0 = (int)y0f, x0 = (int)x0f;
    float w00 = (1.f - fy) * (1.f - fx), w01 = (1.f - fy) * fx;
    float w10 = fy * (1.f - fx),         w11 = fy * fx;
#pragma unroll
    for (int t = 0; t < 2; ++t) {
        int p = (tid + t * 256) * 8;
        int h = p >> 6, w = p & 63;
        int ry0 = h + y0, ry1 = ry0 + 1;
        bool my0 = (ry0 >= 0) & (ry0 < 64);
        bool my1 = (ry1 >= 0) & (ry1 < 64);
        ushort8 ov;
#pragma unroll
        for (int q = 0; q < 8; ++q) {
            int rx0 = w + q + x0, rx1 = rx0 + 1;
            bool mx0 = (rx0 >= 0) & (rx0 < 64);
            bool mx1 = (rx1 >= 0) & (rx1 < 64);
            float acc = 0.f;
            if (my0 & mx0) acc += w00 * pl[ry0 * 68 + rx0];
            if (my0 & mx1) acc += w01 * pl[ry0 * 68 + rx1];
            if (my1 & mx0) acc += w10 * pl[ry1 * 68 + rx0];
            if (my1 & mx1) acc += w11 * pl[ry1 * 68 + rx1];
            ov[q] = f2bf(acc);
        }
        *reinterpret_cast<ushort8*>(ip + p) = ov;
    }
}

// ---------------------------------------------------------------------------
// BN stats for att half of dpout[b][1024][hw]: planes b*1024 + 512 + c
// ---------------------------------------------------------------------------
__global__ __launch_bounds__(256) void bnstats_att_k(const ushort* __restrict__ a,
                                                     const float* __restrict__ gamma,
                                                     const float* __restrict__ beta,
                                                     float* __restrict__ scale,
                                                     float* __restrict__ shift) {
    const int c = blockIdx.x;
    float s = 0.f, s2 = 0.f;
    for (int b = 0; b < NB; ++b) {
        const ushort* p = a + ((size_t)b * 1024 + 512 + c) * HWS;
        for (int i = threadIdx.x * 8; i < HWS; i += 2048) {
            ushort8 v = *reinterpret_cast<const ushort8*>(p + i);
#pragma unroll
            for (int j = 0; j < 8; ++j) { float f = bf2f(v[j]); s += f; s2 += f * f; }
        }
    }
#pragma unroll
    for (int off = 32; off > 0; off >>= 1) {
        s += __shfl_down(s, off, 64);
        s2 += __shfl_down(s2, off, 64);
    }
    __shared__ float t1[4], t2[4];
    int lane = threadIdx.x & 63, wid = threadIdx.x >> 6;
    if (lane == 0) { t1[wid] = s; t2[wid] = s2; }
    __syncthreads();
    if (threadIdx.x == 0) {
        float S = t1[0] + t1[1] + t1[2] + t1[3];
        float S2 = t2[0] + t2[1] + t2[2] + t2[3];
        float n = (float)(NB * HWS);
        float mean = S / n;
        float var = S2 / n - mean * mean;
        float invs = rsqrtf(var + BN_EPS);
        float sc = invs * gamma[c];
        scale[c] = sc;
        shift[c] = beta[c] - mean * sc;
    }
}

// BN stats over f32 tensor (final BN on d_out)
template<int CT>
__global__ __launch_bounds__(256) void bnstats_k(const float* __restrict__ a,
                                                 const float* __restrict__ gamma,
                                                 const float* __restrict__ beta,
                                                 float* __restrict__ scale,
                                                 float* __restrict__ shift) {
    const int c = blockIdx.x;
    float s = 0.f, s2 = 0.f;
    for (int b = 0; b < NB; ++b) {
        const float* p = a + ((size_t)b * CT + c) * HWS;
        for (int i = threadIdx.x * 4; i < HWS; i += 1024) {
            float4 v = *reinterpret_cast<const float4*>(p + i);
            s += v.x + v.y + v.z + v.w;
            s2 += v.x * v.x + v.y * v.y + v.z * v.z + v.w * v.w;
        }
    }
#pragma unroll
    for (int off = 32; off > 0; off >>= 1) {
        s += __shfl_down(s, off, 64);
        s2 += __shfl_down(s2, off, 64);
    }
    __shared__ float t1[4], t2[4];
    int lane = threadIdx.x & 63, wid = threadIdx.x >> 6;
    if (lane == 0) { t1[wid] = s; t2[wid] = s2; }
    __syncthreads();
    if (threadIdx.x == 0) {
        float S = t1[0] + t1[1] + t1[2] + t1[3];
        float S2 = t2[0] + t2[1] + t2[2] + t2[3];
        float n = (float)(NB * HWS);
        float mean = S / n;
        float var = S2 / n - mean * mean;
        float invs = rsqrtf(var + BN_EPS);
        float sc = invs * gamma[c];
        scale[c] = sc;
        shift[c] = beta[c] - mean * sc;
    }
}

// ---------------------------------------------------------------------------
// FUSED spatial-softplus-sum + attention*disp, transposed write to mT.
// Block = (cgroup of 8 channels, b).  att rows staged in 64KB LDS.
// ---------------------------------------------------------------------------
__global__ __launch_bounds__(256) void attmulss_k(const ushort* __restrict__ dp,
                                                  const float* __restrict__ scale,
                                                  const float* __restrict__ shift,
                                                  ushort* __restrict__ mT) {
    const int c0 = blockIdx.x * 8, b = blockIdx.y;
    __shared__ ushort attL[8][4096];
    __shared__ float rs[8];
    const int t = threadIdx.x;
    const ushort* abase = dp + ((size_t)b * 1024 + 512 + c0) * HWS;
#pragma unroll
    for (int q = 0; q < 8; ++q) {
        *reinterpret_cast<ushort8*>(&attL[q][t * 16]) =
            *reinterpret_cast<const ushort8*>(abase + (size_t)q * HWS + t * 16);
        *reinterpret_cast<ushort8*>(&attL[q][t * 16 + 8]) =
            *reinterpret_cast<const ushort8*>(abase + (size_t)q * HWS + t * 16 + 8);
    }
    __syncthreads();
    {
        int q = t >> 5, ln = t & 31;
        float sc = scale[c0 + q], sh = shift[c0 + q];
        float s = 0.f;
        for (int e = ln; e < HWS; e += 32)
            s += softplus_fast(bf2f(attL[q][e]) * sc + sh);
#pragma unroll
        for (int off = 16; off > 0; off >>= 1) s += __shfl_down(s, off, 32);
        if (ln == 0) rs[q] = 1.f / s;
    }
    __syncthreads();
    float sc8[8], sh8[8], r8[8];
#pragma unroll
    for (int q = 0; q < 8; ++q) {
        sc8[q] = scale[c0 + q]; sh8[q] = shift[c0 + q]; r8[q] = rs[q];
    }
    const ushort* dbase = dp + ((size_t)b * 1024 + c0) * HWS;   // disp (pre half)
#pragma unroll
    for (int k = 0; k < 16; ++k) {
        int hw = t + k * 256;
        ushort8 ov;
#pragma unroll
        for (int q = 0; q < 8; ++q) {
            float a = bf2f(attL[q][hw]) * sc8[q] + sh8[q];
            float m = softplus_fast(a) * r8[q] * bf2f(dbase[(size_t)q * HWS + hw]);
            ov[q] = f2bf(m);
        }
        *reinterpret_cast<ushort8*>(mT + ((size_t)b * HWS + hw) * DPC + c0) = ov;
    }
}

// Final: out = relu(out*scale + shift) in place
__global__ __launch_bounds__(256) void final_k(float* __restrict__ out,
                                               const float* __restrict__ scale,
                                               const float* __restrict__ shift) {
    int i = blockIdx.x * 256 + threadIdx.x;
    int c = (i >> 12) & (COUTC - 1);
    float v = out[i] * scale[c] + shift[c];
    out[i] = fmaxf(v, 0.f);
}

extern "C" void kernel_launch(void* const* d_in, const int* in_sizes, int n_in,
                              void* d_out, int out_size, void* d_ws, size_t ws_size,
                              hipStream_t stream) {
    const float* x           = (const float*)d_in[0];
    const float* pre_w       = (const float*)d_in[1];
    const float* pre_b       = (const float*)d_in[2];
    const float* sigma       = (const float*)d_in[3];
    const float* offsets     = (const float*)d_in[4];
    const float* atten_w     = (const float*)d_in[5];
    const float* atten_b     = (const float*)d_in[6];
    const float* atten_gamma = (const float*)d_in[7];
    const float* atten_beta  = (const float*)d_in[8];
    const float* post_w      = (const float*)d_in[9];
    const float* post_b      = (const float*)d_in[10];
    const float* bn_gamma    = (const float*)d_in[11];
    const float* bn_beta     = (const float*)d_in[12];
    float* out = (float*)d_out;

    // Workspace (MiB offsets), peak 226 MiB:
    //  [0,32)   xT bf16 [B][HW][256]
    //  [32,33)  weights bf16: wbig [1024][256], wpost [256][512]
    //  [33,34)  stats
    //  [34,162) dpout bf16 [B][1024][HW]  (o<512 = pre->disp in place, o>=512 = att)
    //  [162,226) mT bf16 [B][HW][512]
    char* wsb = (char*)d_ws;
    ushort* xT    = (ushort*)(wsb);
    ushort* wbig  = (ushort*)(wsb + ((size_t)32 << 20));   // 1024*256*2 = 512 KiB
    ushort* wpost = wbig + 1024 * 256;                     // 256*512*2  = 256 KiB
    float*  stats = (float*)(wsb + ((size_t)33 << 20));
    ushort* dpout = (ushort*)(wsb + ((size_t)34 << 20));
    ushort* mT    = (ushort*)(wsb + ((size_t)162 << 20));

    float* scaleA = stats;          // 512
    float* shiftA = stats + 512;    // 512
    float* scale2 = stats + 1024;   // 256
    float* shift2 = stats + 1280;   // 256

    // 0. casts / transposes
    castT_k<<<dim3(64, 4, NB), 256, 0, stream>>>(x, xT);
    cast_k<<<128, 256, 0, stream>>>(pre_w,   wbig,             DPC * CINC);
    cast_k<<<128, 256, 0, stream>>>(atten_w, wbig + 512 * 256, DPC * CINC);
    cast_k<<<128, 256, 0, stream>>>(post_w,  wpost,            COUTC * DPC);

    // 1. FUSED pre+atten conv1x1 (MFMA, gload_lds) -> dpout
    mfma_gemm_k<1024, CINC, true, false><<<dim3(32, 8, NB), 256, 0, stream>>>(
        wbig, xT, pre_b, atten_b, nullptr, dpout);
    // 2. fused dynamic pool + displace, in place on pre half
    pooldisp_k<<<NB * DPC, 256, 0, stream>>>(dpout, sigma, offsets);
    // 3. BN stats (atten)
    bnstats_att_k<<<DPC, 256, 0, stream>>>(dpout, atten_gamma, atten_beta, scaleA, shiftA);
    // 4. fused ssum + attmul -> mT (K-major)
    attmulss_k<<<dim3(64, NB), 256, 0, stream>>>(dpout, scaleA, shiftA, mT);
    // 5. post conv1x1 (MFMA, gload_lds) + skip -> out (f32)
    mfma_gemm_k<COUTC, DPC, false, true><<<dim3(32, 2, NB), 256, 0, stream>>>(
        wpost, mT, post_b, post_b, x, out);
    // 6. final BN stats
    bnstats_k<COUTC><<<COUTC, 256, 0, stream>>>(out, bn_gamma, bn_beta, scale2, shift2);
    // 7. relu(bn) in place
    final_k<<<out_size / 256, 256, 0, stream>>>(out, scale2, shift2);
}

// Round 7
// 355.792 us; speedup vs baseline: 3.0911x; 1.0755x over previous
//
#include <hip/hip_runtime.h>
#include <cmath>

#define NB   16
#define CINC 256
#define DPC  512
#define COUTC 256
#define HWS  4096
#define EPSF 1.1920928955078125e-07f
#define BN_EPS 1e-5f
#define EXP_CLAMP 88.722835f

typedef unsigned int uint32;
typedef unsigned short ushort;
typedef __bf16 bf16x8 __attribute__((ext_vector_type(8)));
typedef float f32x4 __attribute__((ext_vector_type(4)));
typedef unsigned short ushort8 __attribute__((ext_vector_type(8)));

__device__ inline ushort f2bf(float f) {          // RNE float->bf16
    uint32 u = __builtin_bit_cast(uint32, f);
    u += 0x7fffu + ((u >> 16) & 1u);
    return (ushort)(u >> 16);
}
__device__ inline float bf2f(ushort u) {
    return __builtin_bit_cast(float, (uint32)u << 16);
}
__device__ inline float softplus_fast(float v) {
    return fmaxf(v, 0.f) + __logf(1.f + __expf(-fabsf(v)));
}
__device__ __forceinline__ void gload16(const void* g, void* l) {
    __builtin_amdgcn_global_load_lds(
        (__attribute__((address_space(1))) void*)g,
        (__attribute__((address_space(3))) void*)l, 16, 0, 0);
}

// ---------------------------------------------------------------------------
// MFMA bf16 GEMM, global_load_lds staging, conflict-free via source-side
// slot permutation (slot ^= (row>>1)&3).
// out[b][o][hw] = bias[o] + sum_k A[o][k] * BT[b][hw][k]  (+skip)
// 128x128 tile, BK=32, 4 waves.  grid (HWS/128, OTOT/128, NB), block 256.
// ---------------------------------------------------------------------------
template<int OTOT, int KTOT, bool BF16_OUT, bool ADD_SKIP>
__global__ __launch_bounds__(256) void mfma_gemm_k(
    const ushort* __restrict__ A, const ushort* __restrict__ BT,
    const float* __restrict__ bias1, const float* __restrict__ bias2,
    const float* __restrict__ skip, void* __restrict__ outv) {
    const int hw0 = blockIdx.x * 128;
    const int o0  = blockIdx.y * 128;
    const int b   = blockIdx.z;
    __shared__ ushort As[128 * 32];
    __shared__ ushort Bs[128 * 32];
    const int tid  = threadIdx.x;
    const int lane = tid & 63;
    const int w    = tid >> 6;
    const int wm0  = (w >> 1) * 64;
    const int wn0  = (w & 1) * 64;

    f32x4 acc[4][4] = {};

    const ushort* Ab = A + (size_t)o0 * KTOT;
    const ushort* Bb = BT + ((size_t)b * HWS + hw0) * KTOT;
    const int rsub  = lane >> 2;                               // 0..15
    const int ksubp = ((lane & 3) ^ ((lane >> 3) & 3)) * 8;    // permuted k slot

    for (int step = 0; step < KTOT / 32; ++step) {
        const int k0 = step * 32;
#pragma unroll
        for (int i = 0; i < 2; ++i) {
            const int row = w * 32 + i * 16 + rsub;
            gload16(Ab + (size_t)row * KTOT + k0 + ksubp, &As[(w * 32 + i * 16) * 32]);
            gload16(Bb + (size_t)row * KTOT + k0 + ksubp, &Bs[(w * 32 + i * 16) * 32]);
        }
        __syncthreads();
        bf16x8 af[4], bfr[4];
#pragma unroll
        for (int mi = 0; mi < 4; ++mi) {
            int row = wm0 + mi * 16 + (lane & 15);
            int sl = (lane >> 4) ^ ((row >> 1) & 3);
            af[mi] = *reinterpret_cast<const bf16x8*>(As + row * 32 + sl * 8);
        }
#pragma unroll
        for (int ni = 0; ni < 4; ++ni) {
            int row = wn0 + ni * 16 + (lane & 15);
            int sl = (lane >> 4) ^ ((row >> 1) & 3);
            bfr[ni] = *reinterpret_cast<const bf16x8*>(Bs + row * 32 + sl * 8);
        }
#pragma unroll
        for (int mi = 0; mi < 4; ++mi)
#pragma unroll
            for (int ni = 0; ni < 4; ++ni)
                acc[mi][ni] = __builtin_amdgcn_mfma_f32_16x16x32_bf16(af[mi], bfr[ni], acc[mi][ni], 0, 0, 0);
        __syncthreads();
    }

#pragma unroll
    for (int mi = 0; mi < 4; ++mi) {
#pragma unroll
        for (int r = 0; r < 4; ++r) {
            int o = o0 + wm0 + mi * 16 + ((lane >> 4) << 2) + r;
            float bi = (o < 512) ? bias1[o] : bias2[o - 512];
            size_t base = ((size_t)b * OTOT + o) * HWS + hw0 + wn0 + (lane & 15);
            if constexpr (BF16_OUT) {
                ushort* outp = (ushort*)outv;
#pragma unroll
                for (int ni = 0; ni < 4; ++ni)
                    outp[base + ni * 16] = f2bf(acc[mi][ni][r] + bi);
            } else {
                float* outp = (float*)outv;
#pragma unroll
                for (int ni = 0; ni < 4; ++ni) {
                    float v = acc[mi][ni][r] + bi;
                    if constexpr (ADD_SKIP) v += skip[base + ni * 16];
                    outp[base + ni * 16] = v;
                }
            }
        }
    }
}

// ---------------------------------------------------------------------------
// x [B][256][HW] f32  ->  xT [B][HW][256] bf16
// ---------------------------------------------------------------------------
__global__ __launch_bounds__(256) void castT_k(const float* __restrict__ x,
                                               ushort* __restrict__ xT) {
    const int b = blockIdx.z, c0 = blockIdx.y * 64, hw0 = blockIdx.x * 64;
    __shared__ float tile[64][65];
    const int tid = threadIdx.x;
#pragma unroll
    for (int r = 0; r < 16; ++r) {
        int cl = r * 4 + (tid >> 6), hwl = tid & 63;
        tile[cl][hwl] = x[((size_t)b * CINC + c0 + cl) * HWS + hw0 + hwl];
    }
    __syncthreads();
#pragma unroll
    for (int r = 0; r < 16; ++r) {
        int hwl = r * 4 + (tid >> 6), cl = tid & 63;
        xT[((size_t)b * HWS + hw0 + hwl) * CINC + c0 + cl] = f2bf(tile[cl][hwl]);
    }
}

// generic f32 -> bf16 cast
__global__ __launch_bounds__(256) void cast_k(const float* __restrict__ in,
                                              ushort* __restrict__ out, int n) {
    int i = (blockIdx.x * 256 + threadIdx.x) * 4;
    if (i < n) {
        float4 v = *reinterpret_cast<const float4*>(in + i);
        out[i + 0] = f2bf(v.x); out[i + 1] = f2bf(v.y);
        out[i + 2] = f2bf(v.z); out[i + 3] = f2bf(v.w);
    }
}

// ---------------------------------------------------------------------------
// FUSED dynamic_pool + displace, IN PLACE on plane (b,c) of dpout[b][1024][hw]
// ---------------------------------------------------------------------------
__global__ __launch_bounds__(256) void pooldisp_k(ushort* __restrict__ dp,
                                                  const float* __restrict__ sigma,
                                                  const float* __restrict__ offsets) {
    const int bc = blockIdx.x;
    const int b = bc >> 9, c = bc & 511;
    __shared__ float ex[68 * 68];
    __shared__ float tmp[68 * 68];
    const int tid = threadIdx.x;
    ushort* ip = dp + ((size_t)b * 1024 + c) * HWS;

    float s = sigma[c];
    float inv = 0.5f / (s * s + EPSF);
    float g0 = __expf(-4.f * inv), g1 = __expf(-1.f * inv);
    float gs = g0 + g1 + 1.f + g1 + g0;
    float rnorm = 1.f / (gs * gs);

    for (int i = tid; i < 68 * 68; i += 256) ex[i] = 0.f;
    __syncthreads();

#pragma unroll
    for (int t = 0; t < 2; ++t) {
        int p = (tid + t * 256) * 8;
        int h = p >> 6, w = p & 63;
        ushort8 v = *reinterpret_cast<const ushort8*>(ip + p);
        float* er = &ex[(h + 2) * 68 + (w + 2)];
#pragma unroll
        for (int q = 0; q < 8; ++q)
            er[q] = __expf(fminf(bf2f(v[q]), EXP_CLAMP));
    }
    __syncthreads();

    // row pass
#pragma unroll
    for (int t = 0; t < 5; ++t) {
        int task = tid + t * 256;
        if (task < 1088) {
            int r = task >> 4, wq = (task & 15) * 4;
            float4 e0 = *reinterpret_cast<const float4*>(&ex[r * 68 + wq]);
            float4 e1 = *reinterpret_cast<const float4*>(&ex[r * 68 + wq + 4]);
            float e[8] = {e0.x, e0.y, e0.z, e0.w, e1.x, e1.y, e1.z, e1.w};
            float4 o;
            o.x = g0 * (e[0] + e[4]) + g1 * (e[1] + e[3]) + e[2];
            o.y = g0 * (e[1] + e[5]) + g1 * (e[2] + e[4]) + e[3];
            o.z = g0 * (e[2] + e[6]) + g1 * (e[3] + e[5]) + e[4];
            o.w = g0 * (e[3] + e[7]) + g1 * (e[4] + e[6]) + e[5];
            *reinterpret_cast<float4*>(&tmp[r * 68 + wq]) = o;
        }
    }
    __syncthreads();

    // col pass + log
    float* pl = ex;
#pragma unroll
    for (int t = 0; t < 4; ++t) {
        int task = tid + t * 256;
        int h = task >> 4, wq = (task & 15) * 4;
        float4 t0 = *reinterpret_cast<const float4*>(&tmp[(h + 0) * 68 + wq]);
        float4 t1 = *reinterpret_cast<const float4*>(&tmp[(h + 1) * 68 + wq]);
        float4 t2 = *reinterpret_cast<const float4*>(&tmp[(h + 2) * 68 + wq]);
        float4 t3 = *reinterpret_cast<const float4*>(&tmp[(h + 3) * 68 + wq]);
        float4 t4 = *reinterpret_cast<const float4*>(&tmp[(h + 4) * 68 + wq]);
        float4 o;
        o.x = g0 * (t0.x + t4.x) + g1 * (t1.x + t3.x) + t2.x;
        o.y = g0 * (t0.y + t4.y) + g1 * (t1.y + t3.y) + t2.y;
        o.z = g0 * (t0.z + t4.z) + g1 * (t1.z + t3.z) + t2.z;
        o.w = g0 * (t0.w + t4.w) + g1 * (t1.w + t3.w) + t2.w;
        float4 r;
        r.x = __logf(o.x * rnorm + EPSF);
        r.y = __logf(o.y * rnorm + EPSF);
        r.z = __logf(o.z * rnorm + EPSF);
        r.w = __logf(o.w * rnorm + EPSF);
        *reinterpret_cast<float4*>(&pl[h * 68 + wq]) = r;
    }
    __syncthreads();

    // displace: bilinear shift, zero padding; in place (bf16)
    int oi = c >> 3;
    float dy = offsets[oi * 2 + 0];
    float dx = offsets[oi * 2 + 1];
    float y0f = floorf(dy), x0f = floorf(dx);
    float fy = dy - y0f, fx = dx - x0f;
    int y0 = (int)y0f, x0 = (int)x0f;
    float w00 = (1.f - fy) * (1.f - fx), w01 = (1.f - fy) * fx;
    float w10 = fy * (1.f - fx),         w11 = fy * fx;
#pragma unroll
    for (int t = 0; t < 2; ++t) {
        int p = (tid + t * 256) * 8;
        int h = p >> 6, w = p & 63;
        int ry0 = h + y0, ry1 = ry0 + 1;
        bool my0 = (ry0 >= 0) & (ry0 < 64);
        bool my1 = (ry1 >= 0) & (ry1 < 64);
        ushort8 ov;
#pragma unroll
        for (int q = 0; q < 8; ++q) {
            int rx0 = w + q + x0, rx1 = rx0 + 1;
            bool mx0 = (rx0 >= 0) & (rx0 < 64);
            bool mx1 = (rx1 >= 0) & (rx1 < 64);
            float acc = 0.f;
            if (my0 & mx0) acc += w00 * pl[ry0 * 68 + rx0];
            if (my0 & mx1) acc += w01 * pl[ry0 * 68 + rx1];
            if (my1 & mx0) acc += w10 * pl[ry1 * 68 + rx0];
            if (my1 & mx1) acc += w11 * pl[ry1 * 68 + rx1];
            ov[q] = f2bf(acc);
        }
        *reinterpret_cast<ushort8*>(ip + p) = ov;
    }
}

// ---------------------------------------------------------------------------
// FUSED BN stats + per-(b,c) softplus spatial sums for the att half.
// Block = channel c.  Phase 1: mean/var over [NB][HWS].  Phase 2: per-b
// softplus sums (L2-warm re-read).  Stores reciprocal sums.
// ---------------------------------------------------------------------------
__global__ __launch_bounds__(256) void attstats_k(const ushort* __restrict__ dp,
                                                  const float* __restrict__ gamma,
                                                  const float* __restrict__ beta,
                                                  float* __restrict__ scale,
                                                  float* __restrict__ shift,
                                                  float* __restrict__ rsum) {
    const int c = blockIdx.x;
    const int t = threadIdx.x;
    const int lane = t & 63, wid = t >> 6;
    __shared__ float t1[4], t2[4], red[4];
    __shared__ float sc_sh, sh_sh;

    float s = 0.f, s2 = 0.f;
    for (int b = 0; b < NB; ++b) {
        const ushort* p = dp + ((size_t)b * 1024 + 512 + c) * HWS;
        for (int i = t * 8; i < HWS; i += 2048) {
            ushort8 v = *reinterpret_cast<const ushort8*>(p + i);
#pragma unroll
            for (int j = 0; j < 8; ++j) { float f = bf2f(v[j]); s += f; s2 += f * f; }
        }
    }
#pragma unroll
    for (int off = 32; off > 0; off >>= 1) {
        s += __shfl_down(s, off, 64);
        s2 += __shfl_down(s2, off, 64);
    }
    if (lane == 0) { t1[wid] = s; t2[wid] = s2; }
    __syncthreads();
    if (t == 0) {
        float S = t1[0] + t1[1] + t1[2] + t1[3];
        float S2 = t2[0] + t2[1] + t2[2] + t2[3];
        float n = (float)(NB * HWS);
        float mean = S / n;
        float var = S2 / n - mean * mean;
        float invs = rsqrtf(var + BN_EPS);
        float sc = invs * gamma[c];
        float sh = beta[c] - mean * sc;
        scale[c] = sc; shift[c] = sh;
        sc_sh = sc; sh_sh = sh;
    }
    __syncthreads();
    float sc = sc_sh, sh = sh_sh;

    for (int b = 0; b < NB; ++b) {
        const ushort* p = dp + ((size_t)b * 1024 + 512 + c) * HWS;
        ushort8 v0 = *reinterpret_cast<const ushort8*>(p + t * 16);
        ushort8 v1 = *reinterpret_cast<const ushort8*>(p + t * 16 + 8);
        float ps = 0.f;
#pragma unroll
        for (int j = 0; j < 8; ++j) ps += softplus_fast(bf2f(v0[j]) * sc + sh);
#pragma unroll
        for (int j = 0; j < 8; ++j) ps += softplus_fast(bf2f(v1[j]) * sc + sh);
#pragma unroll
        for (int off = 32; off > 0; off >>= 1) ps += __shfl_down(ps, off, 64);
        if (lane == 0) red[wid] = ps;
        __syncthreads();
        if (t == 0) rsum[b * DPC + c] = 1.f / (red[0] + red[1] + red[2] + red[3]);
        __syncthreads();
    }
}

// ---------------------------------------------------------------------------
// m = softplus(bn(att)) * rsum * disp, transposed via LDS -> mT[b][hw][512]
// grid (HW/64, DPC/64, NB), block 256.  Coalesced reads AND writes.
// ---------------------------------------------------------------------------
__global__ __launch_bounds__(256) void attmulT_k(const ushort* __restrict__ dp,
                                                 const float* __restrict__ scale,
                                                 const float* __restrict__ shift,
                                                 const float* __restrict__ rsum,
                                                 ushort* __restrict__ mT) {
    const int b = blockIdx.z, c0 = blockIdx.y * 64, hw0 = blockIdx.x * 64;
    __shared__ float tile[64][65];
    const int tid = threadIdx.x;
#pragma unroll
    for (int r = 0; r < 16; ++r) {
        int cl = r * 4 + (tid >> 6), hwl = tid & 63;
        int c = c0 + cl;
        size_t aidx = ((size_t)b * 1024 + 512 + c) * HWS + hw0 + hwl;
        size_t didx = ((size_t)b * 1024 + c) * HWS + hw0 + hwl;
        float a = bf2f(dp[aidx]) * scale[c] + shift[c];
        float m = softplus_fast(a) * rsum[b * DPC + c] * bf2f(dp[didx]);
        tile[cl][hwl] = m;
    }
    __syncthreads();
#pragma unroll
    for (int r = 0; r < 16; ++r) {
        int hwl = r * 4 + (tid >> 6), cl = tid & 63;
        mT[((size_t)b * HWS + hw0 + hwl) * DPC + c0 + cl] = f2bf(tile[cl][hwl]);
    }
}

// BN stats over f32 tensor (final BN on d_out)
template<int CT>
__global__ __launch_bounds__(256) void bnstats_k(const float* __restrict__ a,
                                                 const float* __restrict__ gamma,
                                                 const float* __restrict__ beta,
                                                 float* __restrict__ scale,
                                                 float* __restrict__ shift) {
    const int c = blockIdx.x;
    float s = 0.f, s2 = 0.f;
    for (int b = 0; b < NB; ++b) {
        const float* p = a + ((size_t)b * CT + c) * HWS;
        for (int i = threadIdx.x * 4; i < HWS; i += 1024) {
            float4 v = *reinterpret_cast<const float4*>(p + i);
            s += v.x + v.y + v.z + v.w;
            s2 += v.x * v.x + v.y * v.y + v.z * v.z + v.w * v.w;
        }
    }
#pragma unroll
    for (int off = 32; off > 0; off >>= 1) {
        s += __shfl_down(s, off, 64);
        s2 += __shfl_down(s2, off, 64);
    }
    __shared__ float t1[4], t2[4];
    int lane = threadIdx.x & 63, wid = threadIdx.x >> 6;
    if (lane == 0) { t1[wid] = s; t2[wid] = s2; }
    __syncthreads();
    if (threadIdx.x == 0) {
        float S = t1[0] + t1[1] + t1[2] + t1[3];
        float S2 = t2[0] + t2[1] + t2[2] + t2[3];
        float n = (float)(NB * HWS);
        float mean = S / n;
        float var = S2 / n - mean * mean;
        float invs = rsqrtf(var + BN_EPS);
        float sc = invs * gamma[c];
        scale[c] = sc;
        shift[c] = beta[c] - mean * sc;
    }
}

// Final: out = relu(out*scale + shift) in place
__global__ __launch_bounds__(256) void final_k(float* __restrict__ out,
                                               const float* __restrict__ scale,
                                               const float* __restrict__ shift) {
    int i = blockIdx.x * 256 + threadIdx.x;
    int c = (i >> 12) & (COUTC - 1);
    float v = out[i] * scale[c] + shift[c];
    out[i] = fmaxf(v, 0.f);
}

extern "C" void kernel_launch(void* const* d_in, const int* in_sizes, int n_in,
                              void* d_out, int out_size, void* d_ws, size_t ws_size,
                              hipStream_t stream) {
    const float* x           = (const float*)d_in[0];
    const float* pre_w       = (const float*)d_in[1];
    const float* pre_b       = (const float*)d_in[2];
    const float* sigma       = (const float*)d_in[3];
    const float* offsets     = (const float*)d_in[4];
    const float* atten_w     = (const float*)d_in[5];
    const float* atten_b     = (const float*)d_in[6];
    const float* atten_gamma = (const float*)d_in[7];
    const float* atten_beta  = (const float*)d_in[8];
    const float* post_w      = (const float*)d_in[9];
    const float* post_b      = (const float*)d_in[10];
    const float* bn_gamma    = (const float*)d_in[11];
    const float* bn_beta     = (const float*)d_in[12];
    float* out = (float*)d_out;

    // Workspace (MiB offsets), peak 226 MiB:
    //  [0,32)   xT bf16 [B][HW][256]
    //  [32,33)  weights bf16
    //  [33,34)  stats
    //  [34,162) dpout bf16 [B][1024][HW]  (c<512: pre->disp in place; c>=512: att)
    //  [162,226) mT bf16 [B][HW][512]
    char* wsb = (char*)d_ws;
    ushort* xT    = (ushort*)(wsb);
    ushort* wbig  = (ushort*)(wsb + ((size_t)32 << 20));
    ushort* wpost = wbig + 1024 * 256;
    float*  stats = (float*)(wsb + ((size_t)33 << 20));
    ushort* dpout = (ushort*)(wsb + ((size_t)34 << 20));
    ushort* mT    = (ushort*)(wsb + ((size_t)162 << 20));

    float* scaleA = stats;          // 512
    float* shiftA = stats + 512;    // 512
    float* rsum   = stats + 1024;   // 8192
    float* scale2 = stats + 9216;   // 256
    float* shift2 = stats + 9472;   // 256

    // 0. casts / transposes
    castT_k<<<dim3(64, 4, NB), 256, 0, stream>>>(x, xT);
    cast_k<<<128, 256, 0, stream>>>(pre_w,   wbig,             DPC * CINC);
    cast_k<<<128, 256, 0, stream>>>(atten_w, wbig + 512 * 256, DPC * CINC);
    cast_k<<<128, 256, 0, stream>>>(post_w,  wpost,            COUTC * DPC);

    // 1. FUSED pre+atten conv1x1 (MFMA, gload_lds) -> dpout
    mfma_gemm_k<1024, CINC, true, false><<<dim3(32, 8, NB), 256, 0, stream>>>(
        wbig, xT, pre_b, atten_b, nullptr, dpout);
    // 2. fused dynamic pool + displace, in place on pre half
    pooldisp_k<<<NB * DPC, 256, 0, stream>>>(dpout, sigma, offsets);
    // 3. FUSED BN stats + softplus spatial sums (atten)
    attstats_k<<<DPC, 256, 0, stream>>>(dpout, atten_gamma, atten_beta,
                                        scaleA, shiftA, rsum);
    // 4. attmul, transposed -> mT (coalesced both sides)
    attmulT_k<<<dim3(64, 8, NB), 256, 0, stream>>>(dpout, scaleA, shiftA, rsum, mT);
    // 5. post conv1x1 (MFMA, gload_lds) + skip -> out (f32)
    mfma_gemm_k<COUTC, DPC, false, true><<<dim3(32, 2, NB), 256, 0, stream>>>(
        wpost, mT, post_b, post_b, x, out);
    // 6. final BN stats
    bnstats_k<COUTC><<<COUTC, 256, 0, stream>>>(out, bn_gamma, bn_beta, scale2, shift2);
    // 7. relu(bn) in place
    final_k<<<out_size / 256, 256, 0, stream>>>(out, scale2, shift2);
}

// Round 8
// 305.210 us; speedup vs baseline: 3.6034x; 1.1657x over previous
//
#include <hip/hip_runtime.h>
#include <cmath>

#define NB   16
#define CINC 256
#define DPC  512
#define COUTC 256
#define HWS  4096
#define EPSF 1.1920928955078125e-07f
#define BN_EPS 1e-5f
#define EXP_CLAMP 88.722835f
#define SW 80   // pooldisp LDS ushort stride (interior cols at 8..71)

typedef unsigned int uint32;
typedef unsigned short ushort;
typedef __bf16 bf16x8 __attribute__((ext_vector_type(8)));
typedef float f32x4 __attribute__((ext_vector_type(4)));
typedef unsigned short ushort8 __attribute__((ext_vector_type(8)));

__device__ inline ushort f2bf(float f) {          // RNE float->bf16
    uint32 u = __builtin_bit_cast(uint32, f);
    u += 0x7fffu + ((u >> 16) & 1u);
    return (ushort)(u >> 16);
}
__device__ inline float bf2f(ushort u) {
    return __builtin_bit_cast(float, (uint32)u << 16);
}
__device__ inline float softplus_fast(float v) {
    return fmaxf(v, 0.f) + __logf(1.f + __expf(-fabsf(v)));
}
__device__ __forceinline__ void gload16(const void* g, void* l) {
    __builtin_amdgcn_global_load_lds(
        (__attribute__((address_space(1))) void*)g,
        (__attribute__((address_space(3))) void*)l, 16, 0, 0);
}

// ---------------------------------------------------------------------------
// MFMA bf16 GEMM, global_load_lds staging, conflict-free via source-side
// slot permutation (slot ^= (row>>1)&3).
// out[b][o][hw] = bias[o] + sum_k A[o][k] * BT[b][hw][k]  (+skip)
// 128x128 tile, BK=32, 4 waves.  grid (HWS/128, OTOT/128, NB), block 256.
// ---------------------------------------------------------------------------
template<int OTOT, int KTOT, bool BF16_OUT, bool ADD_SKIP>
__global__ __launch_bounds__(256) void mfma_gemm_k(
    const ushort* __restrict__ A, const ushort* __restrict__ BT,
    const float* __restrict__ bias1, const float* __restrict__ bias2,
    const float* __restrict__ skip, void* __restrict__ outv) {
    const int hw0 = blockIdx.x * 128;
    const int o0  = blockIdx.y * 128;
    const int b   = blockIdx.z;
    __shared__ ushort As[128 * 32];
    __shared__ ushort Bs[128 * 32];
    const int tid  = threadIdx.x;
    const int lane = tid & 63;
    const int w    = tid >> 6;
    const int wm0  = (w >> 1) * 64;
    const int wn0  = (w & 1) * 64;

    f32x4 acc[4][4] = {};

    const ushort* Ab = A + (size_t)o0 * KTOT;
    const ushort* Bb = BT + ((size_t)b * HWS + hw0) * KTOT;
    const int rsub  = lane >> 2;
    const int ksubp = ((lane & 3) ^ ((lane >> 3) & 3)) * 8;

    for (int step = 0; step < KTOT / 32; ++step) {
        const int k0 = step * 32;
#pragma unroll
        for (int i = 0; i < 2; ++i) {
            const int row = w * 32 + i * 16 + rsub;
            gload16(Ab + (size_t)row * KTOT + k0 + ksubp, &As[(w * 32 + i * 16) * 32]);
            gload16(Bb + (size_t)row * KTOT + k0 + ksubp, &Bs[(w * 32 + i * 16) * 32]);
        }
        __syncthreads();
        bf16x8 af[4], bfr[4];
#pragma unroll
        for (int mi = 0; mi < 4; ++mi) {
            int row = wm0 + mi * 16 + (lane & 15);
            int sl = (lane >> 4) ^ ((row >> 1) & 3);
            af[mi] = *reinterpret_cast<const bf16x8*>(As + row * 32 + sl * 8);
        }
#pragma unroll
        for (int ni = 0; ni < 4; ++ni) {
            int row = wn0 + ni * 16 + (lane & 15);
            int sl = (lane >> 4) ^ ((row >> 1) & 3);
            bfr[ni] = *reinterpret_cast<const bf16x8*>(Bs + row * 32 + sl * 8);
        }
#pragma unroll
        for (int mi = 0; mi < 4; ++mi)
#pragma unroll
            for (int ni = 0; ni < 4; ++ni)
                acc[mi][ni] = __builtin_amdgcn_mfma_f32_16x16x32_bf16(af[mi], bfr[ni], acc[mi][ni], 0, 0, 0);
        __syncthreads();
    }

#pragma unroll
    for (int mi = 0; mi < 4; ++mi) {
#pragma unroll
        for (int r = 0; r < 4; ++r) {
            int o = o0 + wm0 + mi * 16 + ((lane >> 4) << 2) + r;
            float bi = (o < 512) ? bias1[o] : bias2[o - 512];
            size_t base = ((size_t)b * OTOT + o) * HWS + hw0 + wn0 + (lane & 15);
            if constexpr (BF16_OUT) {
                ushort* outp = (ushort*)outv;
#pragma unroll
                for (int ni = 0; ni < 4; ++ni)
                    outp[base + ni * 16] = f2bf(acc[mi][ni][r] + bi);
            } else {
                float* outp = (float*)outv;
#pragma unroll
                for (int ni = 0; ni < 4; ++ni) {
                    float v = acc[mi][ni][r] + bi;
                    if constexpr (ADD_SKIP) v += skip[base + ni * 16];
                    outp[base + ni * 16] = v;
                }
            }
        }
    }
}

// ---------------------------------------------------------------------------
// x [B][256][HW] f32  ->  xT [B][HW][256] bf16
// ---------------------------------------------------------------------------
__global__ __launch_bounds__(256) void castT_k(const float* __restrict__ x,
                                               ushort* __restrict__ xT) {
    const int b = blockIdx.z, c0 = blockIdx.y * 64, hw0 = blockIdx.x * 64;
    __shared__ float tile[64][65];
    const int tid = threadIdx.x;
#pragma unroll
    for (int r = 0; r < 16; ++r) {
        int cl = r * 4 + (tid >> 6), hwl = tid & 63;
        tile[cl][hwl] = x[((size_t)b * CINC + c0 + cl) * HWS + hw0 + hwl];
    }
    __syncthreads();
#pragma unroll
    for (int r = 0; r < 16; ++r) {
        int hwl = r * 4 + (tid >> 6), cl = tid & 63;
        xT[((size_t)b * HWS + hw0 + hwl) * CINC + c0 + cl] = f2bf(tile[cl][hwl]);
    }
}

// generic f32 -> bf16 cast
__global__ __launch_bounds__(256) void cast_k(const float* __restrict__ in,
                                              ushort* __restrict__ out, int n) {
    int i = (blockIdx.x * 256 + threadIdx.x) * 4;
    if (i < n) {
        float4 v = *reinterpret_cast<const float4*>(in + i);
        out[i + 0] = f2bf(v.x); out[i + 1] = f2bf(v.y);
        out[i + 2] = f2bf(v.z); out[i + 3] = f2bf(v.w);
    }
}

// ---------------------------------------------------------------------------
// FUSED dynamic_pool + displace v2: bf16 LDS planes (21.8 KB -> 7 blocks/CU),
// merged zero+stage phase (3 barriers), aligned ushort8 LDS ops.
// IN PLACE on plane (b,c) of dpout[b][1024][hw], c < 512.
// ---------------------------------------------------------------------------
__global__ __launch_bounds__(256) void pooldisp_k(ushort* __restrict__ dp,
                                                  const float* __restrict__ sigma,
                                                  const float* __restrict__ offsets) {
    const int bc = blockIdx.x;
    const int b = bc >> 9, c = bc & 511;
    __shared__ ushort ex[68 * SW];    // bf16 exp plane (padded); reused as pl
    __shared__ ushort tmp[68 * SW];   // bf16 row-pass intermediate
    const int tid = threadIdx.x;
    ushort* ip = dp + ((size_t)b * 1024 + c) * HWS;

    float s = sigma[c];
    float inv = 0.5f / (s * s + EPSF);
    float g0 = __expf(-4.f * inv), g1 = __expf(-1.f * inv);
    float gs = g0 + g1 + 1.f + g1 + g0;
    float rnorm = 1.f / (gs * gs);

    // phase 1: zero pads + stage exp(min(x,clamp)) interior (disjoint regions)
    if (tid < 168) {
        int row, colc;
        if (tid < 40) {
            row = (tid < 20) ? (tid / 10) : (66 + (tid - 20) / 10);
            colc = (tid % 10) * 8;
        } else {
            int k = tid - 40;
            row = 2 + (k >> 1);
            colc = (k & 1) ? 72 : 0;
        }
        ushort8 z = {0, 0, 0, 0, 0, 0, 0, 0};
        *reinterpret_cast<ushort8*>(&ex[row * SW + colc]) = z;
    }
#pragma unroll
    for (int t = 0; t < 2; ++t) {
        int p = (tid + t * 256) * 8;
        int h = p >> 6, w = p & 63;
        ushort8 v = *reinterpret_cast<const ushort8*>(ip + p);
        ushort8 e;
#pragma unroll
        for (int q = 0; q < 8; ++q)
            e[q] = f2bf(__expf(fminf(bf2f(v[q]), EXP_CLAMP)));
        *reinterpret_cast<ushort8*>(&ex[(h + 2) * SW + 8 + w]) = e;
    }
    __syncthreads();

    // phase 2: row pass (68 rows x 8 col-groups = 544 tasks)
    for (int t = 0; t < 3; ++t) {
        int task = tid + t * 256;
        if (task < 544) {
            int r = task >> 3, wgc = (task & 7) * 8;   // wgc = LDS chunk col
            ushort8 c0 = *reinterpret_cast<const ushort8*>(&ex[r * SW + wgc]);
            ushort8 c1 = *reinterpret_cast<const ushort8*>(&ex[r * SW + wgc + 8]);
            ushort8 c2 = *reinterpret_cast<const ushort8*>(&ex[r * SW + wgc + 16]);
            float P[24];
#pragma unroll
            for (int q = 0; q < 8; ++q) {
                P[q] = bf2f(c0[q]); P[8 + q] = bf2f(c1[q]); P[16 + q] = bf2f(c2[q]);
            }
            ushort8 o;
#pragma unroll
            for (int j = 0; j < 8; ++j)
                o[j] = f2bf(g0 * (P[6 + j] + P[10 + j]) + g1 * (P[7 + j] + P[9 + j]) + P[8 + j]);
            *reinterpret_cast<ushort8*>(&tmp[r * SW + wgc + 8]) = o;
        }
    }
    __syncthreads();

    // phase 3: col pass + log -> pl (stored back into ex interior)
#pragma unroll
    for (int t = 0; t < 2; ++t) {
        int task = tid + t * 256;
        int h = task >> 3, wgc = (task & 7) * 8;
        ushort8 t0 = *reinterpret_cast<const ushort8*>(&tmp[(h + 0) * SW + wgc + 8]);
        ushort8 t1 = *reinterpret_cast<const ushort8*>(&tmp[(h + 1) * SW + wgc + 8]);
        ushort8 t2 = *reinterpret_cast<const ushort8*>(&tmp[(h + 2) * SW + wgc + 8]);
        ushort8 t3 = *reinterpret_cast<const ushort8*>(&tmp[(h + 3) * SW + wgc + 8]);
        ushort8 t4 = *reinterpret_cast<const ushort8*>(&tmp[(h + 4) * SW + wgc + 8]);
        ushort8 o;
#pragma unroll
        for (int j = 0; j < 8; ++j) {
            float v = g0 * (bf2f(t0[j]) + bf2f(t4[j]))
                    + g1 * (bf2f(t1[j]) + bf2f(t3[j])) + bf2f(t2[j]);
            o[j] = f2bf(__logf(v * rnorm + EPSF));
        }
        *reinterpret_cast<ushort8*>(&ex[(h + 2) * SW + 8 + wgc]) = o;
    }
    __syncthreads();

    // phase 4: displace (bilinear shift, zero pad), write back in place
    int oi = c >> 3;
    float dy = offsets[oi * 2 + 0];
    float dx = offsets[oi * 2 + 1];
    float y0f = floorf(dy), x0f = floorf(dx);
    float fy = dy - y0f, fx = dx - x0f;
    int y0 = (int)y0f, x0 = (int)x0f;
    float w00 = (1.f - fy) * (1.f - fx), w01 = (1.f - fy) * fx;
    float w10 = fy * (1.f - fx),         w11 = fy * fx;
#pragma unroll
    for (int t = 0; t < 2; ++t) {
        int p = (tid + t * 256) * 8;
        int h = p >> 6, w = p & 63;
        int ry0 = h + y0, ry1 = ry0 + 1;
        bool my0 = (ry0 >= 0) & (ry0 < 64);
        bool my1 = (ry1 >= 0) & (ry1 < 64);
        ushort8 ov;
#pragma unroll
        for (int q = 0; q < 8; ++q) {
            int rx0 = w + q + x0, rx1 = rx0 + 1;
            bool mx0 = (rx0 >= 0) & (rx0 < 64);
            bool mx1 = (rx1 >= 0) & (rx1 < 64);
            float acc = 0.f;
            if (my0 & mx0) acc += w00 * bf2f(ex[(ry0 + 2) * SW + 8 + rx0]);
            if (my0 & mx1) acc += w01 * bf2f(ex[(ry0 + 2) * SW + 8 + rx1]);
            if (my1 & mx0) acc += w10 * bf2f(ex[(ry1 + 2) * SW + 8 + rx0]);
            if (my1 & mx1) acc += w11 * bf2f(ex[(ry1 + 2) * SW + 8 + rx1]);
            ov[q] = f2bf(acc);
        }
        *reinterpret_cast<ushort8*>(ip + p) = ov;
    }
}

// ---------------------------------------------------------------------------
// FUSED BN stats + softplus spatial sums (att half), 1024 threads:
// wave wv owns batch wv (NB==16 waves); plane kept in registers between
// phases (no re-read).  Stores reciprocal sums.
// ---------------------------------------------------------------------------
__global__ __launch_bounds__(1024) void attstats_k(const ushort* __restrict__ dp,
                                                   const float* __restrict__ gamma,
                                                   const float* __restrict__ beta,
                                                   float* __restrict__ scale,
                                                   float* __restrict__ shift,
                                                   float* __restrict__ rsum) {
    const int c = blockIdx.x;
    const int t = threadIdx.x;
    const int wv = t >> 6, lane = t & 63;
    const ushort* p = dp + ((size_t)wv * 1024 + 512 + c) * HWS;

    ushort8 v[8];
    float s = 0.f, s2 = 0.f;
#pragma unroll
    for (int k = 0; k < 8; ++k) {
        v[k] = *reinterpret_cast<const ushort8*>(p + lane * 8 + k * 512);
#pragma unroll
        for (int j = 0; j < 8; ++j) { float f = bf2f(v[k][j]); s += f; s2 += f * f; }
    }
#pragma unroll
    for (int off = 32; off > 0; off >>= 1) {
        s += __shfl_down(s, off, 64);
        s2 += __shfl_down(s2, off, 64);
    }
    __shared__ float t1[16], t2[16], scsh[2];
    if (lane == 0) { t1[wv] = s; t2[wv] = s2; }
    __syncthreads();
    if (t == 0) {
        float S = 0.f, S2 = 0.f;
#pragma unroll
        for (int k = 0; k < 16; ++k) { S += t1[k]; S2 += t2[k]; }
        float n = (float)(NB * HWS);
        float mean = S / n;
        float var = S2 / n - mean * mean;
        float invs = rsqrtf(var + BN_EPS);
        float sc = invs * gamma[c];
        float sh = beta[c] - mean * sc;
        scale[c] = sc; shift[c] = sh;
        scsh[0] = sc; scsh[1] = sh;
    }
    __syncthreads();
    float sc = scsh[0], sh = scsh[1];
    float ps = 0.f;
#pragma unroll
    for (int k = 0; k < 8; ++k)
#pragma unroll
        for (int j = 0; j < 8; ++j)
            ps += softplus_fast(bf2f(v[k][j]) * sc + sh);
#pragma unroll
    for (int off = 32; off > 0; off >>= 1) ps += __shfl_down(ps, off, 64);
    if (lane == 0) rsum[wv * DPC + c] = 1.f / ps;
}

// ---------------------------------------------------------------------------
// m = softplus(bn(att)) * rsum * disp, transposed via LDS -> mT[b][hw][512]
// ---------------------------------------------------------------------------
__global__ __launch_bounds__(256) void attmulT_k(const ushort* __restrict__ dp,
                                                 const float* __restrict__ scale,
                                                 const float* __restrict__ shift,
                                                 const float* __restrict__ rsum,
                                                 ushort* __restrict__ mT) {
    const int b = blockIdx.z, c0 = blockIdx.y * 64, hw0 = blockIdx.x * 64;
    __shared__ float tile[64][65];
    const int tid = threadIdx.x;
#pragma unroll
    for (int r = 0; r < 16; ++r) {
        int cl = r * 4 + (tid >> 6), hwl = tid & 63;
        int c = c0 + cl;
        size_t aidx = ((size_t)b * 1024 + 512 + c) * HWS + hw0 + hwl;
        size_t didx = ((size_t)b * 1024 + c) * HWS + hw0 + hwl;
        float a = bf2f(dp[aidx]) * scale[c] + shift[c];
        float m = softplus_fast(a) * rsum[b * DPC + c] * bf2f(dp[didx]);
        tile[cl][hwl] = m;
    }
    __syncthreads();
#pragma unroll
    for (int r = 0; r < 16; ++r) {
        int hwl = r * 4 + (tid >> 6), cl = tid & 63;
        mT[((size_t)b * HWS + hw0 + hwl) * DPC + c0 + cl] = f2bf(tile[cl][hwl]);
    }
}

// ---------------------------------------------------------------------------
// Final BN stats over f32 out, 1024 threads, wave-per-batch.
// ---------------------------------------------------------------------------
__global__ __launch_bounds__(1024) void bnstats_k(const float* __restrict__ a,
                                                  const float* __restrict__ gamma,
                                                  const float* __restrict__ beta,
                                                  float* __restrict__ scale,
                                                  float* __restrict__ shift) {
    const int c = blockIdx.x;
    const int t = threadIdx.x;
    const int wv = t >> 6, lane = t & 63;
    const float* p = a + ((size_t)wv * COUTC + c) * HWS;
    float s = 0.f, s2 = 0.f;
#pragma unroll
    for (int k = 0; k < 16; ++k) {
        float4 v = *reinterpret_cast<const float4*>(p + lane * 4 + k * 256);
        s += v.x + v.y + v.z + v.w;
        s2 += v.x * v.x + v.y * v.y + v.z * v.z + v.w * v.w;
    }
#pragma unroll
    for (int off = 32; off > 0; off >>= 1) {
        s += __shfl_down(s, off, 64);
        s2 += __shfl_down(s2, off, 64);
    }
    __shared__ float t1[16], t2[16];
    if (lane == 0) { t1[wv] = s; t2[wv] = s2; }
    __syncthreads();
    if (t == 0) {
        float S = 0.f, S2 = 0.f;
#pragma unroll
        for (int k = 0; k < 16; ++k) { S += t1[k]; S2 += t2[k]; }
        float n = (float)(NB * HWS);
        float mean = S / n;
        float var = S2 / n - mean * mean;
        float invs = rsqrtf(var + BN_EPS);
        float sc = invs * gamma[c];
        scale[c] = sc;
        shift[c] = beta[c] - mean * sc;
    }
}

// Final: out = relu(out*scale + shift) in place
__global__ __launch_bounds__(256) void final_k(float* __restrict__ out,
                                               const float* __restrict__ scale,
                                               const float* __restrict__ shift) {
    int i = blockIdx.x * 256 + threadIdx.x;
    int c = (i >> 12) & (COUTC - 1);
    float v = out[i] * scale[c] + shift[c];
    out[i] = fmaxf(v, 0.f);
}

extern "C" void kernel_launch(void* const* d_in, const int* in_sizes, int n_in,
                              void* d_out, int out_size, void* d_ws, size_t ws_size,
                              hipStream_t stream) {
    const float* x           = (const float*)d_in[0];
    const float* pre_w       = (const float*)d_in[1];
    const float* pre_b       = (const float*)d_in[2];
    const float* sigma       = (const float*)d_in[3];
    const float* offsets     = (const float*)d_in[4];
    const float* atten_w     = (const float*)d_in[5];
    const float* atten_b     = (const float*)d_in[6];
    const float* atten_gamma = (const float*)d_in[7];
    const float* atten_beta  = (const float*)d_in[8];
    const float* post_w      = (const float*)d_in[9];
    const float* post_b      = (const float*)d_in[10];
    const float* bn_gamma    = (const float*)d_in[11];
    const float* bn_beta     = (const float*)d_in[12];
    float* out = (float*)d_out;

    // Workspace (MiB offsets), peak 226 MiB.
    char* wsb = (char*)d_ws;
    ushort* xT    = (ushort*)(wsb);
    ushort* wbig  = (ushort*)(wsb + ((size_t)32 << 20));
    ushort* wpost = wbig + 1024 * 256;
    float*  stats = (float*)(wsb + ((size_t)33 << 20));
    ushort* dpout = (ushort*)(wsb + ((size_t)34 << 20));
    ushort* mT    = (ushort*)(wsb + ((size_t)162 << 20));

    float* scaleA = stats;          // 512
    float* shiftA = stats + 512;    // 512
    float* rsum   = stats + 1024;   // 8192
    float* scale2 = stats + 9216;   // 256
    float* shift2 = stats + 9472;   // 256

    // 0. casts / transposes
    castT_k<<<dim3(64, 4, NB), 256, 0, stream>>>(x, xT);
    cast_k<<<128, 256, 0, stream>>>(pre_w,   wbig,             DPC * CINC);
    cast_k<<<128, 256, 0, stream>>>(atten_w, wbig + 512 * 256, DPC * CINC);
    cast_k<<<128, 256, 0, stream>>>(post_w,  wpost,            COUTC * DPC);

    // 1. FUSED pre+atten conv1x1 (MFMA, gload_lds) -> dpout
    mfma_gemm_k<1024, CINC, true, false><<<dim3(32, 8, NB), 256, 0, stream>>>(
        wbig, xT, pre_b, atten_b, nullptr, dpout);
    // 2. fused dynamic pool + displace, in place on pre half
    pooldisp_k<<<NB * DPC, 256, 0, stream>>>(dpout, sigma, offsets);
    // 3. FUSED BN stats + softplus spatial sums (atten)
    attstats_k<<<DPC, 1024, 0, stream>>>(dpout, atten_gamma, atten_beta,
                                         scaleA, shiftA, rsum);
    // 4. attmul, transposed -> mT
    attmulT_k<<<dim3(64, 8, NB), 256, 0, stream>>>(dpout, scaleA, shiftA, rsum, mT);
    // 5. post conv1x1 (MFMA, gload_lds) + skip -> out (f32)
    mfma_gemm_k<COUTC, DPC, false, true><<<dim3(32, 2, NB), 256, 0, stream>>>(
        wpost, mT, post_b, post_b, x, out);
    // 6. final BN stats (wave-per-batch)
    bnstats_k<<<COUTC, 1024, 0, stream>>>(out, bn_gamma, bn_beta, scale2, shift2);
    // 7. relu(bn) in place
    final_k<<<out_size / 256, 256, 0, stream>>>(out, scale2, shift2);
}

// Round 9
// 297.937 us; speedup vs baseline: 3.6914x; 1.0244x over previous
//
#include <hip/hip_runtime.h>
#include <cmath>

#define NB   16
#define CINC 256
#define DPC  512
#define COUTC 256
#define HWS  4096
#define EPSF 1.1920928955078125e-07f
#define BN_EPS 1e-5f
#define EXP_CLAMP 88.722835f
#define TS 76   // pooldisp tmp f32 stride
#define PS 72   // pooldisp pl ushort stride

typedef unsigned int uint32;
typedef unsigned short ushort;
typedef __bf16 bf16x8 __attribute__((ext_vector_type(8)));
typedef float f32x4 __attribute__((ext_vector_type(4)));
typedef unsigned short ushort8 __attribute__((ext_vector_type(8)));

__device__ inline ushort f2bf(float f) {          // native RNE cvt (1 VALU op)
    __bf16 h = (__bf16)f;
    return __builtin_bit_cast(ushort, h);
}
__device__ inline float bf2f(ushort u) {
    return __builtin_bit_cast(float, (uint32)u << 16);
}
__device__ inline float softplus_fast(float v) {
    return fmaxf(v, 0.f) + __logf(1.f + __expf(-fabsf(v)));
}
__device__ __forceinline__ void gload16(const void* g, void* l) {
    __builtin_amdgcn_global_load_lds(
        (__attribute__((address_space(1))) void*)g,
        (__attribute__((address_space(3))) void*)l, 16, 0, 0);
}

// ---------------------------------------------------------------------------
// MFMA bf16 GEMM, global_load_lds staging, BK=64 (two 32-K slabs, each with
// the proven source-side slot permutation slot ^= (row>>1)&3).
// out[b][o][hw] = bias[o] + sum_k A[o][k] * BT[b][hw][k]  (+skip)
// 128x128 tile, 4 waves.  grid (HWS/128, OTOT/128, NB), block 256.
// ---------------------------------------------------------------------------
template<int OTOT, int KTOT, bool BF16_OUT, bool ADD_SKIP>
__global__ __launch_bounds__(256) void mfma_gemm_k(
    const ushort* __restrict__ A, const ushort* __restrict__ BT,
    const float* __restrict__ bias1, const float* __restrict__ bias2,
    const float* __restrict__ skip, void* __restrict__ outv) {
    const int hw0 = blockIdx.x * 128;
    const int o0  = blockIdx.y * 128;
    const int b   = blockIdx.z;
    __shared__ ushort As[2 * 128 * 32];   // [slab][row][32]
    __shared__ ushort Bs[2 * 128 * 32];
    const int tid  = threadIdx.x;
    const int lane = tid & 63;
    const int w    = tid >> 6;
    const int wm0  = (w >> 1) * 64;
    const int wn0  = (w & 1) * 64;

    f32x4 acc[4][4] = {};

    const ushort* Ab = A + (size_t)o0 * KTOT;
    const ushort* Bb = BT + ((size_t)b * HWS + hw0) * KTOT;
    const int rsub  = lane >> 2;
    const int ksubp = ((lane & 3) ^ ((lane >> 3) & 3)) * 8;

    for (int step = 0; step < KTOT / 64; ++step) {
        const int k0 = step * 64;
#pragma unroll
        for (int h = 0; h < 2; ++h)
#pragma unroll
            for (int i = 0; i < 2; ++i) {
                const int row = w * 32 + i * 16 + rsub;
                gload16(Ab + (size_t)row * KTOT + k0 + h * 32 + ksubp,
                        &As[h * 4096 + (w * 32 + i * 16) * 32]);
                gload16(Bb + (size_t)row * KTOT + k0 + h * 32 + ksubp,
                        &Bs[h * 4096 + (w * 32 + i * 16) * 32]);
            }
        __syncthreads();
        bf16x8 af[2][4], bfr[2][4];
#pragma unroll
        for (int h = 0; h < 2; ++h) {
#pragma unroll
            for (int mi = 0; mi < 4; ++mi) {
                int row = wm0 + mi * 16 + (lane & 15);
                int sl = (lane >> 4) ^ ((row >> 1) & 3);
                af[h][mi] = *reinterpret_cast<const bf16x8*>(As + h * 4096 + row * 32 + sl * 8);
            }
#pragma unroll
            for (int ni = 0; ni < 4; ++ni) {
                int row = wn0 + ni * 16 + (lane & 15);
                int sl = (lane >> 4) ^ ((row >> 1) & 3);
                bfr[h][ni] = *reinterpret_cast<const bf16x8*>(Bs + h * 4096 + row * 32 + sl * 8);
            }
        }
#pragma unroll
        for (int h = 0; h < 2; ++h)
#pragma unroll
            for (int mi = 0; mi < 4; ++mi)
#pragma unroll
                for (int ni = 0; ni < 4; ++ni)
                    acc[mi][ni] = __builtin_amdgcn_mfma_f32_16x16x32_bf16(
                        af[h][mi], bfr[h][ni], acc[mi][ni], 0, 0, 0);
        __syncthreads();
    }

#pragma unroll
    for (int mi = 0; mi < 4; ++mi) {
#pragma unroll
        for (int r = 0; r < 4; ++r) {
            int o = o0 + wm0 + mi * 16 + ((lane >> 4) << 2) + r;
            float bi = (o < 512) ? bias1[o] : bias2[o - 512];
            size_t base = ((size_t)b * OTOT + o) * HWS + hw0 + wn0 + (lane & 15);
            if constexpr (BF16_OUT) {
                ushort* outp = (ushort*)outv;
#pragma unroll
                for (int ni = 0; ni < 4; ++ni)
                    outp[base + ni * 16] = f2bf(acc[mi][ni][r] + bi);
            } else {
                float* outp = (float*)outv;
#pragma unroll
                for (int ni = 0; ni < 4; ++ni) {
                    float v = acc[mi][ni][r] + bi;
                    if constexpr (ADD_SKIP) v += skip[base + ni * 16];
                    outp[base + ni * 16] = v;
                }
            }
        }
    }
}

// ---------------------------------------------------------------------------
// x [B][256][HW] f32  ->  xT [B][HW][256] bf16
// ---------------------------------------------------------------------------
__global__ __launch_bounds__(256) void castT_k(const float* __restrict__ x,
                                               ushort* __restrict__ xT) {
    const int b = blockIdx.z, c0 = blockIdx.y * 64, hw0 = blockIdx.x * 64;
    __shared__ float tile[64][65];
    const int tid = threadIdx.x;
#pragma unroll
    for (int r = 0; r < 16; ++r) {
        int cl = r * 4 + (tid >> 6), hwl = tid & 63;
        tile[cl][hwl] = x[((size_t)b * CINC + c0 + cl) * HWS + hw0 + hwl];
    }
    __syncthreads();
#pragma unroll
    for (int r = 0; r < 16; ++r) {
        int hwl = r * 4 + (tid >> 6), cl = tid & 63;
        xT[((size_t)b * HWS + hw0 + hwl) * CINC + c0 + cl] = f2bf(tile[cl][hwl]);
    }
}

// generic f32 -> bf16 cast
__global__ __launch_bounds__(256) void cast_k(const float* __restrict__ in,
                                              ushort* __restrict__ out, int n) {
    int i = (blockIdx.x * 256 + threadIdx.x) * 4;
    if (i < n) {
        float4 v = *reinterpret_cast<const float4*>(in + i);
        out[i + 0] = f2bf(v.x); out[i + 1] = f2bf(v.y);
        out[i + 2] = f2bf(v.z); out[i + 3] = f2bf(v.w);
    }
}

// ---------------------------------------------------------------------------
// FUSED dynamic_pool + displace v3: exp+row-pass fused (global->reg->tmp f32),
// col-pass+log -> pl bf16, displace from pl.  2 barriers, 29.2 KB LDS.
// IN PLACE on plane (b,c) of dpout[b][1024][hw], c < 512.
// ---------------------------------------------------------------------------
__global__ __launch_bounds__(256) void pooldisp_k(ushort* __restrict__ dp,
                                                  const float* __restrict__ sigma,
                                                  const float* __restrict__ offsets) {
    const int bc = blockIdx.x;
    const int b = bc >> 9, c = bc & 511;
    __shared__ float  tmp[68 * TS];   // row-conv result, tmp row = plane row + 2
    __shared__ ushort pl[64 * PS];    // pooled log plane (bf16)
    const int tid = threadIdx.x;
    ushort* ip = dp + ((size_t)b * 1024 + c) * HWS;

    float s = sigma[c];
    float inv = 0.5f / (s * s + EPSF);
    float g0 = __expf(-4.f * inv), g1 = __expf(-1.f * inv);
    float gs = g0 + g1 + 1.f + g1 + g0;
    float rnorm = 1.f / (gs * gs);

    // phase 1a: zero tmp pad rows 0,1,66,67
    if (tid < 64) {
        int r = tid >> 4;
        int rr = (r < 2) ? r : 64 + r;   // 0,1,66,67
        int cq = (tid & 15) * 4;
        f32x4 z = {0.f, 0.f, 0.f, 0.f};
        *reinterpret_cast<f32x4*>(&tmp[rr * TS + cq]) = z;
    }
    // phase 1b: fused exp + row conv.  512 tasks (64 rows x 8 col-groups).
#pragma unroll
    for (int t = 0; t < 2; ++t) {
        int task = tid + t * 256;
        int hr = task >> 3, w0 = (task & 7) * 8;
        const ushort* rp = ip + hr * 64 + w0;
        ushort8 mv = *reinterpret_cast<const ushort8*>(rp);
        float e[12];
        e[0] = (w0 > 0) ? __expf(fminf(bf2f(rp[-2]), EXP_CLAMP)) : 0.f;
        e[1] = (w0 > 0) ? __expf(fminf(bf2f(rp[-1]), EXP_CLAMP)) : 0.f;
#pragma unroll
        for (int q = 0; q < 8; ++q)
            e[2 + q] = __expf(fminf(bf2f(mv[q]), EXP_CLAMP));
        e[10] = (w0 < 56) ? __expf(fminf(bf2f(rp[8]), EXP_CLAMP)) : 0.f;
        e[11] = (w0 < 56) ? __expf(fminf(bf2f(rp[9]), EXP_CLAMP)) : 0.f;
        f32x4 o0, o1;
#pragma unroll
        for (int j = 0; j < 4; ++j) {
            o0[j] = g0 * (e[j] + e[j + 4]) + g1 * (e[j + 1] + e[j + 3]) + e[j + 2];
            o1[j] = g0 * (e[j + 4] + e[j + 8]) + g1 * (e[j + 5] + e[j + 7]) + e[j + 6];
        }
        *reinterpret_cast<f32x4*>(&tmp[(hr + 2) * TS + w0]) = o0;
        *reinterpret_cast<f32x4*>(&tmp[(hr + 2) * TS + w0 + 4]) = o1;
    }
    __syncthreads();

    // phase 2: col conv + log -> pl.  1024 tasks (64 rows x 16 quads).
#pragma unroll
    for (int t = 0; t < 4; ++t) {
        int task = tid + t * 256;
        int h = task >> 4, wq = (task & 15) * 4;
        f32x4 t0 = *reinterpret_cast<const f32x4*>(&tmp[(h + 0) * TS + wq]);
        f32x4 t1 = *reinterpret_cast<const f32x4*>(&tmp[(h + 1) * TS + wq]);
        f32x4 t2 = *reinterpret_cast<const f32x4*>(&tmp[(h + 2) * TS + wq]);
        f32x4 t3 = *reinterpret_cast<const f32x4*>(&tmp[(h + 3) * TS + wq]);
        f32x4 t4 = *reinterpret_cast<const f32x4*>(&tmp[(h + 4) * TS + wq]);
        ushort o[4];
#pragma unroll
        for (int j = 0; j < 4; ++j) {
            float v = g0 * (t0[j] + t4[j]) + g1 * (t1[j] + t3[j]) + t2[j];
            o[j] = f2bf(__logf(v * rnorm + EPSF));
        }
        *reinterpret_cast<uint32*>(&pl[h * PS + wq]) =
            (uint32)o[0] | ((uint32)o[1] << 16);
        *reinterpret_cast<uint32*>(&pl[h * PS + wq + 2]) =
            (uint32)o[2] | ((uint32)o[3] << 16);
    }
    __syncthreads();

    // phase 3: displace (bilinear shift, zero pad), write back in place
    int oi = c >> 3;
    float dy = offsets[oi * 2 + 0];
    float dx = offsets[oi * 2 + 1];
    float y0f = floorf(dy), x0f = floorf(dx);
    float fy = dy - y0f, fx = dx - x0f;
    int y0 = (int)y0f, x0 = (int)x0f;
    float w00 = (1.f - fy) * (1.f - fx), w01 = (1.f - fy) * fx;
    float w10 = fy * (1.f - fx),         w11 = fy * fx;
#pragma unroll
    for (int t = 0; t < 2; ++t) {
        int p = (tid + t * 256) * 8;
        int h = p >> 6, w = p & 63;
        int ry0 = h + y0, ry1 = ry0 + 1;
        bool my0 = (ry0 >= 0) & (ry0 < 64);
        bool my1 = (ry1 >= 0) & (ry1 < 64);
        ushort8 ov;
#pragma unroll
        for (int q = 0; q < 8; ++q) {
            int rx0 = w + q + x0, rx1 = rx0 + 1;
            bool mx0 = (rx0 >= 0) & (rx0 < 64);
            bool mx1 = (rx1 >= 0) & (rx1 < 64);
            float acc = 0.f;
            if (my0 & mx0) acc += w00 * bf2f(pl[ry0 * PS + rx0]);
            if (my0 & mx1) acc += w01 * bf2f(pl[ry0 * PS + rx1]);
            if (my1 & mx0) acc += w10 * bf2f(pl[ry1 * PS + rx0]);
            if (my1 & mx1) acc += w11 * bf2f(pl[ry1 * PS + rx1]);
            ov[q] = f2bf(acc);
        }
        *reinterpret_cast<ushort8*>(ip + p) = ov;
    }
}

// ---------------------------------------------------------------------------
// FUSED BN stats + softplus spatial sums (att half), 1024 threads,
// wave-per-batch, plane kept in registers between phases.
// ---------------------------------------------------------------------------
__global__ __launch_bounds__(1024) void attstats_k(const ushort* __restrict__ dp,
                                                   const float* __restrict__ gamma,
                                                   const float* __restrict__ beta,
                                                   float* __restrict__ scale,
                                                   float* __restrict__ shift,
                                                   float* __restrict__ rsum) {
    const int c = blockIdx.x;
    const int t = threadIdx.x;
    const int wv = t >> 6, lane = t & 63;
    const ushort* p = dp + ((size_t)wv * 1024 + 512 + c) * HWS;

    ushort8 v[8];
    float s = 0.f, s2 = 0.f;
#pragma unroll
    for (int k = 0; k < 8; ++k) {
        v[k] = *reinterpret_cast<const ushort8*>(p + lane * 8 + k * 512);
#pragma unroll
        for (int j = 0; j < 8; ++j) { float f = bf2f(v[k][j]); s += f; s2 += f * f; }
    }
#pragma unroll
    for (int off = 32; off > 0; off >>= 1) {
        s += __shfl_down(s, off, 64);
        s2 += __shfl_down(s2, off, 64);
    }
    __shared__ float t1[16], t2[16], scsh[2];
    if (lane == 0) { t1[wv] = s; t2[wv] = s2; }
    __syncthreads();
    if (t == 0) {
        float S = 0.f, S2 = 0.f;
#pragma unroll
        for (int k = 0; k < 16; ++k) { S += t1[k]; S2 += t2[k]; }
        float n = (float)(NB * HWS);
        float mean = S / n;
        float var = S2 / n - mean * mean;
        float invs = rsqrtf(var + BN_EPS);
        float sc = invs * gamma[c];
        float sh = beta[c] - mean * sc;
        scale[c] = sc; shift[c] = sh;
        scsh[0] = sc; scsh[1] = sh;
    }
    __syncthreads();
    float sc = scsh[0], sh = scsh[1];
    float ps = 0.f;
#pragma unroll
    for (int k = 0; k < 8; ++k)
#pragma unroll
        for (int j = 0; j < 8; ++j)
            ps += softplus_fast(bf2f(v[k][j]) * sc + sh);
#pragma unroll
    for (int off = 32; off > 0; off >>= 1) ps += __shfl_down(ps, off, 64);
    if (lane == 0) rsum[wv * DPC + c] = 1.f / ps;
}

// ---------------------------------------------------------------------------
// m = softplus(bn(att)) * rsum * disp, transposed via LDS -> mT[b][hw][512]
// ---------------------------------------------------------------------------
__global__ __launch_bounds__(256) void attmulT_k(const ushort* __restrict__ dp,
                                                 const float* __restrict__ scale,
                                                 const float* __restrict__ shift,
                                                 const float* __restrict__ rsum,
                                                 ushort* __restrict__ mT) {
    const int b = blockIdx.z, c0 = blockIdx.y * 64, hw0 = blockIdx.x * 64;
    __shared__ float tile[64][65];
    const int tid = threadIdx.x;
#pragma unroll
    for (int r = 0; r < 16; ++r) {
        int cl = r * 4 + (tid >> 6), hwl = tid & 63;
        int c = c0 + cl;
        size_t aidx = ((size_t)b * 1024 + 512 + c) * HWS + hw0 + hwl;
        size_t didx = ((size_t)b * 1024 + c) * HWS + hw0 + hwl;
        float a = bf2f(dp[aidx]) * scale[c] + shift[c];
        float m = softplus_fast(a) * rsum[b * DPC + c] * bf2f(dp[didx]);
        tile[cl][hwl] = m;
    }
    __syncthreads();
#pragma unroll
    for (int r = 0; r < 16; ++r) {
        int hwl = r * 4 + (tid >> 6), cl = tid & 63;
        mT[((size_t)b * HWS + hw0 + hwl) * DPC + c0 + cl] = f2bf(tile[cl][hwl]);
    }
}

// ---------------------------------------------------------------------------
// Final BN stats over f32 out, 1024 threads, wave-per-batch.
// ---------------------------------------------------------------------------
__global__ __launch_bounds__(1024) void bnstats_k(const float* __restrict__ a,
                                                  const float* __restrict__ gamma,
                                                  const float* __restrict__ beta,
                                                  float* __restrict__ scale,
                                                  float* __restrict__ shift) {
    const int c = blockIdx.x;
    const int t = threadIdx.x;
    const int wv = t >> 6, lane = t & 63;
    const float* p = a + ((size_t)wv * COUTC + c) * HWS;
    float s = 0.f, s2 = 0.f;
#pragma unroll
    for (int k = 0; k < 16; ++k) {
        float4 v = *reinterpret_cast<const float4*>(p + lane * 4 + k * 256);
        s += v.x + v.y + v.z + v.w;
        s2 += v.x * v.x + v.y * v.y + v.z * v.z + v.w * v.w;
    }
#pragma unroll
    for (int off = 32; off > 0; off >>= 1) {
        s += __shfl_down(s, off, 64);
        s2 += __shfl_down(s2, off, 64);
    }
    __shared__ float t1[16], t2[16];
    if (lane == 0) { t1[wv] = s; t2[wv] = s2; }
    __syncthreads();
    if (t == 0) {
        float S = 0.f, S2 = 0.f;
#pragma unroll
        for (int k = 0; k < 16; ++k) { S += t1[k]; S2 += t2[k]; }
        float n = (float)(NB * HWS);
        float mean = S / n;
        float var = S2 / n - mean * mean;
        float invs = rsqrtf(var + BN_EPS);
        float sc = invs * gamma[c];
        scale[c] = sc;
        shift[c] = beta[c] - mean * sc;
    }
}

// Final: out = relu(out*scale + shift) in place
__global__ __launch_bounds__(256) void final_k(float* __restrict__ out,
                                               const float* __restrict__ scale,
                                               const float* __restrict__ shift) {
    int i = blockIdx.x * 256 + threadIdx.x;
    int c = (i >> 12) & (COUTC - 1);
    float v = out[i] * scale[c] + shift[c];
    out[i] = fmaxf(v, 0.f);
}

extern "C" void kernel_launch(void* const* d_in, const int* in_sizes, int n_in,
                              void* d_out, int out_size, void* d_ws, size_t ws_size,
                              hipStream_t stream) {
    const float* x           = (const float*)d_in[0];
    const float* pre_w       = (const float*)d_in[1];
    const float* pre_b       = (const float*)d_in[2];
    const float* sigma       = (const float*)d_in[3];
    const float* offsets     = (const float*)d_in[4];
    const float* atten_w     = (const float*)d_in[5];
    const float* atten_b     = (const float*)d_in[6];
    const float* atten_gamma = (const float*)d_in[7];
    const float* atten_beta  = (const float*)d_in[8];
    const float* post_w      = (const float*)d_in[9];
    const float* post_b      = (const float*)d_in[10];
    const float* bn_gamma    = (const float*)d_in[11];
    const float* bn_beta     = (const float*)d_in[12];
    float* out = (float*)d_out;

    // Workspace (MiB offsets), peak 226 MiB.
    char* wsb = (char*)d_ws;
    ushort* xT    = (ushort*)(wsb);
    ushort* wbig  = (ushort*)(wsb + ((size_t)32 << 20));
    ushort* wpost = wbig + 1024 * 256;
    float*  stats = (float*)(wsb + ((size_t)33 << 20));
    ushort* dpout = (ushort*)(wsb + ((size_t)34 << 20));
    ushort* mT    = (ushort*)(wsb + ((size_t)162 << 20));

    float* scaleA = stats;          // 512
    float* shiftA = stats + 512;    // 512
    float* rsum   = stats + 1024;   // 8192
    float* scale2 = stats + 9216;   // 256
    float* shift2 = stats + 9472;   // 256

    // 0. casts / transposes
    castT_k<<<dim3(64, 4, NB), 256, 0, stream>>>(x, xT);
    cast_k<<<128, 256, 0, stream>>>(pre_w,   wbig,             DPC * CINC);
    cast_k<<<128, 256, 0, stream>>>(atten_w, wbig + 512 * 256, DPC * CINC);
    cast_k<<<128, 256, 0, stream>>>(post_w,  wpost,            COUTC * DPC);

    // 1. FUSED pre+atten conv1x1 (MFMA, gload_lds, BK=64) -> dpout
    mfma_gemm_k<1024, CINC, true, false><<<dim3(32, 8, NB), 256, 0, stream>>>(
        wbig, xT, pre_b, atten_b, nullptr, dpout);
    // 2. fused dynamic pool + displace v3, in place on pre half
    pooldisp_k<<<NB * DPC, 256, 0, stream>>>(dpout, sigma, offsets);
    // 3. FUSED BN stats + softplus spatial sums (atten)
    attstats_k<<<DPC, 1024, 0, stream>>>(dpout, atten_gamma, atten_beta,
                                         scaleA, shiftA, rsum);
    // 4. attmul, transposed -> mT
    attmulT_k<<<dim3(64, 8, NB), 256, 0, stream>>>(dpout, scaleA, shiftA, rsum, mT);
    // 5. post conv1x1 (MFMA, gload_lds, BK=64) + skip -> out (f32)
    mfma_gemm_k<COUTC, DPC, false, true><<<dim3(32, 2, NB), 256, 0, stream>>>(
        wpost, mT, post_b, post_b, x, out);
    // 6. final BN stats (wave-per-batch)
    bnstats_k<<<COUTC, 1024, 0, stream>>>(out, bn_gamma, bn_beta, scale2, shift2);
    // 7. relu(bn) in place
    final_k<<<out_size / 256, 256, 0, stream>>>(out, scale2, shift2);
}

// Round 10
// 288.117 us; speedup vs baseline: 3.8172x; 1.0341x over previous
//
#include <hip/hip_runtime.h>
#include <cmath>

#define NB   16
#define CINC 256
#define DPC  512
#define COUTC 256
#define HWS  4096
#define EPSF 1.1920928955078125e-07f
#define BN_EPS 1e-5f
#define EXP_CLAMP 88.722835f
#define TS 76   // pooldisp tmp f32 stride
#define PS2 66  // pooldisp pl ushort stride (33 words == 1 mod 32 -> 2-way banks)

typedef unsigned int uint32;
typedef unsigned short ushort;
typedef __bf16 bf16x8 __attribute__((ext_vector_type(8)));
typedef float f32x4 __attribute__((ext_vector_type(4)));
typedef unsigned short ushort8 __attribute__((ext_vector_type(8)));

__device__ inline ushort f2bf(float f) {          // native RNE cvt
    __bf16 h = (__bf16)f;
    return __builtin_bit_cast(ushort, h);
}
__device__ inline float bf2f(ushort u) {
    return __builtin_bit_cast(float, (uint32)u << 16);
}
__device__ inline float softplus_fast(float v) {
    return fmaxf(v, 0.f) + __logf(1.f + __expf(-fabsf(v)));
}
__device__ __forceinline__ void gload16(const void* g, void* l) {
    __builtin_amdgcn_global_load_lds(
        (__attribute__((address_space(1))) void*)g,
        (__attribute__((address_space(3))) void*)l, 16, 0, 0);
}

// ---------------------------------------------------------------------------
// MFMA bf16 GEMM, global_load_lds staging, BK=64 (two 32-K slabs, each with
// source-side slot permutation slot ^= (row>>1)&3).
// out[b][o][hw] = bias[o] + sum_k A[o][k] * BT[b][hw][k]  (+skip)
// 128x128 tile, 4 waves.  grid (HWS/128, OTOT/128, NB), block 256.
// ---------------------------------------------------------------------------
template<int OTOT, int KTOT, bool BF16_OUT, bool ADD_SKIP>
__global__ __launch_bounds__(256) void mfma_gemm_k(
    const ushort* __restrict__ A, const ushort* __restrict__ BT,
    const float* __restrict__ bias1, const float* __restrict__ bias2,
    const float* __restrict__ skip, void* __restrict__ outv) {
    const int hw0 = blockIdx.x * 128;
    const int o0  = blockIdx.y * 128;
    const int b   = blockIdx.z;
    __shared__ ushort As[2 * 128 * 32];
    __shared__ ushort Bs[2 * 128 * 32];
    const int tid  = threadIdx.x;
    const int lane = tid & 63;
    const int w    = tid >> 6;
    const int wm0  = (w >> 1) * 64;
    const int wn0  = (w & 1) * 64;

    f32x4 acc[4][4] = {};

    const ushort* Ab = A + (size_t)o0 * KTOT;
    const ushort* Bb = BT + ((size_t)b * HWS + hw0) * KTOT;
    const int rsub  = lane >> 2;
    const int ksubp = ((lane & 3) ^ ((lane >> 3) & 3)) * 8;

    for (int step = 0; step < KTOT / 64; ++step) {
        const int k0 = step * 64;
#pragma unroll
        for (int h = 0; h < 2; ++h)
#pragma unroll
            for (int i = 0; i < 2; ++i) {
                const int row = w * 32 + i * 16 + rsub;
                gload16(Ab + (size_t)row * KTOT + k0 + h * 32 + ksubp,
                        &As[h * 4096 + (w * 32 + i * 16) * 32]);
                gload16(Bb + (size_t)row * KTOT + k0 + h * 32 + ksubp,
                        &Bs[h * 4096 + (w * 32 + i * 16) * 32]);
            }
        __syncthreads();
        bf16x8 af[2][4], bfr[2][4];
#pragma unroll
        for (int h = 0; h < 2; ++h) {
#pragma unroll
            for (int mi = 0; mi < 4; ++mi) {
                int row = wm0 + mi * 16 + (lane & 15);
                int sl = (lane >> 4) ^ ((row >> 1) & 3);
                af[h][mi] = *reinterpret_cast<const bf16x8*>(As + h * 4096 + row * 32 + sl * 8);
            }
#pragma unroll
            for (int ni = 0; ni < 4; ++ni) {
                int row = wn0 + ni * 16 + (lane & 15);
                int sl = (lane >> 4) ^ ((row >> 1) & 3);
                bfr[h][ni] = *reinterpret_cast<const bf16x8*>(Bs + h * 4096 + row * 32 + sl * 8);
            }
        }
#pragma unroll
        for (int h = 0; h < 2; ++h)
#pragma unroll
            for (int mi = 0; mi < 4; ++mi)
#pragma unroll
                for (int ni = 0; ni < 4; ++ni)
                    acc[mi][ni] = __builtin_amdgcn_mfma_f32_16x16x32_bf16(
                        af[h][mi], bfr[h][ni], acc[mi][ni], 0, 0, 0);
        __syncthreads();
    }

#pragma unroll
    for (int mi = 0; mi < 4; ++mi) {
#pragma unroll
        for (int r = 0; r < 4; ++r) {
            int o = o0 + wm0 + mi * 16 + ((lane >> 4) << 2) + r;
            float bi = (o < 512) ? bias1[o] : bias2[o - 512];
            size_t base = ((size_t)b * OTOT + o) * HWS + hw0 + wn0 + (lane & 15);
            if constexpr (BF16_OUT) {
                ushort* outp = (ushort*)outv;
#pragma unroll
                for (int ni = 0; ni < 4; ++ni)
                    outp[base + ni * 16] = f2bf(acc[mi][ni][r] + bi);
            } else {
                float* outp = (float*)outv;
#pragma unroll
                for (int ni = 0; ni < 4; ++ni) {
                    float v = acc[mi][ni][r] + bi;
                    if constexpr (ADD_SKIP) v += skip[base + ni * 16];
                    outp[base + ni * 16] = v;
                }
            }
        }
    }
}

// ---------------------------------------------------------------------------
// x [B][256][HW] f32  ->  xT [B][HW][256] bf16
// ---------------------------------------------------------------------------
__global__ __launch_bounds__(256) void castT_k(const float* __restrict__ x,
                                               ushort* __restrict__ xT) {
    const int b = blockIdx.z, c0 = blockIdx.y * 64, hw0 = blockIdx.x * 64;
    __shared__ float tile[64][65];
    const int tid = threadIdx.x;
#pragma unroll
    for (int r = 0; r < 16; ++r) {
        int cl = r * 4 + (tid >> 6), hwl = tid & 63;
        tile[cl][hwl] = x[((size_t)b * CINC + c0 + cl) * HWS + hw0 + hwl];
    }
    __syncthreads();
#pragma unroll
    for (int r = 0; r < 16; ++r) {
        int hwl = r * 4 + (tid >> 6), cl = tid & 63;
        xT[((size_t)b * HWS + hw0 + hwl) * CINC + c0 + cl] = f2bf(tile[cl][hwl]);
    }
}

// generic f32 -> bf16 cast
__global__ __launch_bounds__(256) void cast_k(const float* __restrict__ in,
                                              ushort* __restrict__ out, int n) {
    int i = (blockIdx.x * 256 + threadIdx.x) * 4;
    if (i < n) {
        float4 v = *reinterpret_cast<const float4*>(in + i);
        out[i + 0] = f2bf(v.x); out[i + 1] = f2bf(v.y);
        out[i + 2] = f2bf(v.z); out[i + 3] = f2bf(v.w);
    }
}

// ---------------------------------------------------------------------------
// FUSED dynamic_pool + displace v4: 512 threads (100% occupancy at 4 blk/CU),
// exp+row-pass fused -> tmp f32; col-pass+log -> pl bf16 (stride 66: 2-way
// banks); displace with 9-tap register reuse (18 scalar LDS reads/thread).
// IN PLACE on plane (b,c) of dpout[b][1024][hw], c < 512.
// ---------------------------------------------------------------------------
__global__ __launch_bounds__(512, 8) void pooldisp_k(ushort* __restrict__ dp,
                                                     const float* __restrict__ sigma,
                                                     const float* __restrict__ offsets) {
    const int bc = blockIdx.x;
    const int b = bc >> 9, c = bc & 511;
    __shared__ float  tmp[68 * TS];    // row-conv result; tmp row = plane row + 2
    __shared__ ushort pl[64 * PS2];    // pooled log plane (bf16)
    const int tid = threadIdx.x;
    ushort* ip = dp + ((size_t)b * 1024 + c) * HWS;

    float s = sigma[c];
    float inv = 0.5f / (s * s + EPSF);
    float g0 = __expf(-4.f * inv), g1 = __expf(-1.f * inv);
    float gs = g0 + g1 + 1.f + g1 + g0;
    float rnorm = 1.f / (gs * gs);

    // phase 1a: zero tmp pad rows 0,1,66,67
    {
        int r4 = tid >> 7, col = tid & 127;
        if (col < TS) {
            int row = (r4 < 2) ? r4 : 64 + r4;   // 0,1,66,67
            tmp[row * TS + col] = 0.f;
        }
    }
    // phase 1b: fused exp + row conv (512 tasks, 8-wide each)
    {
        int hr = tid >> 3, w0 = (tid & 7) * 8;
        const ushort* rp = ip + hr * 64 + w0;
        ushort8 mv = *reinterpret_cast<const ushort8*>(rp);
        float e[12];
        e[0] = (w0 > 0) ? __expf(fminf(bf2f(rp[-2]), EXP_CLAMP)) : 0.f;
        e[1] = (w0 > 0) ? __expf(fminf(bf2f(rp[-1]), EXP_CLAMP)) : 0.f;
#pragma unroll
        for (int q = 0; q < 8; ++q)
            e[2 + q] = __expf(fminf(bf2f(mv[q]), EXP_CLAMP));
        e[10] = (w0 < 56) ? __expf(fminf(bf2f(rp[8]), EXP_CLAMP)) : 0.f;
        e[11] = (w0 < 56) ? __expf(fminf(bf2f(rp[9]), EXP_CLAMP)) : 0.f;
        f32x4 o0, o1;
#pragma unroll
        for (int j = 0; j < 4; ++j) {
            o0[j] = g0 * (e[j] + e[j + 4]) + g1 * (e[j + 1] + e[j + 3]) + e[j + 2];
            o1[j] = g0 * (e[j + 4] + e[j + 8]) + g1 * (e[j + 5] + e[j + 7]) + e[j + 6];
        }
        *reinterpret_cast<f32x4*>(&tmp[(hr + 2) * TS + w0]) = o0;
        *reinterpret_cast<f32x4*>(&tmp[(hr + 2) * TS + w0 + 4]) = o1;
    }
    __syncthreads();

    // phase 2: col conv + log -> pl (1024 tasks: 64 rows x 16 quads)
#pragma unroll
    for (int t = 0; t < 2; ++t) {
        int task = tid + t * 512;
        int h = task >> 4, wq = (task & 15) * 4;
        f32x4 t0 = *reinterpret_cast<const f32x4*>(&tmp[(h + 0) * TS + wq]);
        f32x4 t1 = *reinterpret_cast<const f32x4*>(&tmp[(h + 1) * TS + wq]);
        f32x4 t2 = *reinterpret_cast<const f32x4*>(&tmp[(h + 2) * TS + wq]);
        f32x4 t3 = *reinterpret_cast<const f32x4*>(&tmp[(h + 3) * TS + wq]);
        f32x4 t4 = *reinterpret_cast<const f32x4*>(&tmp[(h + 4) * TS + wq]);
        ushort o[4];
#pragma unroll
        for (int j = 0; j < 4; ++j) {
            float v = g0 * (t0[j] + t4[j]) + g1 * (t1[j] + t3[j]) + t2[j];
            o[j] = f2bf(__logf(v * rnorm + EPSF));
        }
        *reinterpret_cast<uint32*>(&pl[h * PS2 + wq]) =
            (uint32)o[0] | ((uint32)o[1] << 16);
        *reinterpret_cast<uint32*>(&pl[h * PS2 + wq + 2]) =
            (uint32)o[2] | ((uint32)o[3] << 16);
    }
    __syncthreads();

    // phase 3: displace with 9-tap register reuse; write back in place
    {
        int oi = c >> 3;
        float dy = offsets[oi * 2 + 0];
        float dx = offsets[oi * 2 + 1];
        float y0f = floorf(dy), x0f = floorf(dx);
        float fy = dy - y0f, fx = dx - x0f;
        int y0 = (int)y0f, x0 = (int)x0f;
        float w00 = (1.f - fy) * (1.f - fx), w01 = (1.f - fy) * fx;
        float w10 = fy * (1.f - fx),         w11 = fy * fx;
        int h = tid >> 3, w = (tid & 7) * 8;
        int ry0 = h + y0, ry1 = ry0 + 1;
        bool my0 = (ry0 >= 0) & (ry0 < 64);
        bool my1 = (ry1 >= 0) & (ry1 < 64);
        float e0[9], e1[9];
#pragma unroll
        for (int j = 0; j < 9; ++j) {
            int col = w + x0 + j;
            bool mx = (col >= 0) & (col < 64);
            e0[j] = (my0 & mx) ? bf2f(pl[ry0 * PS2 + col]) : 0.f;
            e1[j] = (my1 & mx) ? bf2f(pl[ry1 * PS2 + col]) : 0.f;
        }
        ushort8 ov;
#pragma unroll
        for (int q = 0; q < 8; ++q)
            ov[q] = f2bf(w00 * e0[q] + w01 * e0[q + 1]
                       + w10 * e1[q] + w11 * e1[q + 1]);
        *reinterpret_cast<ushort8*>(ip + tid * 8) = ov;
    }
}

// ---------------------------------------------------------------------------
// FUSED BN stats + softplus spatial sums (att half), 1024 threads,
// wave-per-batch, plane kept in registers between phases.
// ---------------------------------------------------------------------------
__global__ __launch_bounds__(1024) void attstats_k(const ushort* __restrict__ dp,
                                                   const float* __restrict__ gamma,
                                                   const float* __restrict__ beta,
                                                   float* __restrict__ scale,
                                                   float* __restrict__ shift,
                                                   float* __restrict__ rsum) {
    const int c = blockIdx.x;
    const int t = threadIdx.x;
    const int wv = t >> 6, lane = t & 63;
    const ushort* p = dp + ((size_t)wv * 1024 + 512 + c) * HWS;

    ushort8 v[8];
    float s = 0.f, s2 = 0.f;
#pragma unroll
    for (int k = 0; k < 8; ++k) {
        v[k] = *reinterpret_cast<const ushort8*>(p + lane * 8 + k * 512);
#pragma unroll
        for (int j = 0; j < 8; ++j) { float f = bf2f(v[k][j]); s += f; s2 += f * f; }
    }
#pragma unroll
    for (int off = 32; off > 0; off >>= 1) {
        s += __shfl_down(s, off, 64);
        s2 += __shfl_down(s2, off, 64);
    }
    __shared__ float t1[16], t2[16], scsh[2];
    if (lane == 0) { t1[wv] = s; t2[wv] = s2; }
    __syncthreads();
    if (t == 0) {
        float S = 0.f, S2 = 0.f;
#pragma unroll
        for (int k = 0; k < 16; ++k) { S += t1[k]; S2 += t2[k]; }
        float n = (float)(NB * HWS);
        float mean = S / n;
        float var = S2 / n - mean * mean;
        float invs = rsqrtf(var + BN_EPS);
        float sc = invs * gamma[c];
        float sh = beta[c] - mean * sc;
        scale[c] = sc; shift[c] = sh;
        scsh[0] = sc; scsh[1] = sh;
    }
    __syncthreads();
    float sc = scsh[0], sh = scsh[1];
    float ps = 0.f;
#pragma unroll
    for (int k = 0; k < 8; ++k)
#pragma unroll
        for (int j = 0; j < 8; ++j)
            ps += softplus_fast(bf2f(v[k][j]) * sc + sh);
#pragma unroll
    for (int off = 32; off > 0; off >>= 1) ps += __shfl_down(ps, off, 64);
    if (lane == 0) rsum[wv * DPC + c] = 1.f / ps;
}

// ---------------------------------------------------------------------------
// m = softplus(bn(att)) * rsum * disp, transposed via LDS -> mT[b][hw][512]
// ---------------------------------------------------------------------------
__global__ __launch_bounds__(256) void attmulT_k(const ushort* __restrict__ dp,
                                                 const float* __restrict__ scale,
                                                 const float* __restrict__ shift,
                                                 const float* __restrict__ rsum,
                                                 ushort* __restrict__ mT) {
    const int b = blockIdx.z, c0 = blockIdx.y * 64, hw0 = blockIdx.x * 64;
    __shared__ float tile[64][65];
    const int tid = threadIdx.x;
#pragma unroll
    for (int r = 0; r < 16; ++r) {
        int cl = r * 4 + (tid >> 6), hwl = tid & 63;
        int c = c0 + cl;
        size_t aidx = ((size_t)b * 1024 + 512 + c) * HWS + hw0 + hwl;
        size_t didx = ((size_t)b * 1024 + c) * HWS + hw0 + hwl;
        float a = bf2f(dp[aidx]) * scale[c] + shift[c];
        float m = softplus_fast(a) * rsum[b * DPC + c] * bf2f(dp[didx]);
        tile[cl][hwl] = m;
    }
    __syncthreads();
#pragma unroll
    for (int r = 0; r < 16; ++r) {
        int hwl = r * 4 + (tid >> 6), cl = tid & 63;
        mT[((size_t)b * HWS + hw0 + hwl) * DPC + c0 + cl] = f2bf(tile[cl][hwl]);
    }
}

// ---------------------------------------------------------------------------
// Final BN stats over f32 out, 1024 threads, wave-per-batch.
// ---------------------------------------------------------------------------
__global__ __launch_bounds__(1024) void bnstats_k(const float* __restrict__ a,
                                                  const float* __restrict__ gamma,
                                                  const float* __restrict__ beta,
                                                  float* __restrict__ scale,
                                                  float* __restrict__ shift) {
    const int c = blockIdx.x;
    const int t = threadIdx.x;
    const int wv = t >> 6, lane = t & 63;
    const float* p = a + ((size_t)wv * COUTC + c) * HWS;
    float s = 0.f, s2 = 0.f;
#pragma unroll
    for (int k = 0; k < 16; ++k) {
        float4 v = *reinterpret_cast<const float4*>(p + lane * 4 + k * 256);
        s += v.x + v.y + v.z + v.w;
        s2 += v.x * v.x + v.y * v.y + v.z * v.z + v.w * v.w;
    }
#pragma unroll
    for (int off = 32; off > 0; off >>= 1) {
        s += __shfl_down(s, off, 64);
        s2 += __shfl_down(s2, off, 64);
    }
    __shared__ float t1[16], t2[16];
    if (lane == 0) { t1[wv] = s; t2[wv] = s2; }
    __syncthreads();
    if (t == 0) {
        float S = 0.f, S2 = 0.f;
#pragma unroll
        for (int k = 0; k < 16; ++k) { S += t1[k]; S2 += t2[k]; }
        float n = (float)(NB * HWS);
        float mean = S / n;
        float var = S2 / n - mean * mean;
        float invs = rsqrtf(var + BN_EPS);
        float sc = invs * gamma[c];
        scale[c] = sc;
        shift[c] = beta[c] - mean * sc;
    }
}

// Final: out = relu(out*scale + shift) in place
__global__ __launch_bounds__(256) void final_k(float* __restrict__ out,
                                               const float* __restrict__ scale,
                                               const float* __restrict__ shift) {
    int i = blockIdx.x * 256 + threadIdx.x;
    int c = (i >> 12) & (COUTC - 1);
    float v = out[i] * scale[c] + shift[c];
    out[i] = fmaxf(v, 0.f);
}

extern "C" void kernel_launch(void* const* d_in, const int* in_sizes, int n_in,
                              void* d_out, int out_size, void* d_ws, size_t ws_size,
                              hipStream_t stream) {
    const float* x           = (const float*)d_in[0];
    const float* pre_w       = (const float*)d_in[1];
    const float* pre_b       = (const float*)d_in[2];
    const float* sigma       = (const float*)d_in[3];
    const float* offsets     = (const float*)d_in[4];
    const float* atten_w     = (const float*)d_in[5];
    const float* atten_b     = (const float*)d_in[6];
    const float* atten_gamma = (const float*)d_in[7];
    const float* atten_beta  = (const float*)d_in[8];
    const float* post_w      = (const float*)d_in[9];
    const float* post_b      = (const float*)d_in[10];
    const float* bn_gamma    = (const float*)d_in[11];
    const float* bn_beta     = (const float*)d_in[12];
    float* out = (float*)d_out;

    // Workspace (MiB offsets), peak 226 MiB.
    char* wsb = (char*)d_ws;
    ushort* xT    = (ushort*)(wsb);
    ushort* wbig  = (ushort*)(wsb + ((size_t)32 << 20));
    ushort* wpost = wbig + 1024 * 256;
    float*  stats = (float*)(wsb + ((size_t)33 << 20));
    ushort* dpout = (ushort*)(wsb + ((size_t)34 << 20));
    ushort* mT    = (ushort*)(wsb + ((size_t)162 << 20));

    float* scaleA = stats;          // 512
    float* shiftA = stats + 512;    // 512
    float* rsum   = stats + 1024;   // 8192
    float* scale2 = stats + 9216;   // 256
    float* shift2 = stats + 9472;   // 256

    // 0. casts / transposes
    castT_k<<<dim3(64, 4, NB), 256, 0, stream>>>(x, xT);
    cast_k<<<128, 256, 0, stream>>>(pre_w,   wbig,             DPC * CINC);
    cast_k<<<128, 256, 0, stream>>>(atten_w, wbig + 512 * 256, DPC * CINC);
    cast_k<<<128, 256, 0, stream>>>(post_w,  wpost,            COUTC * DPC);

    // 1. FUSED pre+atten conv1x1 (MFMA, gload_lds, BK=64) -> dpout
    mfma_gemm_k<1024, CINC, true, false><<<dim3(32, 8, NB), 256, 0, stream>>>(
        wbig, xT, pre_b, atten_b, nullptr, dpout);
    // 2. fused dynamic pool + displace v4, in place on pre half
    pooldisp_k<<<NB * DPC, 512, 0, stream>>>(dpout, sigma, offsets);
    // 3. FUSED BN stats + softplus spatial sums (atten)
    attstats_k<<<DPC, 1024, 0, stream>>>(dpout, atten_gamma, atten_beta,
                                         scaleA, shiftA, rsum);
    // 4. attmul, transposed -> mT
    attmulT_k<<<dim3(64, 8, NB), 256, 0, stream>>>(dpout, scaleA, shiftA, rsum, mT);
    // 5. post conv1x1 (MFMA, gload_lds, BK=64) + skip -> out (f32)
    mfma_gemm_k<COUTC, DPC, false, true><<<dim3(32, 2, NB), 256, 0, stream>>>(
        wpost, mT, post_b, post_b, x, out);
    // 6. final BN stats (wave-per-batch)
    bnstats_k<<<COUTC, 1024, 0, stream>>>(out, bn_gamma, bn_beta, scale2, shift2);
    // 7. relu(bn) in place
    final_k<<<out_size / 256, 256, 0, stream>>>(out, scale2, shift2);
}

// Round 11
// 276.632 us; speedup vs baseline: 3.9757x; 1.0415x over previous
//
#include <hip/hip_runtime.h>
#include <cmath>

#define NB   16
#define CINC 256
#define DPC  512
#define COUTC 256
#define HWS  4096
#define EPSF 1.1920928955078125e-07f
#define BN_EPS 1e-5f
#define EXP_CLAMP 88.722835f
#define TS 76   // pooldisp tmp f32 stride
#define PS2 66  // pooldisp pl ushort stride (33 words == 1 mod 32 -> 2-way banks)

typedef unsigned int uint32;
typedef unsigned short ushort;
typedef __bf16 bf16x8 __attribute__((ext_vector_type(8)));
typedef float f32x4 __attribute__((ext_vector_type(4)));
typedef unsigned short ushort8 __attribute__((ext_vector_type(8)));

__device__ inline ushort f2bf(float f) {          // native RNE cvt
    __bf16 h = (__bf16)f;
    return __builtin_bit_cast(ushort, h);
}
__device__ inline float bf2f(ushort u) {
    return __builtin_bit_cast(float, (uint32)u << 16);
}
__device__ inline float softplus_fast(float v) {
    return fmaxf(v, 0.f) + __logf(1.f + __expf(-fabsf(v)));
}
__device__ __forceinline__ void gload16(const void* g, void* l) {
    __builtin_amdgcn_global_load_lds(
        (__attribute__((address_space(1))) void*)g,
        (__attribute__((address_space(3))) void*)l, 16, 0, 0);
}

// ---------------------------------------------------------------------------
// MFMA bf16 GEMM, 2-phase double-buffered global_load_lds staging (stage next
// tile BEFORE compute of current; one barrier per step hides HBM latency
// under MFMA).  Conflict-free via source-side slot permutation.
// out[b][o][hw] = bias[o] + sum_k A[o][k] * BT[b][hw][k]
// DUALBIAS: bias split at o=512.  PARTIALS: add f32 skip, write bf16 t, and
// emit per-channel (sum, sumsq) partials for the downstream BN.
// 128x128 tile, BK=32 x2 buffers, 4 waves.  grid (HWS/128, OTOT/128, NB).
// ---------------------------------------------------------------------------
template<int OTOT, int KTOT, bool DUALBIAS, bool PARTIALS>
__global__ __launch_bounds__(256) void mfma_gemm_k(
    const ushort* __restrict__ A, const ushort* __restrict__ BT,
    const float* __restrict__ bias1, const float* __restrict__ bias2,
    const float* __restrict__ skip, ushort* __restrict__ outp,
    float* __restrict__ part_s, float* __restrict__ part_s2) {
    const int hw0 = blockIdx.x * 128;
    const int o0  = blockIdx.y * 128;
    const int b   = blockIdx.z;
    __shared__ ushort As[2][128 * 32];
    __shared__ ushort Bs[2][128 * 32];
    const int tid  = threadIdx.x;
    const int lane = tid & 63;
    const int w    = tid >> 6;
    const int wm0  = (w >> 1) * 64;
    const int wn0  = (w & 1) * 64;

    f32x4 acc[4][4] = {};

    const ushort* Ab = A + (size_t)o0 * KTOT;
    const ushort* Bb = BT + ((size_t)b * HWS + hw0) * KTOT;
    const int rsub  = lane >> 2;
    const int ksubp = ((lane & 3) ^ ((lane >> 3) & 3)) * 8;

    auto stage = [&](int buf, int k0) {
#pragma unroll
        for (int i = 0; i < 2; ++i) {
            const int row = w * 32 + i * 16 + rsub;
            gload16(Ab + (size_t)row * KTOT + k0 + ksubp, &As[buf][(w * 32 + i * 16) * 32]);
            gload16(Bb + (size_t)row * KTOT + k0 + ksubp, &Bs[buf][(w * 32 + i * 16) * 32]);
        }
    };

    constexpr int NSTEP = KTOT / 32;
    stage(0, 0);
    __syncthreads();
    int cur = 0;
    for (int step = 0; step < NSTEP; ++step) {
        if (step + 1 < NSTEP) stage(cur ^ 1, (step + 1) * 32);   // issue early
        bf16x8 af[4], bfr[4];
#pragma unroll
        for (int mi = 0; mi < 4; ++mi) {
            int row = wm0 + mi * 16 + (lane & 15);
            int sl = (lane >> 4) ^ ((row >> 1) & 3);
            af[mi] = *reinterpret_cast<const bf16x8*>(&As[cur][row * 32 + sl * 8]);
        }
#pragma unroll
        for (int ni = 0; ni < 4; ++ni) {
            int row = wn0 + ni * 16 + (lane & 15);
            int sl = (lane >> 4) ^ ((row >> 1) & 3);
            bfr[ni] = *reinterpret_cast<const bf16x8*>(&Bs[cur][row * 32 + sl * 8]);
        }
#pragma unroll
        for (int mi = 0; mi < 4; ++mi)
#pragma unroll
            for (int ni = 0; ni < 4; ++ni)
                acc[mi][ni] = __builtin_amdgcn_mfma_f32_16x16x32_bf16(
                    af[mi], bfr[ni], acc[mi][ni], 0, 0, 0);
        __syncthreads();   // drains prefetch vmcnt after MFMA covered latency
        cur ^= 1;
    }

    // reuse dead staging LDS for partial-sum exchange
    float* pS  = reinterpret_cast<float*>(&As[0][0]);   // [2][128]
    float* pS2 = pS + 256;

    // D frag: col = lane&15 (hw), row = (lane>>4)*4 + r (o).
#pragma unroll
    for (int mi = 0; mi < 4; ++mi) {
#pragma unroll
        for (int r = 0; r < 4; ++r) {
            int chL = wm0 + mi * 16 + ((lane >> 4) << 2) + r;
            int o = o0 + chL;
            float bi;
            if constexpr (DUALBIAS) bi = (o < 512) ? bias1[o] : bias2[o - 512];
            else bi = bias1[o];
            size_t base = ((size_t)b * OTOT + o) * HWS + hw0 + wn0 + (lane & 15);
            float s1 = 0.f, s2 = 0.f;
#pragma unroll
            for (int ni = 0; ni < 4; ++ni) {
                float v = acc[mi][ni][r] + bi;
                if constexpr (PARTIALS) v += skip[base + ni * 16];
                ushort tb = f2bf(v);
                outp[base + ni * 16] = tb;
                if constexpr (PARTIALS) {
                    float vf = bf2f(tb);
                    s1 += vf; s2 += vf * vf;
                }
            }
            if constexpr (PARTIALS) {
#pragma unroll
                for (int off = 1; off <= 8; off <<= 1) {
                    s1 += __shfl_xor(s1, off, 64);
                    s2 += __shfl_xor(s2, off, 64);
                }
                if ((lane & 15) == 0) {
                    pS[(w & 1) * 128 + chL]  = s1;
                    pS2[(w & 1) * 128 + chL] = s2;
                }
            }
        }
    }
    if constexpr (PARTIALS) {
        __syncthreads();
        if (tid < 128) {
            int k = blockIdx.x * NB + b;   // 0..511
            float S  = pS[tid]  + pS[128 + tid];
            float S2 = pS2[tid] + pS2[128 + tid];
            part_s[(size_t)(o0 + tid) * 512 + k]  = S;
            part_s2[(size_t)(o0 + tid) * 512 + k] = S2;
        }
    }
}

// ---------------------------------------------------------------------------
// x [B][256][HW] f32  ->  xT [B][HW][256] bf16
// ---------------------------------------------------------------------------
__global__ __launch_bounds__(256) void castT_k(const float* __restrict__ x,
                                               ushort* __restrict__ xT) {
    const int b = blockIdx.z, c0 = blockIdx.y * 64, hw0 = blockIdx.x * 64;
    __shared__ float tile[64][65];
    const int tid = threadIdx.x;
#pragma unroll
    for (int r = 0; r < 16; ++r) {
        int cl = r * 4 + (tid >> 6), hwl = tid & 63;
        tile[cl][hwl] = x[((size_t)b * CINC + c0 + cl) * HWS + hw0 + hwl];
    }
    __syncthreads();
#pragma unroll
    for (int r = 0; r < 16; ++r) {
        int hwl = r * 4 + (tid >> 6), cl = tid & 63;
        xT[((size_t)b * HWS + hw0 + hwl) * CINC + c0 + cl] = f2bf(tile[cl][hwl]);
    }
}

// generic f32 -> bf16 cast
__global__ __launch_bounds__(256) void cast_k(const float* __restrict__ in,
                                              ushort* __restrict__ out, int n) {
    int i = (blockIdx.x * 256 + threadIdx.x) * 4;
    if (i < n) {
        float4 v = *reinterpret_cast<const float4*>(in + i);
        out[i + 0] = f2bf(v.x); out[i + 1] = f2bf(v.y);
        out[i + 2] = f2bf(v.z); out[i + 3] = f2bf(v.w);
    }
}

// ---------------------------------------------------------------------------
// FUSED dynamic_pool + displace v4: 512 threads, exp+row-pass fused -> tmp
// f32; col-pass+log -> pl bf16 (stride 66); displace with 9-tap reuse.
// IN PLACE on plane (b,c) of dpout[b][1024][hw], c < 512.
// ---------------------------------------------------------------------------
__global__ __launch_bounds__(512, 8) void pooldisp_k(ushort* __restrict__ dp,
                                                     const float* __restrict__ sigma,
                                                     const float* __restrict__ offsets) {
    const int bc = blockIdx.x;
    const int b = bc >> 9, c = bc & 511;
    __shared__ float  tmp[68 * TS];
    __shared__ ushort pl[64 * PS2];
    const int tid = threadIdx.x;
    ushort* ip = dp + ((size_t)b * 1024 + c) * HWS;

    float s = sigma[c];
    float inv = 0.5f / (s * s + EPSF);
    float g0 = __expf(-4.f * inv), g1 = __expf(-1.f * inv);
    float gs = g0 + g1 + 1.f + g1 + g0;
    float rnorm = 1.f / (gs * gs);

    {
        int r4 = tid >> 7, col = tid & 127;
        if (col < TS) {
            int row = (r4 < 2) ? r4 : 64 + r4;   // 0,1,66,67
            tmp[row * TS + col] = 0.f;
        }
    }
    {
        int hr = tid >> 3, w0 = (tid & 7) * 8;
        const ushort* rp = ip + hr * 64 + w0;
        ushort8 mv = *reinterpret_cast<const ushort8*>(rp);
        float e[12];
        e[0] = (w0 > 0) ? __expf(fminf(bf2f(rp[-2]), EXP_CLAMP)) : 0.f;
        e[1] = (w0 > 0) ? __expf(fminf(bf2f(rp[-1]), EXP_CLAMP)) : 0.f;
#pragma unroll
        for (int q = 0; q < 8; ++q)
            e[2 + q] = __expf(fminf(bf2f(mv[q]), EXP_CLAMP));
        e[10] = (w0 < 56) ? __expf(fminf(bf2f(rp[8]), EXP_CLAMP)) : 0.f;
        e[11] = (w0 < 56) ? __expf(fminf(bf2f(rp[9]), EXP_CLAMP)) : 0.f;
        f32x4 o0, o1;
#pragma unroll
        for (int j = 0; j < 4; ++j) {
            o0[j] = g0 * (e[j] + e[j + 4]) + g1 * (e[j + 1] + e[j + 3]) + e[j + 2];
            o1[j] = g0 * (e[j + 4] + e[j + 8]) + g1 * (e[j + 5] + e[j + 7]) + e[j + 6];
        }
        *reinterpret_cast<f32x4*>(&tmp[(hr + 2) * TS + w0]) = o0;
        *reinterpret_cast<f32x4*>(&tmp[(hr + 2) * TS + w0 + 4]) = o1;
    }
    __syncthreads();

#pragma unroll
    for (int t = 0; t < 2; ++t) {
        int task = tid + t * 512;
        int h = task >> 4, wq = (task & 15) * 4;
        f32x4 t0 = *reinterpret_cast<const f32x4*>(&tmp[(h + 0) * TS + wq]);
        f32x4 t1 = *reinterpret_cast<const f32x4*>(&tmp[(h + 1) * TS + wq]);
        f32x4 t2 = *reinterpret_cast<const f32x4*>(&tmp[(h + 2) * TS + wq]);
        f32x4 t3 = *reinterpret_cast<const f32x4*>(&tmp[(h + 3) * TS + wq]);
        f32x4 t4 = *reinterpret_cast<const f32x4*>(&tmp[(h + 4) * TS + wq]);
        ushort o[4];
#pragma unroll
        for (int j = 0; j < 4; ++j) {
            float v = g0 * (t0[j] + t4[j]) + g1 * (t1[j] + t3[j]) + t2[j];
            o[j] = f2bf(__logf(v * rnorm + EPSF));
        }
        *reinterpret_cast<uint32*>(&pl[h * PS2 + wq]) =
            (uint32)o[0] | ((uint32)o[1] << 16);
        *reinterpret_cast<uint32*>(&pl[h * PS2 + wq + 2]) =
            (uint32)o[2] | ((uint32)o[3] << 16);
    }
    __syncthreads();

    {
        int oi = c >> 3;
        float dy = offsets[oi * 2 + 0];
        float dx = offsets[oi * 2 + 1];
        float y0f = floorf(dy), x0f = floorf(dx);
        float fy = dy - y0f, fx = dx - x0f;
        int y0 = (int)y0f, x0 = (int)x0f;
        float w00 = (1.f - fy) * (1.f - fx), w01 = (1.f - fy) * fx;
        float w10 = fy * (1.f - fx),         w11 = fy * fx;
        int h = tid >> 3, w = (tid & 7) * 8;
        int ry0 = h + y0, ry1 = ry0 + 1;
        bool my0 = (ry0 >= 0) & (ry0 < 64);
        bool my1 = (ry1 >= 0) & (ry1 < 64);
        float e0[9], e1[9];
#pragma unroll
        for (int j = 0; j < 9; ++j) {
            int col = w + x0 + j;
            bool mx = (col >= 0) & (col < 64);
            e0[j] = (my0 & mx) ? bf2f(pl[ry0 * PS2 + col]) : 0.f;
            e1[j] = (my1 & mx) ? bf2f(pl[ry1 * PS2 + col]) : 0.f;
        }
        ushort8 ov;
#pragma unroll
        for (int q = 0; q < 8; ++q)
            ov[q] = f2bf(w00 * e0[q] + w01 * e0[q + 1]
                       + w10 * e1[q] + w11 * e1[q + 1]);
        *reinterpret_cast<ushort8*>(ip + tid * 8) = ov;
    }
}

// ---------------------------------------------------------------------------
// FUSED BN stats + softplus spatial sums (att half), 1024 threads,
// wave-per-batch, plane kept in registers between phases.
// ---------------------------------------------------------------------------
__global__ __launch_bounds__(1024) void attstats_k(const ushort* __restrict__ dp,
                                                   const float* __restrict__ gamma,
                                                   const float* __restrict__ beta,
                                                   float* __restrict__ scale,
                                                   float* __restrict__ shift,
                                                   float* __restrict__ rsum) {
    const int c = blockIdx.x;
    const int t = threadIdx.x;
    const int wv = t >> 6, lane = t & 63;
    const ushort* p = dp + ((size_t)wv * 1024 + 512 + c) * HWS;

    ushort8 v[8];
    float s = 0.f, s2 = 0.f;
#pragma unroll
    for (int k = 0; k < 8; ++k) {
        v[k] = *reinterpret_cast<const ushort8*>(p + lane * 8 + k * 512);
#pragma unroll
        for (int j = 0; j < 8; ++j) { float f = bf2f(v[k][j]); s += f; s2 += f * f; }
    }
#pragma unroll
    for (int off = 32; off > 0; off >>= 1) {
        s += __shfl_down(s, off, 64);
        s2 += __shfl_down(s2, off, 64);
    }
    __shared__ float t1[16], t2[16], scsh[2];
    if (lane == 0) { t1[wv] = s; t2[wv] = s2; }
    __syncthreads();
    if (t == 0) {
        float S = 0.f, S2 = 0.f;
#pragma unroll
        for (int k = 0; k < 16; ++k) { S += t1[k]; S2 += t2[k]; }
        float n = (float)(NB * HWS);
        float mean = S / n;
        float var = S2 / n - mean * mean;
        float invs = rsqrtf(var + BN_EPS);
        float sc = invs * gamma[c];
        float sh = beta[c] - mean * sc;
        scale[c] = sc; shift[c] = sh;
        scsh[0] = sc; scsh[1] = sh;
    }
    __syncthreads();
    float sc = scsh[0], sh = scsh[1];
    float ps = 0.f;
#pragma unroll
    for (int k = 0; k < 8; ++k)
#pragma unroll
        for (int j = 0; j < 8; ++j)
            ps += softplus_fast(bf2f(v[k][j]) * sc + sh);
#pragma unroll
    for (int off = 32; off > 0; off >>= 1) ps += __shfl_down(ps, off, 64);
    if (lane == 0) rsum[wv * DPC + c] = 1.f / ps;
}

// ---------------------------------------------------------------------------
// m = softplus(bn(att)) * rsum * disp, transposed via LDS -> mT[b][hw][512]
// ---------------------------------------------------------------------------
__global__ __launch_bounds__(256) void attmulT_k(const ushort* __restrict__ dp,
                                                 const float* __restrict__ scale,
                                                 const float* __restrict__ shift,
                                                 const float* __restrict__ rsum,
                                                 ushort* __restrict__ mT) {
    const int b = blockIdx.z, c0 = blockIdx.y * 64, hw0 = blockIdx.x * 64;
    __shared__ float tile[64][65];
    const int tid = threadIdx.x;
#pragma unroll
    for (int r = 0; r < 16; ++r) {
        int cl = r * 4 + (tid >> 6), hwl = tid & 63;
        int c = c0 + cl;
        size_t aidx = ((size_t)b * 1024 + 512 + c) * HWS + hw0 + hwl;
        size_t didx = ((size_t)b * 1024 + c) * HWS + hw0 + hwl;
        float a = bf2f(dp[aidx]) * scale[c] + shift[c];
        float m = softplus_fast(a) * rsum[b * DPC + c] * bf2f(dp[didx]);
        tile[cl][hwl] = m;
    }
    __syncthreads();
#pragma unroll
    for (int r = 0; r < 16; ++r) {
        int hwl = r * 4 + (tid >> 6), cl = tid & 63;
        mT[((size_t)b * HWS + hw0 + hwl) * DPC + c0 + cl] = f2bf(tile[cl][hwl]);
    }
}

// ---------------------------------------------------------------------------
// Reduce GEMM2 partials -> final BN scale/shift (512 partials per channel)
// ---------------------------------------------------------------------------
__global__ __launch_bounds__(256) void bnred_k(const float* __restrict__ part_s,
                                               const float* __restrict__ part_s2,
                                               const float* __restrict__ gamma,
                                               const float* __restrict__ beta,
                                               float* __restrict__ scale,
                                               float* __restrict__ shift) {
    const int c = blockIdx.x, t = threadIdx.x;
    float s  = part_s[(size_t)c * 512 + t]  + part_s[(size_t)c * 512 + 256 + t];
    float s2 = part_s2[(size_t)c * 512 + t] + part_s2[(size_t)c * 512 + 256 + t];
#pragma unroll
    for (int off = 32; off > 0; off >>= 1) {
        s += __shfl_down(s, off, 64);
        s2 += __shfl_down(s2, off, 64);
    }
    __shared__ float t1[4], t2[4];
    int lane = t & 63, wid = t >> 6;
    if (lane == 0) { t1[wid] = s; t2[wid] = s2; }
    __syncthreads();
    if (t == 0) {
        float S = t1[0] + t1[1] + t1[2] + t1[3];
        float S2 = t2[0] + t2[1] + t2[2] + t2[3];
        float n = (float)(NB * HWS);
        float mean = S / n;
        float var = S2 / n - mean * mean;
        float invs = rsqrtf(var + BN_EPS);
        float sc = invs * gamma[c];
        scale[c] = sc;
        shift[c] = beta[c] - mean * sc;
    }
}

// Final: out = relu(t*scale + shift), t bf16 -> out f32
__global__ __launch_bounds__(256) void final_k(const ushort* __restrict__ t,
                                               const float* __restrict__ scale,
                                               const float* __restrict__ shift,
                                               float* __restrict__ out) {
    int i = (blockIdx.x * 256 + threadIdx.x) * 8;
    int c = (i >> 12) & (COUTC - 1);
    float sc = scale[c], sh = shift[c];
    ushort8 v = *reinterpret_cast<const ushort8*>(t + i);
    float4 a, b4;
#pragma unroll
    for (int j = 0; j < 4; ++j) a[j] = fmaxf(bf2f(v[j]) * sc + sh, 0.f);
#pragma unroll
    for (int j = 0; j < 4; ++j) b4[j] = fmaxf(bf2f(v[4 + j]) * sc + sh, 0.f);
    *reinterpret_cast<float4*>(out + i) = a;
    *reinterpret_cast<float4*>(out + i + 4) = b4;
}

extern "C" void kernel_launch(void* const* d_in, const int* in_sizes, int n_in,
                              void* d_out, int out_size, void* d_ws, size_t ws_size,
                              hipStream_t stream) {
    const float* x           = (const float*)d_in[0];
    const float* pre_w       = (const float*)d_in[1];
    const float* pre_b       = (const float*)d_in[2];
    const float* sigma       = (const float*)d_in[3];
    const float* offsets     = (const float*)d_in[4];
    const float* atten_w     = (const float*)d_in[5];
    const float* atten_b     = (const float*)d_in[6];
    const float* atten_gamma = (const float*)d_in[7];
    const float* atten_beta  = (const float*)d_in[8];
    const float* post_w      = (const float*)d_in[9];
    const float* post_b      = (const float*)d_in[10];
    const float* bn_gamma    = (const float*)d_in[11];
    const float* bn_beta     = (const float*)d_in[12];
    float* out = (float*)d_out;

    // Workspace (MiB offsets), peak 227 MiB:
    //  [0,32)    xT bf16 [B][HW][256]
    //  [32,33)   weights bf16
    //  [33,34)   stats
    //  [34,162)  dpout bf16 [B][1024][HW]; after attmulT its [34,66) slice is
    //            reused as t bf16 [B][256][HW]
    //  [162,226) mT bf16 [B][HW][512]
    //  [226,227) BN partials (2 x 512KB)
    char* wsb = (char*)d_ws;
    ushort* xT     = (ushort*)(wsb);
    ushort* wbig   = (ushort*)(wsb + ((size_t)32 << 20));
    ushort* wpost  = wbig + 1024 * 256;
    float*  stats  = (float*)(wsb + ((size_t)33 << 20));
    ushort* dpout  = (ushort*)(wsb + ((size_t)34 << 20));
    ushort* tbuf   = dpout;   // [34,66): dead pre half after attmulT
    ushort* mT     = (ushort*)(wsb + ((size_t)162 << 20));
    float*  part_s  = (float*)(wsb + ((size_t)226 << 20));
    float*  part_s2 = part_s + 256 * 512;

    float* scaleA = stats;          // 512
    float* shiftA = stats + 512;    // 512
    float* rsum   = stats + 1024;   // 8192
    float* scale2 = stats + 9216;   // 256
    float* shift2 = stats + 9472;   // 256

    // 0. casts / transposes
    castT_k<<<dim3(64, 4, NB), 256, 0, stream>>>(x, xT);
    cast_k<<<128, 256, 0, stream>>>(pre_w,   wbig,             DPC * CINC);
    cast_k<<<128, 256, 0, stream>>>(atten_w, wbig + 512 * 256, DPC * CINC);
    cast_k<<<128, 256, 0, stream>>>(post_w,  wpost,            COUTC * DPC);

    // 1. FUSED pre+atten conv1x1 (MFMA, 2-phase dbuf) -> dpout
    mfma_gemm_k<1024, CINC, true, false><<<dim3(32, 8, NB), 256, 0, stream>>>(
        wbig, xT, pre_b, atten_b, nullptr, dpout, nullptr, nullptr);
    // 2. fused dynamic pool + displace, in place on pre half
    pooldisp_k<<<NB * DPC, 512, 0, stream>>>(dpout, sigma, offsets);
    // 3. FUSED BN stats + softplus spatial sums (atten)
    attstats_k<<<DPC, 1024, 0, stream>>>(dpout, atten_gamma, atten_beta,
                                         scaleA, shiftA, rsum);
    // 4. attmul, transposed -> mT
    attmulT_k<<<dim3(64, 8, NB), 256, 0, stream>>>(dpout, scaleA, shiftA, rsum, mT);
    // 5. post conv1x1 (MFMA, 2-phase dbuf) + f32 skip -> t bf16 + BN partials
    mfma_gemm_k<COUTC, DPC, false, true><<<dim3(32, 2, NB), 256, 0, stream>>>(
        wpost, mT, post_b, post_b, x, tbuf, part_s, part_s2);
    // 6. reduce partials -> scale2/shift2
    bnred_k<<<COUTC, 256, 0, stream>>>(part_s, part_s2, bn_gamma, bn_beta,
                                       scale2, shift2);
    // 7. relu(bn(t)) -> out f32
    final_k<<<(NB * COUTC * HWS) / 2048, 256, 0, stream>>>(tbuf, scale2, shift2, out);
}

// Round 12
// 271.983 us; speedup vs baseline: 4.0436x; 1.0171x over previous
//
#include <hip/hip_runtime.h>
#include <cmath>

#define NB   16
#define CINC 256
#define DPC  512
#define COUTC 256
#define HWS  4096
#define EPSF 1.1920928955078125e-07f
#define BN_EPS 1e-5f
#define EXP_CLAMP 88.722835f
#define TS 76   // pooldisp tmp f32 stride
#define PS2 66  // pooldisp pl ushort stride (33 words == 1 mod 32 -> 2-way banks)

typedef unsigned int uint32;
typedef unsigned short ushort;
typedef __bf16 bf16x8 __attribute__((ext_vector_type(8)));
typedef float f32x4 __attribute__((ext_vector_type(4)));
typedef unsigned short ushort8 __attribute__((ext_vector_type(8)));

__device__ inline ushort f2bf(float f) {          // native RNE cvt
    __bf16 h = (__bf16)f;
    return __builtin_bit_cast(ushort, h);
}
__device__ inline float bf2f(ushort u) {
    return __builtin_bit_cast(float, (uint32)u << 16);
}
__device__ inline float softplus_fast(float v) {
    return fmaxf(v, 0.f) + __logf(1.f + __expf(-fabsf(v)));
}
__device__ __forceinline__ void gload16(const void* g, void* l) {
    __builtin_amdgcn_global_load_lds(
        (__attribute__((address_space(1))) void*)g,
        (__attribute__((address_space(3))) void*)l, 16, 0, 0);
}

// ---------------------------------------------------------------------------
// MFMA bf16 GEMM, counted-vmcnt 2-slab pipeline (T4): prefetch stays in
// flight ACROSS barriers; vmcnt(4) waits only the current slab.  Conflict-
// free LDS via source-side slot permutation (slot ^= (row>>1)&3).
// out[b][o][hw] = bias[o] + sum_k A[o][k] * BT[b][hw][k]
// DUALBIAS: bias split at o=512.  PARTIALS: add f32 skip, write bf16 t, and
// emit per-channel (sum, sumsq) partials for the downstream BN.
// 128x128 tile, BK=32 x2 slabs, 4 waves.  grid (HWS/128, OTOT/128, NB).
// ---------------------------------------------------------------------------
template<int OTOT, int KTOT, bool DUALBIAS, bool PARTIALS>
__global__ __launch_bounds__(256) void mfma_gemm_k(
    const ushort* __restrict__ A, const ushort* __restrict__ BT,
    const float* __restrict__ bias1, const float* __restrict__ bias2,
    const float* __restrict__ skip, ushort* __restrict__ outp,
    float* __restrict__ part_s, float* __restrict__ part_s2) {
    const int hw0 = blockIdx.x * 128;
    const int o0  = blockIdx.y * 128;
    const int b   = blockIdx.z;
    __shared__ ushort As[2][128 * 32];
    __shared__ ushort Bs[2][128 * 32];
    const int tid  = threadIdx.x;
    const int lane = tid & 63;
    const int w    = tid >> 6;
    const int wm0  = (w >> 1) * 64;
    const int wn0  = (w & 1) * 64;

    f32x4 acc[4][4] = {};

    const ushort* Ab = A + (size_t)o0 * KTOT;
    const ushort* Bb = BT + ((size_t)b * HWS + hw0) * KTOT;
    const int rsub  = lane >> 2;
    const int ksubp = ((lane & 3) ^ ((lane >> 3) & 3)) * 8;

    auto stage = [&](int buf, int k0) {   // 4 global_load_lds per thread
#pragma unroll
        for (int i = 0; i < 2; ++i) {
            const int row = w * 32 + i * 16 + rsub;
            gload16(Ab + (size_t)row * KTOT + k0 + ksubp, &As[buf][(w * 32 + i * 16) * 32]);
            gload16(Bb + (size_t)row * KTOT + k0 + ksubp, &Bs[buf][(w * 32 + i * 16) * 32]);
        }
    };

    constexpr int NSTEP = KTOT / 32;
    stage(0, 0);
    stage(1, 32);
    int cur = 0;
#pragma unroll
    for (int step = 0; step < NSTEP; ++step) {
        // wait for current slab only; next slab's 4 loads stay in flight
        if (step == NSTEP - 1) asm volatile("s_waitcnt vmcnt(0)" ::: "memory");
        else                   asm volatile("s_waitcnt vmcnt(4)" ::: "memory");
        __builtin_amdgcn_s_barrier();
        __builtin_amdgcn_sched_barrier(0);   // keep ds_read below the barrier
        bf16x8 af[4], bfr[4];
#pragma unroll
        for (int mi = 0; mi < 4; ++mi) {
            int row = wm0 + mi * 16 + (lane & 15);
            int sl = (lane >> 4) ^ ((row >> 1) & 3);
            af[mi] = *reinterpret_cast<const bf16x8*>(&As[cur][row * 32 + sl * 8]);
        }
#pragma unroll
        for (int ni = 0; ni < 4; ++ni) {
            int row = wn0 + ni * 16 + (lane & 15);
            int sl = (lane >> 4) ^ ((row >> 1) & 3);
            bfr[ni] = *reinterpret_cast<const bf16x8*>(&Bs[cur][row * 32 + sl * 8]);
        }
#pragma unroll
        for (int mi = 0; mi < 4; ++mi)
#pragma unroll
            for (int ni = 0; ni < 4; ++ni)
                acc[mi][ni] = __builtin_amdgcn_mfma_f32_16x16x32_bf16(
                    af[mi], bfr[ni], acc[mi][ni], 0, 0, 0);
        __builtin_amdgcn_sched_barrier(0);   // nothing crosses into the refill
        __builtin_amdgcn_s_barrier();        // all waves done READING cur
        if (step + 2 < NSTEP) stage(cur, (step + 2) * 32);   // refill cur
        cur ^= 1;
    }

    // reuse dead staging LDS for partial-sum exchange
    float* pS  = reinterpret_cast<float*>(&As[0][0]);   // [2][128]
    float* pS2 = pS + 256;
    if constexpr (PARTIALS) __syncthreads();   // staging fully drained already

    // D frag: col = lane&15 (hw), row = (lane>>4)*4 + r (o).
#pragma unroll
    for (int mi = 0; mi < 4; ++mi) {
#pragma unroll
        for (int r = 0; r < 4; ++r) {
            int chL = wm0 + mi * 16 + ((lane >> 4) << 2) + r;
            int o = o0 + chL;
            float bi;
            if constexpr (DUALBIAS) bi = (o < 512) ? bias1[o] : bias2[o - 512];
            else bi = bias1[o];
            size_t base = ((size_t)b * OTOT + o) * HWS + hw0 + wn0 + (lane & 15);
            float s1 = 0.f, s2 = 0.f;
#pragma unroll
            for (int ni = 0; ni < 4; ++ni) {
                float v = acc[mi][ni][r] + bi;
                if constexpr (PARTIALS) v += skip[base + ni * 16];
                ushort tb = f2bf(v);
                outp[base + ni * 16] = tb;
                if constexpr (PARTIALS) {
                    float vf = bf2f(tb);
                    s1 += vf; s2 += vf * vf;
                }
            }
            if constexpr (PARTIALS) {
#pragma unroll
                for (int off = 1; off <= 8; off <<= 1) {
                    s1 += __shfl_xor(s1, off, 64);
                    s2 += __shfl_xor(s2, off, 64);
                }
                if ((lane & 15) == 0) {
                    pS[(w & 1) * 128 + chL]  = s1;
                    pS2[(w & 1) * 128 + chL] = s2;
                }
            }
        }
    }
    if constexpr (PARTIALS) {
        __syncthreads();
        if (tid < 128) {
            int k = blockIdx.x * NB + b;   // 0..511
            float S  = pS[tid]  + pS[128 + tid];
            float S2 = pS2[tid] + pS2[128 + tid];
            part_s[(size_t)(o0 + tid) * 512 + k]  = S;
            part_s2[(size_t)(o0 + tid) * 512 + k] = S2;
        }
    }
}

// ---------------------------------------------------------------------------
// x [B][256][HW] f32  ->  xT [B][HW][256] bf16
// ---------------------------------------------------------------------------
__global__ __launch_bounds__(256) void castT_k(const float* __restrict__ x,
                                               ushort* __restrict__ xT) {
    const int b = blockIdx.z, c0 = blockIdx.y * 64, hw0 = blockIdx.x * 64;
    __shared__ float tile[64][65];
    const int tid = threadIdx.x;
#pragma unroll
    for (int r = 0; r < 16; ++r) {
        int cl = r * 4 + (tid >> 6), hwl = tid & 63;
        tile[cl][hwl] = x[((size_t)b * CINC + c0 + cl) * HWS + hw0 + hwl];
    }
    __syncthreads();
#pragma unroll
    for (int r = 0; r < 16; ++r) {
        int hwl = r * 4 + (tid >> 6), cl = tid & 63;
        xT[((size_t)b * HWS + hw0 + hwl) * CINC + c0 + cl] = f2bf(tile[cl][hwl]);
    }
}

// generic f32 -> bf16 cast
__global__ __launch_bounds__(256) void cast_k(const float* __restrict__ in,
                                              ushort* __restrict__ out, int n) {
    int i = (blockIdx.x * 256 + threadIdx.x) * 4;
    if (i < n) {
        float4 v = *reinterpret_cast<const float4*>(in + i);
        out[i + 0] = f2bf(v.x); out[i + 1] = f2bf(v.y);
        out[i + 2] = f2bf(v.z); out[i + 3] = f2bf(v.w);
    }
}

// ---------------------------------------------------------------------------
// FUSED dynamic_pool + displace v4: 512 threads, exp+row-pass fused -> tmp
// f32; col-pass+log -> pl bf16 (stride 66); displace with 9-tap reuse.
// IN PLACE on plane (b,c) of dpout[b][1024][hw], c < 512.
// ---------------------------------------------------------------------------
__global__ __launch_bounds__(512, 8) void pooldisp_k(ushort* __restrict__ dp,
                                                     const float* __restrict__ sigma,
                                                     const float* __restrict__ offsets) {
    const int bc = blockIdx.x;
    const int b = bc >> 9, c = bc & 511;
    __shared__ float  tmp[68 * TS];
    __shared__ ushort pl[64 * PS2];
    const int tid = threadIdx.x;
    ushort* ip = dp + ((size_t)b * 1024 + c) * HWS;

    float s = sigma[c];
    float inv = 0.5f / (s * s + EPSF);
    float g0 = __expf(-4.f * inv), g1 = __expf(-1.f * inv);
    float gs = g0 + g1 + 1.f + g1 + g0;
    float rnorm = 1.f / (gs * gs);

    {
        int r4 = tid >> 7, col = tid & 127;
        if (col < TS) {
            int row = (r4 < 2) ? r4 : 64 + r4;   // 0,1,66,67
            tmp[row * TS + col] = 0.f;
        }
    }
    {
        int hr = tid >> 3, w0 = (tid & 7) * 8;
        const ushort* rp = ip + hr * 64 + w0;
        ushort8 mv = *reinterpret_cast<const ushort8*>(rp);
        float e[12];
        e[0] = (w0 > 0) ? __expf(fminf(bf2f(rp[-2]), EXP_CLAMP)) : 0.f;
        e[1] = (w0 > 0) ? __expf(fminf(bf2f(rp[-1]), EXP_CLAMP)) : 0.f;
#pragma unroll
        for (int q = 0; q < 8; ++q)
            e[2 + q] = __expf(fminf(bf2f(mv[q]), EXP_CLAMP));
        e[10] = (w0 < 56) ? __expf(fminf(bf2f(rp[8]), EXP_CLAMP)) : 0.f;
        e[11] = (w0 < 56) ? __expf(fminf(bf2f(rp[9]), EXP_CLAMP)) : 0.f;
        f32x4 o0, o1;
#pragma unroll
        for (int j = 0; j < 4; ++j) {
            o0[j] = g0 * (e[j] + e[j + 4]) + g1 * (e[j + 1] + e[j + 3]) + e[j + 2];
            o1[j] = g0 * (e[j + 4] + e[j + 8]) + g1 * (e[j + 5] + e[j + 7]) + e[j + 6];
        }
        *reinterpret_cast<f32x4*>(&tmp[(hr + 2) * TS + w0]) = o0;
        *reinterpret_cast<f32x4*>(&tmp[(hr + 2) * TS + w0 + 4]) = o1;
    }
    __syncthreads();

#pragma unroll
    for (int t = 0; t < 2; ++t) {
        int task = tid + t * 512;
        int h = task >> 4, wq = (task & 15) * 4;
        f32x4 t0 = *reinterpret_cast<const f32x4*>(&tmp[(h + 0) * TS + wq]);
        f32x4 t1 = *reinterpret_cast<const f32x4*>(&tmp[(h + 1) * TS + wq]);
        f32x4 t2 = *reinterpret_cast<const f32x4*>(&tmp[(h + 2) * TS + wq]);
        f32x4 t3 = *reinterpret_cast<const f32x4*>(&tmp[(h + 3) * TS + wq]);
        f32x4 t4 = *reinterpret_cast<const f32x4*>(&tmp[(h + 4) * TS + wq]);
        ushort o[4];
#pragma unroll
        for (int j = 0; j < 4; ++j) {
            float v = g0 * (t0[j] + t4[j]) + g1 * (t1[j] + t3[j]) + t2[j];
            o[j] = f2bf(__logf(v * rnorm + EPSF));
        }
        *reinterpret_cast<uint32*>(&pl[h * PS2 + wq]) =
            (uint32)o[0] | ((uint32)o[1] << 16);
        *reinterpret_cast<uint32*>(&pl[h * PS2 + wq + 2]) =
            (uint32)o[2] | ((uint32)o[3] << 16);
    }
    __syncthreads();

    {
        int oi = c >> 3;
        float dy = offsets[oi * 2 + 0];
        float dx = offsets[oi * 2 + 1];
        float y0f = floorf(dy), x0f = floorf(dx);
        float fy = dy - y0f, fx = dx - x0f;
        int y0 = (int)y0f, x0 = (int)x0f;
        float w00 = (1.f - fy) * (1.f - fx), w01 = (1.f - fy) * fx;
        float w10 = fy * (1.f - fx),         w11 = fy * fx;
        int h = tid >> 3, w = (tid & 7) * 8;
        int ry0 = h + y0, ry1 = ry0 + 1;
        bool my0 = (ry0 >= 0) & (ry0 < 64);
        bool my1 = (ry1 >= 0) & (ry1 < 64);
        float e0[9], e1[9];
#pragma unroll
        for (int j = 0; j < 9; ++j) {
            int col = w + x0 + j;
            bool mx = (col >= 0) & (col < 64);
            e0[j] = (my0 & mx) ? bf2f(pl[ry0 * PS2 + col]) : 0.f;
            e1[j] = (my1 & mx) ? bf2f(pl[ry1 * PS2 + col]) : 0.f;
        }
        ushort8 ov;
#pragma unroll
        for (int q = 0; q < 8; ++q)
            ov[q] = f2bf(w00 * e0[q] + w01 * e0[q + 1]
                       + w10 * e1[q] + w11 * e1[q + 1]);
        *reinterpret_cast<ushort8*>(ip + tid * 8) = ov;
    }
}

// ---------------------------------------------------------------------------
// FUSED BN stats + softplus spatial sums (att half), 1024 threads,
// wave-per-batch, plane kept in registers between phases.
// ---------------------------------------------------------------------------
__global__ __launch_bounds__(1024) void attstats_k(const ushort* __restrict__ dp,
                                                   const float* __restrict__ gamma,
                                                   const float* __restrict__ beta,
                                                   float* __restrict__ scale,
                                                   float* __restrict__ shift,
                                                   float* __restrict__ rsum) {
    const int c = blockIdx.x;
    const int t = threadIdx.x;
    const int wv = t >> 6, lane = t & 63;
    const ushort* p = dp + ((size_t)wv * 1024 + 512 + c) * HWS;

    ushort8 v[8];
    float s = 0.f, s2 = 0.f;
#pragma unroll
    for (int k = 0; k < 8; ++k) {
        v[k] = *reinterpret_cast<const ushort8*>(p + lane * 8 + k * 512);
#pragma unroll
        for (int j = 0; j < 8; ++j) { float f = bf2f(v[k][j]); s += f; s2 += f * f; }
    }
#pragma unroll
    for (int off = 32; off > 0; off >>= 1) {
        s += __shfl_down(s, off, 64);
        s2 += __shfl_down(s2, off, 64);
    }
    __shared__ float t1[16], t2[16], scsh[2];
    if (lane == 0) { t1[wv] = s; t2[wv] = s2; }
    __syncthreads();
    if (t == 0) {
        float S = 0.f, S2 = 0.f;
#pragma unroll
        for (int k = 0; k < 16; ++k) { S += t1[k]; S2 += t2[k]; }
        float n = (float)(NB * HWS);
        float mean = S / n;
        float var = S2 / n - mean * mean;
        float invs = rsqrtf(var + BN_EPS);
        float sc = invs * gamma[c];
        float sh = beta[c] - mean * sc;
        scale[c] = sc; shift[c] = sh;
        scsh[0] = sc; scsh[1] = sh;
    }
    __syncthreads();
    float sc = scsh[0], sh = scsh[1];
    float ps = 0.f;
#pragma unroll
    for (int k = 0; k < 8; ++k)
#pragma unroll
        for (int j = 0; j < 8; ++j)
            ps += softplus_fast(bf2f(v[k][j]) * sc + sh);
#pragma unroll
    for (int off = 32; off > 0; off >>= 1) ps += __shfl_down(ps, off, 64);
    if (lane == 0) rsum[wv * DPC + c] = 1.f / ps;
}

// ---------------------------------------------------------------------------
// m = softplus(bn(att)) * rsum * disp, transposed via LDS -> mT[b][hw][512]
// ---------------------------------------------------------------------------
__global__ __launch_bounds__(256) void attmulT_k(const ushort* __restrict__ dp,
                                                 const float* __restrict__ scale,
                                                 const float* __restrict__ shift,
                                                 const float* __restrict__ rsum,
                                                 ushort* __restrict__ mT) {
    const int b = blockIdx.z, c0 = blockIdx.y * 64, hw0 = blockIdx.x * 64;
    __shared__ float tile[64][65];
    const int tid = threadIdx.x;
#pragma unroll
    for (int r = 0; r < 16; ++r) {
        int cl = r * 4 + (tid >> 6), hwl = tid & 63;
        int c = c0 + cl;
        size_t aidx = ((size_t)b * 1024 + 512 + c) * HWS + hw0 + hwl;
        size_t didx = ((size_t)b * 1024 + c) * HWS + hw0 + hwl;
        float a = bf2f(dp[aidx]) * scale[c] + shift[c];
        float m = softplus_fast(a) * rsum[b * DPC + c] * bf2f(dp[didx]);
        tile[cl][hwl] = m;
    }
    __syncthreads();
#pragma unroll
    for (int r = 0; r < 16; ++r) {
        int hwl = r * 4 + (tid >> 6), cl = tid & 63;
        mT[((size_t)b * HWS + hw0 + hwl) * DPC + c0 + cl] = f2bf(tile[cl][hwl]);
    }
}

// ---------------------------------------------------------------------------
// Reduce GEMM2 partials -> final BN scale/shift (512 partials per channel)
// ---------------------------------------------------------------------------
__global__ __launch_bounds__(256) void bnred_k(const float* __restrict__ part_s,
                                               const float* __restrict__ part_s2,
                                               const float* __restrict__ gamma,
                                               const float* __restrict__ beta,
                                               float* __restrict__ scale,
                                               float* __restrict__ shift) {
    const int c = blockIdx.x, t = threadIdx.x;
    float s  = part_s[(size_t)c * 512 + t]  + part_s[(size_t)c * 512 + 256 + t];
    float s2 = part_s2[(size_t)c * 512 + t] + part_s2[(size_t)c * 512 + 256 + t];
#pragma unroll
    for (int off = 32; off > 0; off >>= 1) {
        s += __shfl_down(s, off, 64);
        s2 += __shfl_down(s2, off, 64);
    }
    __shared__ float t1[4], t2[4];
    int lane = t & 63, wid = t >> 6;
    if (lane == 0) { t1[wid] = s; t2[wid] = s2; }
    __syncthreads();
    if (t == 0) {
        float S = t1[0] + t1[1] + t1[2] + t1[3];
        float S2 = t2[0] + t2[1] + t2[2] + t2[3];
        float n = (float)(NB * HWS);
        float mean = S / n;
        float var = S2 / n - mean * mean;
        float invs = rsqrtf(var + BN_EPS);
        float sc = invs * gamma[c];
        scale[c] = sc;
        shift[c] = beta[c] - mean * sc;
    }
}

// Final: out = relu(t*scale + shift), t bf16 -> out f32
__global__ __launch_bounds__(256) void final_k(const ushort* __restrict__ t,
                                               const float* __restrict__ scale,
                                               const float* __restrict__ shift,
                                               float* __restrict__ out) {
    int i = (blockIdx.x * 256 + threadIdx.x) * 8;
    int c = (i >> 12) & (COUTC - 1);
    float sc = scale[c], sh = shift[c];
    ushort8 v = *reinterpret_cast<const ushort8*>(t + i);
    float4 a, b4;
#pragma unroll
    for (int j = 0; j < 4; ++j) a[j] = fmaxf(bf2f(v[j]) * sc + sh, 0.f);
#pragma unroll
    for (int j = 0; j < 4; ++j) b4[j] = fmaxf(bf2f(v[4 + j]) * sc + sh, 0.f);
    *reinterpret_cast<float4*>(out + i) = a;
    *reinterpret_cast<float4*>(out + i + 4) = b4;
}

extern "C" void kernel_launch(void* const* d_in, const int* in_sizes, int n_in,
                              void* d_out, int out_size, void* d_ws, size_t ws_size,
                              hipStream_t stream) {
    const float* x           = (const float*)d_in[0];
    const float* pre_w       = (const float*)d_in[1];
    const float* pre_b       = (const float*)d_in[2];
    const float* sigma       = (const float*)d_in[3];
    const float* offsets     = (const float*)d_in[4];
    const float* atten_w     = (const float*)d_in[5];
    const float* atten_b     = (const float*)d_in[6];
    const float* atten_gamma = (const float*)d_in[7];
    const float* atten_beta  = (const float*)d_in[8];
    const float* post_w      = (const float*)d_in[9];
    const float* post_b      = (const float*)d_in[10];
    const float* bn_gamma    = (const float*)d_in[11];
    const float* bn_beta     = (const float*)d_in[12];
    float* out = (float*)d_out;

    // Workspace (MiB offsets), peak 227 MiB.
    char* wsb = (char*)d_ws;
    ushort* xT     = (ushort*)(wsb);
    ushort* wbig   = (ushort*)(wsb + ((size_t)32 << 20));
    ushort* wpost  = wbig + 1024 * 256;
    float*  stats  = (float*)(wsb + ((size_t)33 << 20));
    ushort* dpout  = (ushort*)(wsb + ((size_t)34 << 20));
    ushort* tbuf   = dpout;   // [34,66): dead pre half after attmulT
    ushort* mT     = (ushort*)(wsb + ((size_t)162 << 20));
    float*  part_s  = (float*)(wsb + ((size_t)226 << 20));
    float*  part_s2 = part_s + 256 * 512;

    float* scaleA = stats;          // 512
    float* shiftA = stats + 512;    // 512
    float* rsum   = stats + 1024;   // 8192
    float* scale2 = stats + 9216;   // 256
    float* shift2 = stats + 9472;   // 256

    // 0. casts / transposes
    castT_k<<<dim3(64, 4, NB), 256, 0, stream>>>(x, xT);
    cast_k<<<128, 256, 0, stream>>>(pre_w,   wbig,             DPC * CINC);
    cast_k<<<128, 256, 0, stream>>>(atten_w, wbig + 512 * 256, DPC * CINC);
    cast_k<<<128, 256, 0, stream>>>(post_w,  wpost,            COUTC * DPC);

    // 1. FUSED pre+atten conv1x1 (MFMA, counted-vmcnt pipeline) -> dpout
    mfma_gemm_k<1024, CINC, true, false><<<dim3(32, 8, NB), 256, 0, stream>>>(
        wbig, xT, pre_b, atten_b, nullptr, dpout, nullptr, nullptr);
    // 2. fused dynamic pool + displace, in place on pre half
    pooldisp_k<<<NB * DPC, 512, 0, stream>>>(dpout, sigma, offsets);
    // 3. FUSED BN stats + softplus spatial sums (atten)
    attstats_k<<<DPC, 1024, 0, stream>>>(dpout, atten_gamma, atten_beta,
                                         scaleA, shiftA, rsum);
    // 4. attmul, transposed -> mT
    attmulT_k<<<dim3(64, 8, NB), 256, 0, stream>>>(dpout, scaleA, shiftA, rsum, mT);
    // 5. post conv1x1 (MFMA, counted-vmcnt pipeline) + f32 skip -> t bf16 + partials
    mfma_gemm_k<COUTC, DPC, false, true><<<dim3(32, 2, NB), 256, 0, stream>>>(
        wpost, mT, post_b, post_b, x, tbuf, part_s, part_s2);
    // 6. reduce partials -> scale2/shift2
    bnred_k<<<COUTC, 256, 0, stream>>>(part_s, part_s2, bn_gamma, bn_beta,
                                       scale2, shift2);
    // 7. relu(bn(t)) -> out f32
    final_k<<<(NB * COUTC * HWS) / 2048, 256, 0, stream>>>(tbuf, scale2, shift2, out);
}